// Round 3
// baseline (18072.203 us; speedup 1.0000x reference)
//
#include <hip/hip_runtime.h>
#include <math.h>
#include <stdint.h>

// ---------------------------------------------------------------------------
// SlotAttention forward. Correctness-first implementation.
// Core difficulty: replicate LAPACK dsyevd (numpy eigh) including eigenvector
// SIGN conventions: dsytd2 + D&C (tear -> dsteqr(16) leaves -> dlaed1/2/3
// merges) + reflector back-transform of the 8 needed columns. All f64.
// R1: leaf_kernel arrays scratch->LDS (swizzled) + fused rotation apply.
// R2: dsytrd wave-parallel matvec/rank-2; 128x128 f32 GEMM (bit-identical k).
// R3: dsytrd -> blocked dlatrd (NB=32, V/W panels, 1 trailing pass/panel);
//     merge_scan block-per-merge with LDS arrays + deferred rotations;
//     defl_copy row-parallel; zproj coalesced (bit-identical).
// ---------------------------------------------------------------------------

#define NB 64
#define ND 512
#define NN_ 256
#define NSL 8
#define LPB 24  // leaves per block in leaf_kernel; LDS = 24*(256+33)*8 = 55.5KB
#define TNB 32  // dlatrd panel width
#define VWROWS 260  // padded rows for V/W panels

static __device__ __forceinline__ double fsign(double a, double b) {
  return (b >= 0.0) ? fabs(a) : -fabs(a);
}
static __device__ __forceinline__ double dlapy2d(double x, double y) {
  double ax = fabs(x), ay = fabs(y);
  double w = ax > ay ? ax : ay, z = ax > ay ? ay : ax;
  if (z == 0.0) return w;
  double q = z / w;
  return w * sqrt(1.0 + q * q);
}
#define EPS_D 1.1102230246251565e-16

// LAPACK >= 3.10 dlartg convention (modern numpy/OpenBLAS)
static __device__ void dlartgd(double f, double g, double& cs, double& sn, double& r) {
  if (g == 0.0) { cs = 1.0; sn = 0.0; r = f; }
  else if (f == 0.0) { cs = 0.0; sn = fsign(1.0, g); r = fabs(g); }
  else {
    double f1 = fabs(f);
    double d = sqrt(f * f + g * g);
    cs = f1 / d;
    r = fsign(d, f);
    sn = g / r;
  }
}

static __device__ void dlaev2d(double a, double b, double c, double& rt1, double& rt2,
                               double& cs1, double& sn1) {
  double sm = a + c, df = a - c, adf = fabs(df), tb = b + b, ab = fabs(tb);
  double acmx, acmn;
  if (fabs(a) > fabs(c)) { acmx = a; acmn = c; } else { acmx = c; acmn = a; }
  double rt;
  if (adf > ab) { double q = ab / adf; rt = adf * sqrt(1.0 + q * q); }
  else if (adf < ab) { double q = adf / ab; rt = ab * sqrt(1.0 + q * q); }
  else rt = ab * sqrt(2.0);
  int sgn1;
  if (sm < 0.0) { rt1 = 0.5 * (sm - rt); sgn1 = -1; rt2 = (acmx / rt1) * acmn - (b / rt1) * b; }
  else if (sm > 0.0) { rt1 = 0.5 * (sm + rt); sgn1 = 1; rt2 = (acmx / rt1) * acmn - (b / rt1) * b; }
  else { rt1 = 0.5 * rt; rt2 = -0.5 * rt; sgn1 = 1; }
  double cs; int sgn2;
  if (df >= 0.0) { cs = df + rt; sgn2 = 1; } else { cs = df - rt; sgn2 = -1; }
  double acs = fabs(cs);
  if (acs > ab) { double ct = -tb / cs; sn1 = 1.0 / sqrt(1.0 + ct * ct); cs1 = ct * sn1; }
  else {
    if (ab == 0.0) { cs1 = 1.0; sn1 = 0.0; }
    else { double tn = -cs / tb; cs1 = 1.0 / sqrt(1.0 + tn * tn); sn1 = tn * cs1; }
  }
  if (sgn1 == sgn2) { double tn = cs1; cs1 = -sn1; sn1 = tn; }
}

// dsteqr COMPZ='I', n=16, faithful port (1-based d[1..16], e[1..15]).
// Arrays in LDS; Z XOR-swizzled; rotation apply fused (identical order).
static __device__ void dsteqr16_lds(double* dd, double* ee, double* zz, int sw) {
  const int n = 16;
#define ZM(i, j) zz[((((i)-1) << 4) + ((j)-1)) ^ sw]
#define D_(i) dd[(i)]
#define E_(i) ee[(i)]
  for (int i = 1; i <= n; ++i)
    for (int j = 1; j <= n; ++j) ZM(i, j) = (i == j) ? 1.0 : 0.0;
  const double eps = EPS_D, eps2 = eps * eps, safmin = 2.2250738585072014e-308;
  int nmaxit = n * 30, jtot = 0, l1 = 1;
  while (l1 <= n) {
    if (l1 > 1) E_(l1 - 1) = 0.0;
    int m = n;
    for (int mm = l1; mm <= n - 1; ++mm) {
      double tst = fabs(E_(mm));
      if (tst == 0.0) { m = mm; break; }
      if (tst <= (sqrt(fabs(D_(mm))) * sqrt(fabs(D_(mm + 1)))) * eps) { E_(mm) = 0.0; m = mm; break; }
    }
    int l = l1, lsv = l, lend = m, lendsv = m;
    l1 = m + 1;
    if (lend == l) continue;
    double anorm = 0.0;
    for (int i = l; i <= lend; ++i) anorm = fmax(anorm, fabs(D_(i)));
    for (int i = l; i <= lend - 1; ++i) anorm = fmax(anorm, fabs(E_(i)));
    if (anorm == 0.0) continue;
    if (fabs(D_(lend)) < fabs(D_(l))) { lend = lsv; l = lendsv; }
    if (lend > l) {  // QL
      for (;;) {
        int m2 = lend;
        if (l != lend) {
          for (int mm = l; mm <= lend - 1; ++mm) {
            double tst = E_(mm) * E_(mm);
            if (tst <= (eps2 * fabs(D_(mm))) * fabs(D_(mm + 1)) + safmin) { m2 = mm; break; }
          }
        }
        if (m2 < lend) E_(m2) = 0.0;
        double p = D_(l);
        if (m2 == l) { D_(l) = p; ++l; if (l > lend) break; continue; }
        if (m2 == l + 1) {
          double rt1, rt2, c, s;
          dlaev2d(D_(l), E_(l), D_(l + 1), rt1, rt2, c, s);
          for (int i = 1; i <= n; ++i) {
            double tmp = ZM(i, l + 1);
            ZM(i, l + 1) = c * tmp - s * ZM(i, l);
            ZM(i, l) = s * tmp + c * ZM(i, l);
          }
          D_(l) = rt1; D_(l + 1) = rt2; E_(l) = 0.0;
          l += 2; if (l > lend) break; continue;
        }
        if (jtot == nmaxit) break;
        ++jtot;
        double g = (D_(l + 1) - p) / (2.0 * E_(l));
        double r = dlapy2d(g, 1.0);
        g = D_(m2) - p + E_(l) / (g + fsign(r, g));
        double s = 1.0, c = 1.0; p = 0.0;
        for (int i = m2 - 1; i >= l; --i) {
          double f = s * E_(i), bb = c * E_(i);
          dlartgd(g, f, c, s, r);
          if (i != m2 - 1) E_(i + 1) = r;
          g = D_(i + 1) - p;
          r = (D_(i) - g) * s + 2.0 * c * bb;
          p = s * r;
          D_(i + 1) = g + p;
          g = c * r - bb;
          double cj = c, sj = -s;
          for (int i2 = 1; i2 <= n; ++i2) {
            double tmp = ZM(i2, i + 1);
            ZM(i2, i + 1) = cj * tmp - sj * ZM(i2, i);
            ZM(i2, i) = sj * tmp + cj * ZM(i2, i);
          }
        }
        D_(l) -= p; E_(l) = g;
      }
    } else {  // QR
      for (;;) {
        int m2 = lend;
        if (l != lend) {
          for (int mm = l; mm >= lend + 1; --mm) {
            double tst = E_(mm - 1) * E_(mm - 1);
            if (tst <= (eps2 * fabs(D_(mm))) * fabs(D_(mm - 1)) + safmin) { m2 = mm; break; }
          }
        }
        if (m2 > lend) E_(m2 - 1) = 0.0;
        double p = D_(l);
        if (m2 == l) { D_(l) = p; --l; if (l < lend) break; continue; }
        if (m2 == l - 1) {
          double rt1, rt2, c, s;
          dlaev2d(D_(l - 1), E_(l - 1), D_(l), rt1, rt2, c, s);
          for (int i = 1; i <= n; ++i) {
            double tmp = ZM(i, l);
            ZM(i, l) = c * tmp - s * ZM(i, l - 1);
            ZM(i, l - 1) = s * tmp + c * ZM(i, l - 1);
          }
          D_(l - 1) = rt1; D_(l) = rt2; E_(l - 1) = 0.0;
          l -= 2; if (l < lend) break; continue;
        }
        if (jtot == nmaxit) break;
        ++jtot;
        double g = (D_(l - 1) - p) / (2.0 * E_(l - 1));
        double r = dlapy2d(g, 1.0);
        g = D_(m2) - p + E_(l - 1) / (g + fsign(r, g));
        double s = 1.0, c = 1.0; p = 0.0;
        for (int i = m2; i <= l - 1; ++i) {
          double f = s * E_(i), bb = c * E_(i);
          dlartgd(g, f, c, s, r);
          if (i != m2) E_(i - 1) = r;
          g = D_(i) - p;
          r = (D_(i + 1) - g) * s + 2.0 * c * bb;
          p = s * r;
          D_(i) = g + p;
          g = c * r - bb;
          double cj = c, sj = s;
          for (int i2 = 1; i2 <= n; ++i2) {
            double tmp = ZM(i2, i + 1);
            ZM(i2, i + 1) = cj * tmp - sj * ZM(i2, i);
            ZM(i2, i) = sj * tmp + cj * ZM(i2, i);
          }
        }
        D_(l) -= p; E_(l - 1) = g;
      }
    }
  }
  for (int ii = 2; ii <= n; ++ii) {
    int i = ii - 1, k = i;
    double p = D_(i);
    for (int j = ii; j <= n; ++j)
      if (D_(j) < p) { k = j; p = D_(j); }
    if (k != i) {
      D_(k) = D_(i); D_(i) = p;
      for (int r = 1; r <= n; ++r) { double t = ZM(r, i); ZM(r, i) = ZM(r, k); ZM(r, k) = t; }
    }
  }
#undef ZM
#undef D_
#undef E_
}

static __device__ void dlamrg_dev(int n1v, int n2v, const double* a, int strd1, int strd2, int* index) {
  int n1sv = n1v, n2sv = n2v;
  int ind1 = (strd1 > 0) ? 1 : n1v;
  int ind2 = (strd2 > 0) ? n1v + 1 : n1v + n2v;
  int i = 1;
  while (n1sv > 0 && n2sv > 0) {
    if (a[ind1] <= a[ind2]) { index[i++] = ind1; ind1 += strd1; --n1sv; }
    else { index[i++] = ind2; ind2 += strd2; --n2sv; }
  }
  if (n1sv == 0) { while (n2sv > 0) { index[i++] = ind2; ind2 += strd2; --n2sv; } }
  else { while (n1sv > 0) { index[i++] = ind1; ind1 += strd1; --n1sv; } }
}

// -------------------------------- kernels ----------------------------------

__global__ __launch_bounds__(256) void pos_kernel(const float* __restrict__ w,
                                                  const float* __restrict__ bias,
                                                  float* __restrict__ posT) {
  int idx = blockIdx.x * 256 + threadIdx.x;
  if (idx >= 512 * 256) return;
  int d = idx / 256, n = idx % 256;
  int i = n / 16, j = n % 16;
  double step = 1.0 / 15.0;
  float gi = (i == 15) ? 1.0f : (float)(i * step);
  float gj = (j == 15) ? 1.0f : (float)(j * step);
  float v = gi * w[0 * 512 + d] + gj * w[1 * 512 + d] + (1.0f - gi) * w[2 * 512 + d] +
            (1.0f - gj) * w[3 * 512 + d] + bias[d];
  posT[(size_t)d * 256 + n] = v;
}

__global__ __launch_bounds__(256) void stats_kernel(const float* __restrict__ x,
                                                    const float* __restrict__ posT,
                                                    float* mean_o, float* rstd_o, int addpos) {
  int b = blockIdx.x, t = threadIdx.x;
  __shared__ double r1[256], r2[256];
  double s = 0.0, ss = 0.0;
  const float* xb = x + (size_t)b * 131072;
  for (int i = t; i < 131072; i += 256) {
    float v = xb[i];
    if (addpos) v += posT[i];
    s += v; ss += (double)v * v;
  }
  r1[t] = s; r2[t] = ss; __syncthreads();
  for (int o = 128; o > 0; o >>= 1) { if (t < o) { r1[t] += r1[t + o]; r2[t] += r2[t + o]; } __syncthreads(); }
  if (t == 0) {
    double m = r1[0] / 131072.0;
    double var = r2[0] / 131072.0 - m * m;
    mean_o[b] = (float)m;
    rstd_o[b] = 1.0f / sqrtf((float)var + 1e-5f);
  }
}

__global__ __launch_bounds__(256) void tln_kernel(const float* __restrict__ x,
                                                  const float* __restrict__ posT,
                                                  const float* __restrict__ g,
                                                  const float* __restrict__ be,
                                                  const float* m1, const float* r1,
                                                  const float* m2, const float* r2,
                                                  float* __restrict__ fnp,
                                                  float* __restrict__ fpln) {
  int b = blockIdx.x, dt = blockIdx.y, nt = blockIdx.z;
  __shared__ float t1[32][33], t2[32][33];
  int t = threadIdx.x;
  const float* xb = x + (size_t)b * 131072;
  for (int l = 0; l < 4; ++l) {
    int idx = t + l * 256;
    int row = idx >> 5, col = idx & 31;
    int dd = dt * 32 + row, nn = nt * 32 + col;
    float v = xb[(size_t)dd * 256 + nn];
    t1[row][col] = v;
    t2[row][col] = v + posT[(size_t)dd * 256 + nn];
  }
  __syncthreads();
  float mm1 = m1[b], rr1 = r1[b], mm2 = m2[b], rr2 = r2[b];
  for (int l = 0; l < 4; ++l) {
    int idx = t + l * 256;
    int row = idx >> 5, col = idx & 31;
    int nn = nt * 32 + row, dd = dt * 32 + col;
    float gg = g[(size_t)nn * 512 + dd], bb = be[(size_t)nn * 512 + dd];
    size_t o = (size_t)b * 131072 + (size_t)nn * 512 + dd;
    fnp[o] = (t1[col][row] - mm1) * rr1 * gg + bb;
    fpln[o] = (t2[col][row] - mm2) * rr2 * gg + bb;
  }
}

__global__ __launch_bounds__(256) void gemm_f32(const float* __restrict__ A,
                                                const float* __restrict__ Bm,
                                                const float* __restrict__ bias,
                                                const float* __restrict__ base,
                                                float* __restrict__ C, int M, int Nc, int Kd,
                                                int bt, int act, int addb) {
  __shared__ float As[16][65];
  __shared__ float Bs[16][65];
  int bm = blockIdx.x * 64, bn = blockIdx.y * 64;
  int t = threadIdx.x;
  int tx = t & 15, ty = t >> 4;
  float acc[4][4] = {};
  for (int k0 = 0; k0 < Kd; k0 += 16) {
    for (int l = 0; l < 4; ++l) {
      int idx = t + l * 256;
      { int r = idx >> 4, kk = idx & 15;
        float v = 0.f;
        if (bm + r < M && k0 + kk < Kd) v = A[(size_t)(bm + r) * Kd + k0 + kk];
        As[kk][r] = v; }
      if (bt == 0) {
        int kk = idx >> 6, nn = idx & 63;
        float v = 0.f;
        if (k0 + kk < Kd && bn + nn < Nc) v = Bm[(size_t)(k0 + kk) * Nc + bn + nn];
        Bs[kk][nn] = v;
      } else {
        int nn = idx >> 4, kk = idx & 15;
        float v = 0.f;
        if (bn + nn < Nc && k0 + kk < Kd) v = Bm[(size_t)(bn + nn) * Kd + k0 + kk];
        Bs[kk][nn] = v;
      }
    }
    __syncthreads();
#pragma unroll
    for (int kk = 0; kk < 16; ++kk) {
      float a0[4], b0[4];
#pragma unroll
      for (int q = 0; q < 4; ++q) a0[q] = As[kk][ty * 4 + q];
#pragma unroll
      for (int q = 0; q < 4; ++q) b0[q] = Bs[kk][tx * 4 + q];
#pragma unroll
      for (int q = 0; q < 4; ++q)
#pragma unroll
        for (int p = 0; p < 4; ++p) acc[q][p] += a0[q] * b0[p];
    }
    __syncthreads();
  }
  for (int q = 0; q < 4; ++q) {
    int r = bm + ty * 4 + q;
    if (r >= M) continue;
    for (int p = 0; p < 4; ++p) {
      int c = bn + tx * 4 + p;
      if (c >= Nc) continue;
      float v = acc[q][p];
      if (bias) v += bias[c];
      if (act == 1) v = fmaxf(v, 0.f);
      if (addb) v += base[(size_t)r * Nc + c];
      C[(size_t)r * Nc + c] = v;
    }
  }
}

// 128x128 tile, 8x8 acc/thread. M%128==0, Nc%128==0, Kd%16==0.
__global__ __launch_bounds__(256) void gemm_f32_big(const float* __restrict__ A,
                                                    const float* __restrict__ Bm,
                                                    const float* __restrict__ bias,
                                                    const float* __restrict__ base,
                                                    float* __restrict__ C, int M, int Nc, int Kd,
                                                    int bt, int act, int addb) {
  __shared__ float As[16][128];
  __shared__ float Bs[16][128];
  int bm = blockIdx.x * 128, bn = blockIdx.y * 128;
  int t = threadIdx.x;
  int tx = t & 15, ty = t >> 4;
  int lrow = t >> 1, lseg = (t & 1) * 8;
  float acc[8][8] = {};
  for (int k0 = 0; k0 < Kd; k0 += 16) {
    {
      const float* src = A + (size_t)(bm + lrow) * Kd + k0 + lseg;
      float4 p0 = *(const float4*)src;
      float4 p1 = *(const float4*)(src + 4);
      As[lseg + 0][lrow] = p0.x; As[lseg + 1][lrow] = p0.y;
      As[lseg + 2][lrow] = p0.z; As[lseg + 3][lrow] = p0.w;
      As[lseg + 4][lrow] = p1.x; As[lseg + 5][lrow] = p1.y;
      As[lseg + 6][lrow] = p1.z; As[lseg + 7][lrow] = p1.w;
    }
    if (bt == 0) {
      int bk = t >> 4, bcol = (t & 15) * 8;
      const float* src = Bm + (size_t)(k0 + bk) * Nc + bn + bcol;
      float4 p0 = *(const float4*)src;
      float4 p1 = *(const float4*)(src + 4);
      *(float4*)&Bs[bk][bcol] = p0;
      *(float4*)&Bs[bk][bcol + 4] = p1;
    } else {
      const float* src = Bm + (size_t)(bn + lrow) * Kd + k0 + lseg;
      float4 p0 = *(const float4*)src;
      float4 p1 = *(const float4*)(src + 4);
      Bs[lseg + 0][lrow] = p0.x; Bs[lseg + 1][lrow] = p0.y;
      Bs[lseg + 2][lrow] = p0.z; Bs[lseg + 3][lrow] = p0.w;
      Bs[lseg + 4][lrow] = p1.x; Bs[lseg + 5][lrow] = p1.y;
      Bs[lseg + 6][lrow] = p1.z; Bs[lseg + 7][lrow] = p1.w;
    }
    __syncthreads();
#pragma unroll
    for (int kk = 0; kk < 16; ++kk) {
      float a0[8], b0[8];
#pragma unroll
      for (int q = 0; q < 8; ++q) a0[q] = As[kk][ty * 8 + q];
#pragma unroll
      for (int p = 0; p < 8; ++p) b0[p] = Bs[kk][tx * 8 + p];
#pragma unroll
      for (int q = 0; q < 8; ++q)
#pragma unroll
        for (int p = 0; p < 8; ++p) acc[q][p] += a0[q] * b0[p];
    }
    __syncthreads();
  }
  for (int q = 0; q < 8; ++q) {
    int r = bm + ty * 8 + q;
    float* Cr = C + (size_t)r * Nc + bn + tx * 8;
    const float* baser = base + (size_t)r * Nc + bn + tx * 8;
#pragma unroll
    for (int p = 0; p < 8; ++p) {
      float vv = acc[q][p];
      if (bias) vv += bias[bn + tx * 8 + p];
      if (act == 1) vv = fmaxf(vv, 0.f);
      if (addb) vv += baser[p];
      Cr[p] = vv;
    }
  }
}

__global__ __launch_bounds__(256) void rowln_kernel(const float* __restrict__ in,
                                                    const float* __restrict__ g,
                                                    const float* __restrict__ be,
                                                    float* __restrict__ out) {
  int r = blockIdx.x, t = threadIdx.x;
  __shared__ double s1[256], s2[256];
  const float* row = in + (size_t)r * 512;
  float v0 = row[t], v1 = row[t + 256];
  s1[t] = (double)v0 + (double)v1;
  s2[t] = (double)v0 * v0 + (double)v1 * v1;
  __syncthreads();
  for (int o = 128; o > 0; o >>= 1) { if (t < o) { s1[t] += s1[t + o]; s2[t] += s2[t + o]; } __syncthreads(); }
  double m = s1[0] / 512.0, var = s2[0] / 512.0 - m * m;
  float rstd = 1.0f / sqrtf((float)var + 1e-5f);
  float mf = (float)m;
  out[(size_t)r * 512 + t] = (v0 - mf) * rstd * g[t] + be[t];
  out[(size_t)r * 512 + t + 256] = (v1 - mf) * rstd * g[t + 256] + be[t + 256];
}

__global__ __launch_bounds__(256) void xnorm_kernel(float* kno) {
  int r = blockIdx.x, t = threadIdx.x;
  __shared__ double s1[256];
  float* row = kno + (size_t)r * 512;
  float v0 = row[t], v1 = row[t + 256];
  s1[t] = (double)v0 * v0 + (double)v1 * v1;
  __syncthreads();
  for (int o = 128; o > 0; o >>= 1) { if (t < o) s1[t] += s1[t + o]; __syncthreads(); }
  float nrm = fmaxf((float)sqrt(s1[0]), 1e-12f);
  row[t] = v0 / nrm; row[t + 256] = v1 / nrm;
}

__global__ __launch_bounds__(256) void cov_kernel(const float* __restrict__ xn, double* __restrict__ cov) {
  int b = blockIdx.x, it = blockIdx.y, jt = blockIdx.z;
  __shared__ float Xi[64][65], Xj[64][65];
  int t = threadIdx.x;
  int tx = t & 15, ty = t >> 4;
  double acc[4][4] = {};
  const float* xb = xn + (size_t)b * 131072;
  for (int f0 = 0; f0 < 512; f0 += 64) {
    for (int l = 0; l < 16; ++l) {
      int idx = t + l * 256;
      int r = idx >> 6, ff = idx & 63;
      Xi[r][ff] = xb[(size_t)(it * 64 + r) * 512 + f0 + ff];
      Xj[r][ff] = xb[(size_t)(jt * 64 + r) * 512 + f0 + ff];
    }
    __syncthreads();
    for (int ff = 0; ff < 64; ++ff) {
      double a0[4], b0[4];
#pragma unroll
      for (int q = 0; q < 4; ++q) { a0[q] = (double)Xi[ty * 4 + q][ff]; b0[q] = (double)Xj[tx * 4 + q][ff]; }
#pragma unroll
      for (int q = 0; q < 4; ++q)
#pragma unroll
        for (int p = 0; p < 4; ++p) acc[q][p] += a0[q] * b0[p];
    }
    __syncthreads();
  }
  double* cb = cov + (size_t)b * 65536;
  for (int q = 0; q < 4; ++q)
    for (int p = 0; p < 4; ++p)
      cb[(size_t)(it * 64 + ty * 4 + q) * 256 + jt * 64 + tx * 4 + p] = acc[q][p];
}

// Blocked Householder tridiagonalization (dlatrd-style, NB=32).
// Per reflector step: ONE pass over trailing matrix (matvec of panel-start A
// with V/W corrections) instead of three; rank-2NB trailing update once per
// panel as register-blocked GEMM. 1024 threads = 16 waves.
__global__ __launch_bounds__(1024) void dsytrd_kernel(double* Aall, double* dE, double* eE,
                                                      double* tauE, double* Vw, double* Ww) {
  int b = blockIdx.x, t = threadIdx.x;
  int lane = t & 63, wid = t >> 6;
  double* A = Aall + (size_t)b * 65536;
  double* V = Vw + (size_t)b * (VWROWS * TNB);
  double* W = Ww + (size_t)b * (VWROWS * TNB);
  __shared__ double v[256], w[256];
  __shared__ double redw[16];
  __shared__ double wvv[TNB], vvv[TNB];
  const int n = 256;
  for (int i0 = 0; i0 < n - 1; i0 += TNB) {
    int jend = (TNB < (n - 1) - i0) ? TNB : (n - 1) - i0;
    for (int j = 0; j < jend; ++j) {
      int i = i0 + j;
      // update column i (rows r >= i) with accumulated panel reflectors
      if (j > 0) {
        for (int r = i + t; r < n; r += 1024) {
          double acc = A[(size_t)r * 256 + i];
          const double* Vr = V + (size_t)r * TNB;
          const double* Wr = W + (size_t)r * TNB;
          const double* Vi = V + (size_t)i * TNB;
          const double* Wi = W + (size_t)i * TNB;
          for (int q = 0; q < j; ++q) acc -= Vr[q] * Wi[q] + Wr[q] * Vi[q];
          A[(size_t)r * 256 + i] = acc;
        }
        __syncthreads();
      }
      // column norm below subdiagonal
      double s = 0.0;
      for (int r = i + 2 + t; r < n; r += 1024) { double xv = A[(size_t)r * 256 + i]; s += xv * xv; }
      for (int o = 1; o < 64; o <<= 1) s += __shfl_xor(s, o);
      if (lane == 0) redw[wid] = s;
      __syncthreads();
      double xns = 0.0;
      for (int k = 0; k < 16; ++k) xns += redw[k];
      double alpha = A[(size_t)(i + 1) * 256 + i];
      double tau, beta, scl;
      if (xns == 0.0) { tau = 0.0; beta = alpha; scl = 0.0; }
      else {
        double xnorm = sqrt(xns);
        double rr = dlapy2d(alpha, xnorm);
        beta = (alpha >= 0.0) ? -rr : rr;
        tau = (beta - alpha) / beta;
        scl = 1.0 / (alpha - beta);
      }
      if (tau != 0.0) {
        // v setup; store V column j (zeros above i+1)
        for (int r = i0 + 1 + t; r < n; r += 1024) {
          double vr;
          if (r < i + 1) vr = 0.0;
          else if (r == i + 1) vr = 1.0;
          else vr = A[(size_t)r * 256 + i] * scl;
          if (r >= i + 1) v[r] = vr;
          if (r >= i + 2) A[(size_t)r * 256 + i] = vr;
          V[(size_t)r * TNB + j] = vr;
        }
        __syncthreads();
        // wv[q] = W(:,q).v, vv[q] = V(:,q).v for q<j
        if (j > 0) {
          for (int q = wid; q < j; q += 16) {
            double aw = 0.0, av = 0.0;
            for (int r = i + 1 + lane; r < n; r += 64) {
              double vr = v[r];
              aw += W[(size_t)r * TNB + q] * vr;
              av += V[(size_t)r * TNB + q] * vr;
            }
            for (int o = 1; o < 64; o <<= 1) { aw += __shfl_xor(aw, o); av += __shfl_xor(av, o); }
            if (lane == 0) { wvv[q] = aw; vvv[q] = av; }
          }
          __syncthreads();
        }
        // w_raw = A_ps * v - V*wv - W*vv (wave per row, corrections folded)
        for (int r = i + 1 + wid; r < n; r += 16) {
          const double* Ar = A + (size_t)r * 256;
          double acc = 0.0;
          for (int c = i + 1 + lane; c < n; c += 64) acc += Ar[c] * v[c];
          if (lane < j)
            acc -= V[(size_t)r * TNB + lane] * wvv[lane] + W[(size_t)r * TNB + lane] * vvv[lane];
          for (int o = 1; o < 64; o <<= 1) acc += __shfl_xor(acc, o);
          if (lane == 0) w[r] = tau * acc;
        }
        __syncthreads();
        // dot = w.v ; w += (-0.5 tau dot) v ; store W column j
        double sd = 0.0;
        for (int r = i + 1 + t; r < n; r += 1024) sd += w[r] * v[r];
        for (int o = 1; o < 64; o <<= 1) sd += __shfl_xor(sd, o);
        if (lane == 0) redw[wid] = sd;
        __syncthreads();
        double dot = 0.0;
        for (int k = 0; k < 16; ++k) dot += redw[k];
        double alpha2 = -0.5 * tau * dot;
        for (int r = i0 + 1 + t; r < n; r += 1024) {
          double wr = (r >= i + 1) ? (w[r] + alpha2 * v[r]) : 0.0;
          if (r >= i + 1) w[r] = wr;
          W[(size_t)r * TNB + j] = wr;
        }
        __syncthreads();
      } else {
        for (int r = i0 + 1 + t; r < n; r += 1024) {
          V[(size_t)r * TNB + j] = 0.0;
          W[(size_t)r * TNB + j] = 0.0;
        }
        __syncthreads();
      }
      if (t == 0) { eE[b * 256 + i] = beta; tauE[b * 256 + i] = tau; }
      __syncthreads();
    }
    // trailing update: A[rs.., rs..] -= V W^T + W V^T (wave: 4 rows; lanes: cols)
    int rs = i0 + jend;
    if (rs < n) {
      for (int r0 = rs + wid * 4; r0 < n; r0 += 64) {
        for (int c = rs + lane; c < n; c += 64) {
          double a0 = 0.0, a1 = 0.0, a2 = 0.0, a3 = 0.0;
          const double* Vc = V + (size_t)c * TNB;
          const double* Wc = W + (size_t)c * TNB;
          const double* Vr = V + (size_t)r0 * TNB;  // rows r0..r0+3 (padded alloc)
          const double* Wr = W + (size_t)r0 * TNB;
          for (int q = 0; q < jend; ++q) {
            double vc = Vc[q], wc = Wc[q];
            a0 += Vr[q] * wc + Wr[q] * vc;
            a1 += Vr[TNB + q] * wc + Wr[TNB + q] * vc;
            a2 += Vr[2 * TNB + q] * wc + Wr[2 * TNB + q] * vc;
            a3 += Vr[3 * TNB + q] * wc + Wr[3 * TNB + q] * vc;
          }
          A[(size_t)r0 * 256 + c] -= a0;
          if (r0 + 1 < n) A[(size_t)(r0 + 1) * 256 + c] -= a1;
          if (r0 + 2 < n) A[(size_t)(r0 + 2) * 256 + c] -= a2;
          if (r0 + 3 < n) A[(size_t)(r0 + 3) * 256 + c] -= a3;
        }
      }
      __syncthreads();
    }
  }
  for (int r = t; r < n; r += 1024) dE[b * 256 + r] = A[(size_t)r * 256 + r];
}

__global__ __launch_bounds__(64) void tear_kernel(double* dE, const double* eE) {
  int b = threadIdx.x;
  if (b >= 64) return;
  for (int m = 1; m < 16; ++m) {
    int p = m * 16 - 1;
    double ae = fabs(eE[b * 256 + p]);
    dE[b * 256 + p] -= ae;
    dE[b * 256 + p + 1] -= ae;
  }
}

// One leaf per thread; Z (16x16) + d/e in LDS, XOR-swizzled.
__global__ __launch_bounds__(64) void leaf_kernel(double* dE, double* eE, double* Qe, int* indxq) {
  __shared__ double Zs[LPB * 256];
  __shared__ double des[LPB * 33];
  int t = threadIdx.x;
  int g = blockIdx.x * LPB + t;
  if (t >= LPB || g >= 1024) return;
  int b = g >> 4, lf = g & 15, off = lf * 16;
  double* zz = Zs + t * 256;
  double* dd = des + t * 33;
  double* ee = dd + 16;
  int sw = t & 15;
  for (int i = 1; i <= 16; ++i) dd[i] = dE[b * 256 + off + i - 1];
  for (int i = 1; i <= 15; ++i) ee[i] = eE[b * 256 + off + i - 1];
  ee[16] = 0.0;
  dsteqr16_lds(dd, ee, zz, sw);
  for (int i = 1; i <= 16; ++i) dE[b * 256 + off + i - 1] = dd[i];
  double* Qb = Qe + (size_t)b * 65536;
  for (int r = 0; r < 16; ++r)
    for (int c = 0; c < 16; ++c) Qb[(size_t)(off + r) * 256 + off + c] = zz[((r << 4) + c) ^ sw];
  for (int i = 0; i < 16; ++i) indxq[b * 256 + off + i] = i + 1;
}

// dlaed2 deflation scan. Block per (b, merge): serial scan on thread 0 with
// all arrays in LDS; Givens rotations deferred to a list (scan never reads Q
// after z extraction) and applied block-parallel row-partitioned afterwards.
__global__ __launch_bounds__(256) void merge_scan_kernel(int nm, int nmerge, double* Qsrc, double* dE,
                                                         const double* eE, int* indxq,
                                                         double* dlamda_g, double* w_g, double* rho_g,
                                                         int* surv_g, int* defl_g, int* Kb) {
  int b = blockIdx.x, mg = blockIdx.y;
  int off = mg * nm, n1 = nm / 2, n2 = nm - n1;
  double* Q = Qsrc + (size_t)b * 65536;
  double* dg = dE + b * 256 + off;
  int* iqg = indxq + b * 256 + off;
  int t = threadIdx.x;

  __shared__ double dl[257], zl[257], dlamA[257], wl2[257];
  __shared__ int iq[257], indxc[257], indxl[257], indxpl[257];
  __shared__ double rotc[256], rots[256];
  __shared__ int rotp[256], rotn[256];
  __shared__ int sh_nrot, sh_K, sh_zero;

  for (int ii = 1 + t; ii <= nm; ii += 256) { dl[ii] = dg[ii - 1]; iq[ii] = iqg[ii - 1]; }
  __syncthreads();

  if (t == 0) {
    double rho = eE[b * 256 + off + n1 - 1];
    for (int j = 1; j <= n1; ++j) zl[j] = Q[(size_t)(off + n1 - 1) * 256 + off + j - 1];
    for (int j = 1; j <= n2; ++j) zl[n1 + j] = Q[(size_t)(off + n1) * 256 + off + n1 + j - 1];
    if (rho < 0.0)
      for (int j = n1 + 1; j <= nm; ++j) zl[j] = -zl[j];
    double tconst = 1.0 / sqrt(2.0);
    for (int j = 1; j <= nm; ++j) zl[j] *= tconst;
    rho = fabs(2.0 * rho);
    rho_g[b * nmerge + mg] = rho;
    for (int i = n1 + 1; i <= nm; ++i) iq[i] += n1;
    for (int i = 1; i <= nm; ++i) dlamA[i] = dl[iq[i]];
    dlamrg_dev(n1, n2, dlamA, 1, 1, indxc);
    for (int i = 1; i <= nm; ++i) indxl[i] = iq[indxc[i]];
    int imax = 1, jmax = 1;
    for (int i = 2; i <= nm; ++i) {
      if (fabs(zl[i]) > fabs(zl[imax])) imax = i;
      if (fabs(dl[i]) > fabs(dl[jmax])) jmax = i;
    }
    double tol = 8.0 * EPS_D * fmax(fabs(dl[jmax]), fabs(zl[imax]));
    if (rho * fabs(zl[imax]) <= tol) {
      sh_K = 0; sh_zero = 1; sh_nrot = 0;
    } else {
      sh_zero = 0;
      int nrot = 0;
      int K = 0, K2 = nm + 1, pj = 0, j = 1;
      bool havepj = false;
      for (j = 1; j <= nm; ++j) {
        int nj = indxl[j];
        if (rho * fabs(zl[nj]) <= tol) {
          K2--; indxpl[K2] = nj;
          if (j == nm) break;
        } else { pj = nj; havepj = true; break; }
      }
      if (havepj) {
        for (;;) {
          j = j + 1;
          if (j > nm) break;
          int nj = indxl[j];
          if (rho * fabs(zl[nj]) <= tol) { K2--; indxpl[K2] = nj; }
          else {
            double s_ = zl[pj], c_ = zl[nj];
            double tau_ = dlapy2d(c_, s_);
            double t_ = dl[nj] - dl[pj];
            c_ = c_ / tau_; s_ = -s_ / tau_;
            if (fabs(t_ * c_ * s_) <= tol) {
              zl[nj] = tau_; zl[pj] = 0.0;
              rotp[nrot] = pj; rotn[nrot] = nj; rotc[nrot] = c_; rots[nrot] = s_; ++nrot;
              double t2 = dl[pj] * c_ * c_ + dl[nj] * s_ * s_;
              dl[nj] = dl[pj] * s_ * s_ + dl[nj] * c_ * c_;
              dl[pj] = t2;
              K2--;
              int i_ = 1;
              for (;;) {
                if (K2 + i_ <= nm) {
                  if (dl[pj] < dl[indxpl[K2 + i_]]) {
                    indxpl[K2 + i_ - 1] = indxpl[K2 + i_];
                    indxpl[K2 + i_] = pj;
                    i_++;
                  } else { indxpl[K2 + i_ - 1] = pj; break; }
                } else { indxpl[K2 + i_ - 1] = pj; break; }
              }
              pj = nj;
            } else {
              K++; dlamA[K] = dl[pj]; wl2[K] = zl[pj]; indxpl[K] = pj; pj = nj;
            }
          }
        }
        K++; dlamA[K] = dl[pj]; wl2[K] = zl[pj]; indxpl[K] = pj;
      }
      sh_K = K; sh_nrot = nrot;
    }
  }
  __syncthreads();
  int nrot = sh_nrot, K = sh_K;
  // apply deferred rotations in order; rows partitioned across threads
  for (int r = t; r < nm; r += 256) {
    size_t rowb = (size_t)(off + r) * 256;
    for (int k = 0; k < nrot; ++k) {
      int cp = off + rotp[k] - 1, cn = off + rotn[k] - 1;
      double c_ = rotc[k], s_ = rots[k];
      double x = Q[rowb + cp], y = Q[rowb + cn];
      Q[rowb + cp] = c_ * x + s_ * y;
      Q[rowb + cn] = c_ * y - s_ * x;
    }
  }
  if (sh_zero) {
    if (t == 0) Kb[b * nmerge + mg] = 0;
    for (int j = 1 + t; j <= nm; j += 256) {
      int il = indxl[j];
      defl_g[b * 256 + off + j - 1] = il;
      dg[j - 1] = dl[il];
      iqg[j - 1] = j;
    }
  } else {
    if (t == 0) Kb[b * nmerge + mg] = K;
    for (int i = 1 + t; i <= K; i += 256) {
      dlamda_g[b * 256 + off + i - 1] = dlamA[i];
      w_g[b * 256 + off + i - 1] = wl2[i];
      surv_g[b * 256 + off + i - 1] = indxpl[i];
    }
    for (int jj = K + 1 + t; jj <= nm; jj += 256) {
      defl_g[b * 256 + off + jj - 1] = indxpl[jj];
      dg[jj - 1] = dl[indxpl[jj]];
    }
  }
}

// secular solver (dlaed4-equivalent, bisection)
__global__ __launch_bounds__(256) void secular_kernel(int nm, int nmerge, const double* dlamda_g,
                                                      const double* w_g, const double* rho_g,
                                                      const int* Kb, double* dE, double* tau_g,
                                                      int* orig_g) {
  int b = blockIdx.x, pos = threadIdx.x;
  int mg = pos / nm, jl = pos % nm + 1;
  int K = Kb[b * nmerge + mg];
  if (jl > K) return;
  int base = b * 256 + mg * nm;
  const double* dl = dlamda_g + base;
  const double* w = w_g + base;
  double rho = rho_g[b * nmerge + mg];
  int orig; double lo, hi;
  if (jl < K) {
    double dj = dl[jl - 1], dj1 = dl[jl];
    double mid = (dj + dj1) * 0.5;
    double acc = 0.0;
    for (int i = 0; i < K; ++i) acc += w[i] * w[i] / (dl[i] - mid);
    double fmid = 1.0 + rho * acc;
    if (fmid > 0.0) { orig = jl; lo = 0.0; hi = mid - dj; }
    else { orig = jl + 1; lo = mid - dj1; hi = 0.0; }
  } else {
    orig = K;
    double zs = 0.0;
    for (int i = 0; i < K; ++i) zs += w[i] * w[i];
    lo = 0.0; hi = rho * zs;
  }
  double dorig = dl[orig - 1];
  for (int it = 0; it < 100; ++it) {
    double tm = 0.5 * (lo + hi);
    if (tm == lo || tm == hi) break;
    double acc = 0.0;
    for (int i = 0; i < K; ++i) acc += w[i] * w[i] / ((dl[i] - dorig) - tm);
    double g = 1.0 + rho * acc;
    if (g > 0.0) hi = tm; else lo = tm;
  }
  double tau = 0.5 * (lo + hi);
  tau_g[base + jl - 1] = tau;
  orig_g[base + jl - 1] = orig;
  dE[base + jl - 1] = dorig + tau;
}

__global__ __launch_bounds__(256) void zhat_kernel(int nm, int nmerge, const double* dlamda_g,
                                                   const double* w_g, const double* tau_g,
                                                   const int* orig_g, const int* Kb, double* zhat_g) {
  int b = blockIdx.x, pos = threadIdx.x;
  int mg = pos / nm, il = pos % nm + 1;
  int K = Kb[b * nmerge + mg];
  if (il > K) return;
  int base = b * 256 + mg * nm;
  const double* dl = dlamda_g + base;
  double di = dl[il - 1];
  double p = (di - dl[orig_g[base + il - 1] - 1]) - tau_g[base + il - 1];
  for (int jj = 1; jj <= K; ++jj) {
    if (jj == il) continue;
    double del = (di - dl[orig_g[base + jj - 1] - 1]) - tau_g[base + jj - 1];
    p *= del / (di - dl[jj - 1]);
  }
  double val = sqrt(fmax(-p, 0.0));
  zhat_g[base + il - 1] = fsign(val, w_g[base + il - 1]);
}

__global__ __launch_bounds__(256) void coeff_kernel(int nm, int nmerge, const double* dlamda_g,
                                                    const double* zhat_g, const double* tau_g,
                                                    const int* orig_g, const int* Kb, double* Cbuf) {
  int b = blockIdx.x, pos = threadIdx.x;
  int mg = pos / nm, jl = pos % nm + 1;
  int K = Kb[b * nmerge + mg];
  if (jl > K) return;
  int off = mg * nm, base = b * 256 + off;
  double* C = Cbuf + (size_t)b * 65536;
  const double* dl = dlamda_g + base;
  if (K == 1) { C[(size_t)off * 256 + off + jl - 1] = 1.0; return; }
  double dorig = dl[orig_g[base + jl - 1] - 1];
  double tau = tau_g[base + jl - 1];
  double ss = 0.0;
  for (int i = 1; i <= K; ++i) {
    double del = (dl[i - 1] - dorig) - tau;
    double ci = zhat_g[base + i - 1] / del;
    C[(size_t)(off + i - 1) * 256 + off + jl - 1] = ci;
    ss += ci * ci;
  }
  double inv = 1.0 / sqrt(ss);
  for (int i = 1; i <= K; ++i) C[(size_t)(off + i - 1) * 256 + off + jl - 1] *= inv;
}

__global__ __launch_bounds__(64) void dlamrg_kernel(int nm, int nmerge, const double* dE,
                                                    const int* Kb, int* indxq) {
  int gid = blockIdx.x * 64 + threadIdx.x;
  if (gid >= 64 * nmerge) return;
  int b = gid / nmerge, mg = gid % nmerge;
  int off = mg * nm;
  int K = Kb[b * nmerge + mg];
  int* iqg = indxq + b * 256 + off;
  if (K == 0) return;  // identity already set by scan
  const double* dg = dE + b * 256 + off;
  int n1sv = K, n2sv = nm - K;
  int ind1 = 1, ind2 = nm;
  int i = 1;
  int idx[257];
  while (n1sv > 0 && n2sv > 0) {
    if (dg[ind1 - 1] <= dg[ind2 - 1]) { idx[i++] = ind1; ind1++; n1sv--; }
    else { idx[i++] = ind2; ind2--; n2sv--; }
  }
  if (n1sv == 0) { while (n2sv > 0) { idx[i++] = ind2; ind2--; n2sv--; } }
  else { while (n1sv > 0) { idx[i++] = ind1; ind1++; n1sv--; } }
  for (int t = 1; t <= nm; ++t) iqg[t - 1] = idx[t];
}

__global__ __launch_bounds__(256) void merge_gemm_kernel(int nm, int nmerge, const double* Qsrc,
                                                         const double* Cbuf, const int* surv_g,
                                                         const int* Kb, double* Qdst) {
  int b = blockIdx.x, mg = blockIdx.y;
  int tcnt = nm / 32;
  int rt = blockIdx.z / tcnt, ct = blockIdx.z % tcnt;
  int off = mg * nm;
  int K = Kb[b * nmerge + mg];
  if (ct * 32 >= K) return;
  __shared__ double Qs[32][33];
  __shared__ double Cs[32][33];
  __shared__ int svs[32];
  int t = threadIdx.x;
  int tc = t & 31, tr = t >> 5;
  const double* Qsb = Qsrc + (size_t)b * 65536;
  const double* Cb = Cbuf + (size_t)b * 65536;
  double acc[4] = {0, 0, 0, 0};
  int r0 = off + rt * 32, c0 = off + ct * 32;
  for (int i0 = 0; i0 < K; i0 += 32) {
    if (t < 32) svs[t] = (i0 + t < K) ? surv_g[b * 256 + off + i0 + t] : 0;
    __syncthreads();
    for (int l = 0; l < 4; ++l) {
      int idx = t + l * 256;
      int r = idx >> 5, ii = idx & 31;
      int sc = svs[ii];
      Qs[r][ii] = (sc > 0) ? Qsb[(size_t)(r0 + r) * 256 + off + sc - 1] : 0.0;
      Cs[r][ii] = (i0 + r < K && ct * 32 + ii < K) ? Cb[(size_t)(off + i0 + r) * 256 + c0 + ii] : 0.0;
    }
    __syncthreads();
    for (int ii = 0; ii < 32; ++ii) {
      double cv = Cs[ii][tc];
#pragma unroll
      for (int q = 0; q < 4; ++q) acc[q] += Qs[tr * 4 + q][ii] * cv;
    }
    __syncthreads();
  }
  if (ct * 32 + tc < K) {
    double* Qd = Qdst + (size_t)b * 65536;
    for (int q = 0; q < 4; ++q) Qd[(size_t)(r0 + tr * 4 + q) * 256 + c0 + tc] = acc[q];
  }
}

// deflated-column copy, row-parallel (each thread owns rows; loops columns)
__global__ __launch_bounds__(256) void defl_copy_kernel(int nm, int nmerge, const double* Qsrc,
                                                        const int* defl_g, const int* Kb,
                                                        double* Qdst) {
  int b = blockIdx.x, mg = blockIdx.y;
  int off = mg * nm;
  int K = Kb[b * nmerge + mg];
  int t = threadIdx.x;
  const double* Qs = Qsrc + (size_t)b * 65536;
  double* Qd = Qdst + (size_t)b * 65536;
  for (int r = t; r < nm; r += 256) {
    const double* Qsr = Qs + (size_t)(off + r) * 256;
    double* Qdr = Qd + (size_t)(off + r) * 256;
    for (int jl = K + 1; jl <= nm; ++jl)
      Qdr[off + jl - 1] = Qsr[off + defl_g[b * 256 + off + jl - 1] - 1];
  }
}

// gather ranks 2..9, apply Householder back-transform, emit E (f32, [b][s][n])
__global__ __launch_bounds__(256) void dormtr_kernel(const double* Aall, const double* tauE,
                                                     const double* Qe, const int* indxq, float* E) {
  int b = blockIdx.x, t = threadIdx.x;
  const double* A = Aall + (size_t)b * 65536;
  __shared__ double U[256][8];
  __shared__ double wred[32][8];
  __shared__ double wfin[8];
  __shared__ int sel[8];
  if (t < 8) sel[t] = indxq[b * 256 + 1 + t] - 1;
  __syncthreads();
  for (int i = t; i < 256 * 8; i += 256) {
    int r = i >> 3, c = i & 7;
    U[r][c] = Qe[(size_t)b * 65536 + (size_t)r * 256 + sel[c]];
  }
  __syncthreads();
  int lane = t & 31, col = t >> 5;
  for (int s = 254; s >= 0; --s) {
    double tv = tauE[b * 256 + s];
    if (tv == 0.0) continue;
    double acc = (lane == 0) ? U[s + 1][col] : 0.0;
    for (int r = s + 2 + lane; r < 256; r += 32) acc += A[(size_t)r * 256 + s] * U[r][col];
    wred[lane][col] = acc;
    __syncthreads();
    if (t < 8) { double a = 0.0; for (int l2 = 0; l2 < 32; ++l2) a += wred[l2][t]; wfin[t] = a; }
    __syncthreads();
    double wc = wfin[col] * tv;
    if (lane == 0) U[s + 1][col] -= wc;
    for (int r = s + 2 + lane; r < 256; r += 32) U[r][col] -= A[(size_t)r * 256 + s] * wc;
    __syncthreads();
  }
  for (int i = t; i < 8 * 256; i += 256) {
    int s = i >> 8, nn = i & 255;
    E[((size_t)b * 8 + s) * 256 + nn] = (float)U[nn][s];
  }
}

// z = E2 . fnp, coalesced streaming of fnp rows; per-output accumulation order
// identical to the previous column-wise version (ascending n) -> bit-identical.
__global__ __launch_bounds__(256) void zproj_kernel(const float* __restrict__ fnp,
                                                    const float* __restrict__ E2,
                                                    float* __restrict__ z) {
  int b = blockIdx.x, t = threadIdx.x;
  __shared__ float er[8][256];
  for (int i = t; i < 8 * 256; i += 256) er[i >> 8][i & 255] = E2[(size_t)b * 2048 + i];
  __syncthreads();
  for (int d0 = 0; d0 < 512; d0 += 256) {
    int d = d0 + t;
    float a0 = 0.f, a1 = 0.f, a2 = 0.f, a3 = 0.f, a4 = 0.f, a5 = 0.f, a6 = 0.f, a7 = 0.f;
    for (int n = 0; n < 256; ++n) {
      float f = fnp[((size_t)b * 256 + n) * 512 + d];
      a0 += er[0][n] * f; a1 += er[1][n] * f; a2 += er[2][n] * f; a3 += er[3][n] * f;
      a4 += er[4][n] * f; a5 += er[5][n] * f; a6 += er[6][n] * f; a7 += er[7][n] * f;
    }
    z[((size_t)b * 8 + 0) * 512 + d] = a0;
    z[((size_t)b * 8 + 1) * 512 + d] = a1;
    z[((size_t)b * 8 + 2) * 512 + d] = a2;
    z[((size_t)b * 8 + 3) * 512 + d] = a3;
    z[((size_t)b * 8 + 4) * 512 + d] = a4;
    z[((size_t)b * 8 + 5) * 512 + d] = a5;
    z[((size_t)b * 8 + 6) * 512 + d] = a6;
    z[((size_t)b * 8 + 7) * 512 + d] = a7;
  }
}

__global__ __launch_bounds__(64) void d2_kernel(const float* __restrict__ z,
                                                const float* __restrict__ ts, double* sdist,
                                                int* idxr) {
  int row = blockIdx.x;
  int lane = threadIdx.x;
  const float* zr = z + (size_t)row * 512;
  const float* tr = ts + (size_t)lane * 512;
  double zz = 0, zt = 0, tt = 0;
  for (int d = 0; d < 512; ++d) {
    double zv = zr[d], tv = tr[d];
    zz += zv * zv; zt += zv * tv; tt += tv * tv;
  }
  double d2 = zz + tt - 2.0 * zt;
  int best = lane; double bv = d2;
  for (int off = 32; off > 0; off >>= 1) {
    double ov = __shfl_down(bv, off);
    int oi = __shfl_down(best, off);
    if (ov < bv || (ov == bv && oi < best)) { bv = ov; best = oi; }
  }
  if (lane == 0) { sdist[row] = bv; idxr[row] = best; }
}

__global__ __launch_bounds__(64) void order_kernel(const double* sdist, const int* idxr, int* fidx,
                                                   float* out_idx) {
  int b = threadIdx.x;
  if (b >= 64) return;
  double sd[8]; int ord[8];
  for (int s = 0; s < 8; ++s) { sd[s] = sdist[b * 8 + s]; ord[s] = s; }
  for (int a = 1; a < 8; ++a) {
    double kv = sd[a]; int ko = ord[a]; int c = a - 1;
    while (c >= 0 && sd[c] > kv) { sd[c + 1] = sd[c]; ord[c + 1] = ord[c]; --c; }
    sd[c + 1] = kv; ord[c + 1] = ko;
  }
  for (int s = 0; s < 8; ++s) {
    int fi = idxr[ord[s]];  // cross-batch quirk: always batch 0's argmins
    fidx[b * 8 + s] = fi;
    out_idx[b * 8 + s] = (float)fi;
  }
}

__global__ __launch_bounds__(256) void slots0_kernel(const float* z, const float* emb,
                                                     const int* fidx, float* slots) {
  int i = blockIdx.x * 256 + threadIdx.x;
  if (i >= 512 * 512) return;
  int t = i / 512, d = i % 512;
  float zv = z[i];
  float zq = emb[fidx[t] * 512 + d];
  slots[i] = zv + (zq - zv);
}

__global__ __launch_bounds__(256) void qloss_kernel(const float* z, const float* ts, const int* fidx,
                                                    float* out) {
  __shared__ double red[256];
  int t = threadIdx.x;
  double acc = 0.0;
  for (int i = t; i < 512 * 512; i += 256) {
    int r = i / 512, d = i % 512;
    float diff = ts[fidx[r] * 512 + d] - z[i];
    acc += (double)diff * (double)diff;
  }
  red[t] = acc; __syncthreads();
  for (int o = 128; o > 0; o >>= 1) { if (t < o) red[t] += red[t + o]; __syncthreads(); }
  if (t == 0) {
    float a = (float)(red[0] / 64.0);
    out[0] = a + 0.99f * a;
  }
}

__global__ __launch_bounds__(256) void dots_kernel(const float* __restrict__ q,
                                                   const float* __restrict__ k,
                                                   float* __restrict__ dots) {
  int b = blockIdx.x, jt = blockIdx.y;
  __shared__ float qs[8][513];
  __shared__ float kc[64][33];
  int t = threadIdx.x;
  for (int i = t; i < 8 * 512; i += 256) qs[i / 512][i % 512] = q[((size_t)b * 8 + i / 512) * 512 + i % 512];
  int j = t % 64, ig = t / 64;
  float acc0 = 0.f, acc1 = 0.f;
  for (int d0 = 0; d0 < 512; d0 += 32) {
    __syncthreads();
    for (int l = 0; l < 8; ++l) {
      int idx = t + l * 256;
      int r = idx >> 5, dd = idx & 31;
      kc[r][dd] = k[((size_t)b * 256 + jt * 64 + r) * 512 + d0 + dd];
    }
    __syncthreads();
    for (int dd = 0; dd < 32; ++dd) {
      float kv = kc[j][dd];
      acc0 += qs[ig * 2][d0 + dd] * kv;
      acc1 += qs[ig * 2 + 1][d0 + dd] * kv;
    }
  }
  const float scale = (float)(1.0 / sqrt(512.0));
  dots[((size_t)b * 8 + ig * 2) * 256 + jt * 64 + j] = acc0 * scale;
  dots[((size_t)b * 8 + ig * 2 + 1) * 256 + jt * 64 + j] = acc1 * scale;
}

__global__ __launch_bounds__(256) void softmax_kernel(const float* dots, float* attn) {
  int b = blockIdx.x, j = threadIdx.x;
  float v[8]; float mx = -1e30f;
  for (int i = 0; i < 8; ++i) { v[i] = dots[((size_t)b * 8 + i) * 256 + j]; mx = fmaxf(mx, v[i]); }
  float s = 0.f;
  for (int i = 0; i < 8; ++i) { v[i] = expf(v[i] - mx); s += v[i]; }
  for (int i = 0; i < 8; ++i) attn[((size_t)b * 8 + i) * 256 + j] = v[i] / s;
}

__global__ __launch_bounds__(64) void asum_kernel(const float* attn, float* asum) {
  int bi = blockIdx.x, lane = threadIdx.x;
  float s = 0.f;
  for (int j = lane; j < 256; j += 64) s += attn[(size_t)bi * 256 + j] + 1e-8f;
  for (int off = 32; off > 0; off >>= 1) s += __shfl_down(s, off);
  if (lane == 0) asum[bi] = s;
}

__global__ __launch_bounds__(256) void updates_kernel(const float* attn, const float* asum,
                                                      const float* v, float* upd) {
  int b = blockIdx.x;
  __shared__ float at[8][257];
  int t = threadIdx.x;
  for (int i = t; i < 8 * 256; i += 256) {
    int ii = i / 256, j = i % 256;
    at[ii][j] = (attn[((size_t)b * 8 + ii) * 256 + j] + 1e-8f) / asum[b * 8 + ii];
  }
  __syncthreads();
  for (int d = t; d < 512; d += 256) {
    float acc[8] = {0, 0, 0, 0, 0, 0, 0, 0};
    for (int j = 0; j < 256; ++j) {
      float vv = v[((size_t)b * 256 + j) * 512 + d];
#pragma unroll
      for (int ii = 0; ii < 8; ++ii) acc[ii] += at[ii][j] * vv;
    }
    for (int ii = 0; ii < 8; ++ii) upd[((size_t)b * 8 + ii) * 512 + d] = acc[ii];
  }
}

__global__ __launch_bounds__(256) void gru_kernel(const float* gi, const float* gh, const float* h,
                                                  float* out) {
  int i = blockIdx.x * 256 + threadIdx.x;
  if (i >= 512 * 512) return;
  int t = i / 512, d = i % 512;
  const float* gir = gi + (size_t)t * 1536;
  const float* ghr = gh + (size_t)t * 1536;
  float r = 1.f / (1.f + expf(-(gir[d] + ghr[d])));
  float zg = 1.f / (1.f + expf(-(gir[512 + d] + ghr[512 + d])));
  float n = tanhf(gir[1024 + d] + r * ghr[1024 + d]);
  out[i] = (1.f - zg) * n + zg * h[i];
}

__global__ __launch_bounds__(64) void feats_kernel(const float* slots, const float* dposT,
                                                   float* out) {
  int blk = blockIdx.x;  // bs*512 + d
  int bs = blk >> 9, d = blk & 511;
  float s = slots[(size_t)bs * 512 + d];
  const float* dp = dposT + (size_t)d * 256;
  int n0 = threadIdx.x * 4;
  float4 o;
  o.x = s + dp[n0]; o.y = s + dp[n0 + 1]; o.z = s + dp[n0 + 2]; o.w = s + dp[n0 + 3];
  *(float4*)(out + (size_t)blk * 256 + n0) = o;
}

// ------------------------------ host driver --------------------------------

extern "C" void kernel_launch(void* const* d_in, const int* in_sizes, int n_in, void* d_out,
                              int out_size, void* d_ws, size_t ws_size, hipStream_t stream) {
  const float* x = (const float*)d_in[0];
  const float* enc_pos_w = (const float*)d_in[1];
  const float* enc_pos_b = (const float*)d_in[2];
  const float* enc_norm_g = (const float*)d_in[3];
  const float* enc_norm_b = (const float*)d_in[4];
  const float* enc_mlp_w1 = (const float*)d_in[5];
  const float* enc_mlp_b1 = (const float*)d_in[6];
  const float* enc_mlp_w2 = (const float*)d_in[7];
  const float* enc_mlp_b2 = (const float*)d_in[8];
  const float* anch_w1 = (const float*)d_in[9];
  const float* anch_b1 = (const float*)d_in[10];
  const float* anch_w2 = (const float*)d_in[11];
  const float* anch_b2 = (const float*)d_in[12];
  const float* wq = (const float*)d_in[13];
  const float* bq = (const float*)d_in[14];
  const float* wk = (const float*)d_in[15];
  const float* bk = (const float*)d_in[16];
  const float* wv = (const float*)d_in[17];
  const float* bv = (const float*)d_in[18];
  const float* gru_wih = (const float*)d_in[19];
  const float* gru_whh = (const float*)d_in[20];
  const float* gru_bih = (const float*)d_in[21];
  const float* gru_bhh = (const float*)d_in[22];
  const float* mlp_w1 = (const float*)d_in[23];
  const float* mlp_b1 = (const float*)d_in[24];
  const float* mlp_w2 = (const float*)d_in[25];
  const float* mlp_b2 = (const float*)d_in[26];
  const float* ni_g = (const float*)d_in[27];
  const float* ni_b = (const float*)d_in[28];
  const float* ns_g = (const float*)d_in[29];
  const float* ns_b = (const float*)d_in[30];
  const float* npf_g = (const float*)d_in[31];
  const float* npf_b = (const float*)d_in[32];
  const float* emb = (const float*)d_in[33];
  const float* dec_pos_w = (const float*)d_in[34];
  const float* dec_pos_b = (const float*)d_in[35];

  float* out = (float*)d_out;
  const size_t FEATS = (size_t)512 * 512 * 256;  // 67108864
  float* out_slots = out + FEATS;
  float* out_idx = out + FEATS + 262144;
  float* out_qloss = out + FEATS + 262144 + 512;

  // workspace layout
  char* ws = (char*)d_ws;
  size_t off = 0;
  auto alloc = [&](size_t bytes) { size_t o = off; off = (off + bytes + 255) & ~(size_t)255; return (void*)(ws + o); };
  const size_t S = (size_t)64 * 256 * 512 * 4;  // 33554432
  float* fnp = (float*)alloc(S);
  float* R2 = (float*)alloc(S);  // kno/xn -> V/W panels (dsytrd) -> Cbuf(f64)
  float* R3 = (float*)alloc(S);  // fpln -> later covA(f64)
  float* R4 = (float*)alloc(S);  // h1 -> later Qe(f64)
  float* R5 = (float*)alloc(S);  // fp -> later Q2(f64)
  float* kbuf = (float*)alloc(S);
  float* vbuf = (float*)alloc(S);
  float* posT = (float*)alloc(512 * 256 * 4);
  float* dposT = (float*)alloc(512 * 256 * 4);
  float* m1 = (float*)alloc(64 * 4);
  float* r1 = (float*)alloc(64 * 4);
  float* m2 = (float*)alloc(64 * 4);
  float* r2 = (float*)alloc(64 * 4);
  double* dE = (double*)alloc(64 * 256 * 8);
  double* eE = (double*)alloc(64 * 256 * 8);
  double* tauE = (double*)alloc(64 * 256 * 8);
  double* dlamda_g = (double*)alloc(64 * 256 * 8);
  double* w_g = (double*)alloc(64 * 256 * 8);
  double* zhat_g = (double*)alloc(64 * 256 * 8);
  double* tau_g = (double*)alloc(64 * 256 * 8);
  double* rho_g = (double*)alloc(64 * 8 * 8);
  int* indxq = (int*)alloc(64 * 256 * 4);
  int* surv_g = (int*)alloc(64 * 256 * 4);
  int* defl_g = (int*)alloc(64 * 256 * 4);
  int* orig_g = (int*)alloc(64 * 256 * 4);
  int* Kb = (int*)alloc(64 * 8 * 4);
  int* fidx = (int*)alloc(512 * 4);
  float* E = (float*)alloc(64 * 8 * 256 * 4);
  float* Eh = (float*)alloc(64 * 8 * 256 * 4);
  float* E2 = (float*)alloc(64 * 8 * 256 * 4);
  float* z = (float*)alloc(512 * 512 * 4);
  float* tslots = (float*)alloc(64 * 512 * 4);
  double* sdist = (double*)alloc(512 * 8);
  int* idxr = (int*)alloc(512 * 4);
  float* sA = (float*)alloc(512 * 512 * 4);
  float* sB = (float*)alloc(512 * 512 * 4);
  float* lnbuf = (float*)alloc(512 * 512 * 4);
  float* qbuf = (float*)alloc(512 * 512 * 4);
  float* dotsb = (float*)alloc(64 * 8 * 256 * 4);
  float* attnb = (float*)alloc(64 * 8 * 256 * 4);
  float* asumb = (float*)alloc(64 * 8 * 4);
  float* updb = (float*)alloc(512 * 512 * 4);
  float* gib = (float*)alloc((size_t)512 * 1536 * 4);
  float* ghb = (float*)alloc((size_t)512 * 1536 * 4);
  float* hidb = (float*)alloc(512 * 512 * 4);
  (void)ws_size; (void)in_sizes; (void)n_in; (void)out_size;

  auto gemm = [&](const float* A, const float* Bm, const float* bias, const float* base, float* C,
                  int M, int Nc, int Kd, int bt, int act, int addb) {
    if ((M % 128) == 0 && (Nc % 128) == 0 && (Kd % 16) == 0) {
      dim3 g(M / 128, Nc / 128);
      gemm_f32_big<<<g, 256, 0, stream>>>(A, Bm, bias, base, C, M, Nc, Kd, bt, act, addb);
    } else {
      dim3 g((M + 63) / 64, (Nc + 63) / 64);
      gemm_f32<<<g, 256, 0, stream>>>(A, Bm, bias, base, C, M, Nc, Kd, bt, act, addb);
    }
  };

  // positional embeddings (transposed [d][n])
  pos_kernel<<<(131072 + 255) / 256, 256, 0, stream>>>(enc_pos_w, enc_pos_b, posT);
  pos_kernel<<<(131072 + 255) / 256, 256, 0, stream>>>(dec_pos_w, dec_pos_b, dposT);
  // batch LN stats over (N,D)
  stats_kernel<<<64, 256, 0, stream>>>(x, posT, m1, r1, 0);
  stats_kernel<<<64, 256, 0, stream>>>(x, posT, m2, r2, 1);
  // transpose + LN -> fnp, fpln
  tln_kernel<<<dim3(64, 16, 8), 256, 0, stream>>>(x, posT, enc_norm_g, enc_norm_b, m1, r1, m2, r2,
                                                  fnp, R3);
  // k_nopos
  gemm(fnp, wk, bk, nullptr, R2, 16384, 512, 512, 0, 0, 0);
  // encoder MLP + ni LN -> fp (R5)
  gemm(R3, enc_mlp_w1, enc_mlp_b1, nullptr, R4, 16384, 512, 512, 0, 1, 0);
  gemm(R4, enc_mlp_w2, enc_mlp_b2, nullptr, R5, 16384, 512, 512, 0, 0, 0);
  rowln_kernel<<<16384, 256, 0, stream>>>(R5, ni_g, ni_b, R5);
  gemm(R5, wk, bk, nullptr, kbuf, 16384, 512, 512, 0, 0, 0);
  gemm(R5, wv, bv, nullptr, vbuf, 16384, 512, 512, 0, 0, 0);
  // xn + cov (f64) into R3 region
  xnorm_kernel<<<16384, 256, 0, stream>>>(R2);
  double* covA = (double*)R3;
  cov_kernel<<<dim3(64, 4, 4), 256, 0, stream>>>(R2, covA);
  // eigensolver buffers
  double* Qe = (double*)R4;
  double* Q2 = (double*)R5;
  double* Cbuf = (double*)R2;
  double* Vw = (double*)R2;  // V/W panels live in R2 during dsytrd (before Cbuf use)
  double* Ww = Vw + (size_t)64 * VWROWS * TNB;
  hipMemsetAsync(Qe, 0, S, stream);
  hipMemsetAsync(Q2, 0, S, stream);
  dsytrd_kernel<<<64, 1024, 0, stream>>>(covA, dE, eE, tauE, Vw, Ww);
  tear_kernel<<<1, 64, 0, stream>>>(dE, eE);
  leaf_kernel<<<(1024 + LPB - 1) / LPB, LPB, 0, stream>>>(dE, eE, Qe, indxq);
  for (int L = 0; L < 4; ++L) {
    int nm = 32 << L;
    int nmerge = 256 / nm;
    double* src = (L % 2 == 0) ? Qe : Q2;
    double* dst = (L % 2 == 0) ? Q2 : Qe;
    int gScan = (64 * nmerge + 63) / 64;
    merge_scan_kernel<<<dim3(64, nmerge), 256, 0, stream>>>(nm, nmerge, src, dE, eE, indxq,
                                                            dlamda_g, w_g, rho_g, surv_g, defl_g, Kb);
    secular_kernel<<<64, 256, 0, stream>>>(nm, nmerge, dlamda_g, w_g, rho_g, Kb, dE, tau_g, orig_g);
    zhat_kernel<<<64, 256, 0, stream>>>(nm, nmerge, dlamda_g, w_g, tau_g, orig_g, Kb, zhat_g);
    coeff_kernel<<<64, 256, 0, stream>>>(nm, nmerge, dlamda_g, zhat_g, tau_g, orig_g, Kb, Cbuf);
    int tcnt = nm / 32;
    merge_gemm_kernel<<<dim3(64, nmerge, tcnt * tcnt), 256, 0, stream>>>(nm, nmerge, src, Cbuf,
                                                                         surv_g, Kb, dst);
    defl_copy_kernel<<<dim3(64, nmerge), 256, 0, stream>>>(nm, nmerge, src, defl_g, Kb, dst);
    dlamrg_kernel<<<gScan, 64, 0, stream>>>(nm, nmerge, dE, Kb, indxq);
  }
  // final eigvecs in Qe; back-transform ranks 2..9 -> E
  dormtr_kernel<<<64, 256, 0, stream>>>(covA, tauE, Qe, indxq, E);
  // anchor MLP
  gemm(E, anch_w1, anch_b1, nullptr, Eh, 512, 256, 256, 0, 1, 0);
  gemm(Eh, anch_w2, anch_b2, nullptr, E2, 512, 256, 256, 0, 0, 0);
  // z projection
  zproj_kernel<<<64, 256, 0, stream>>>(fnp, E2, z);
  // template slots + quantization
  gemm(emb, wq, bq, nullptr, tslots, 64, 512, 512, 0, 0, 0);
  d2_kernel<<<512, 64, 0, stream>>>(z, tslots, sdist, idxr);
  order_kernel<<<1, 64, 0, stream>>>(sdist, idxr, fidx, out_idx);
  slots0_kernel<<<1024, 256, 0, stream>>>(z, emb, fidx, sA);
  qloss_kernel<<<1, 256, 0, stream>>>(z, tslots, fidx, out_qloss);
  // slot attention iterations
  for (int it = 0; it < 3; ++it) {
    rowln_kernel<<<512, 256, 0, stream>>>(sA, ns_g, ns_b, lnbuf);
    gemm(lnbuf, wq, bq, nullptr, qbuf, 512, 512, 512, 0, 0, 0);
    dots_kernel<<<dim3(64, 4), 256, 0, stream>>>(qbuf, kbuf, dotsb);
    softmax_kernel<<<64, 256, 0, stream>>>(dotsb, attnb);
    asum_kernel<<<512, 64, 0, stream>>>(attnb, asumb);
    updates_kernel<<<64, 256, 0, stream>>>(attnb, asumb, vbuf, updb);
    gemm(updb, gru_wih, gru_bih, nullptr, gib, 512, 1536, 512, 1, 0, 0);
    gemm(sA, gru_whh, gru_bhh, nullptr, ghb, 512, 1536, 512, 1, 0, 0);
    gru_kernel<<<1024, 256, 0, stream>>>(gib, ghb, sA, sB);
    rowln_kernel<<<512, 256, 0, stream>>>(sB, npf_g, npf_b, lnbuf);
    gemm(lnbuf, mlp_w1, mlp_b1, nullptr, hidb, 512, 512, 512, 0, 1, 0);
    gemm(hidb, mlp_w2, mlp_b2, sB, sA, 512, 512, 512, 0, 0, 1);
  }
  // outputs
  feats_kernel<<<262144, 64, 0, stream>>>(sA, dposT, out);
  hipMemcpyAsync(out_slots, sA, 262144 * 4, hipMemcpyDeviceToDevice, stream);
}

// Round 5
// 14240.517 us; speedup vs baseline: 1.2691x; 1.2691x over previous
//
#include <hip/hip_runtime.h>
#include <math.h>
#include <stdint.h>

// ---------------------------------------------------------------------------
// SlotAttention forward. Correctness-first implementation.
// Core difficulty: replicate LAPACK dsyevd (numpy eigh) including eigenvector
// SIGN conventions: dsytd2 + D&C (tear -> dsteqr(16) leaves -> dlaed1/2/3
// merges) + reflector back-transform of the 8 needed columns. All f64.
// R1: leaf_kernel arrays scratch->LDS (swizzled) + fused rotation apply.
// R2: dsytrd wave-parallel matvec/rank-2; 128x128 f32 GEMM (bit-identical k).
// R3: merge_scan block-per-merge LDS + deferred rotations; zproj coalesced.
// R4: (blocked dlatrd in big LDS -> FAILED subtle; reverted)
// R5: fused-lazy dsytrd: defer rank-2, apply during next step's matvec pass.
//     Same per-element expressions + same reduction mappings as R2 ->
//     bit-identical to the R2 kernel that passed. One full-matrix R+W pass
//     per step instead of matvec-read + rank2-R/W.
// ---------------------------------------------------------------------------

#define NB 64
#define ND 512
#define NN_ 256
#define NSL 8
#define LPB 24  // leaves per block in leaf_kernel; LDS = 24*(256+33)*8 = 55.5KB

static __device__ __forceinline__ double fsign(double a, double b) {
  return (b >= 0.0) ? fabs(a) : -fabs(a);
}
static __device__ __forceinline__ double dlapy2d(double x, double y) {
  double ax = fabs(x), ay = fabs(y);
  double w = ax > ay ? ax : ay, z = ax > ay ? ay : ax;
  if (z == 0.0) return w;
  double q = z / w;
  return w * sqrt(1.0 + q * q);
}
#define EPS_D 1.1102230246251565e-16

// LAPACK >= 3.10 dlartg convention (modern numpy/OpenBLAS)
static __device__ void dlartgd(double f, double g, double& cs, double& sn, double& r) {
  if (g == 0.0) { cs = 1.0; sn = 0.0; r = f; }
  else if (f == 0.0) { cs = 0.0; sn = fsign(1.0, g); r = fabs(g); }
  else {
    double f1 = fabs(f);
    double d = sqrt(f * f + g * g);
    cs = f1 / d;
    r = fsign(d, f);
    sn = g / r;
  }
}

static __device__ void dlaev2d(double a, double b, double c, double& rt1, double& rt2,
                               double& cs1, double& sn1) {
  double sm = a + c, df = a - c, adf = fabs(df), tb = b + b, ab = fabs(tb);
  double acmx, acmn;
  if (fabs(a) > fabs(c)) { acmx = a; acmn = c; } else { acmx = c; acmn = a; }
  double rt;
  if (adf > ab) { double q = ab / adf; rt = adf * sqrt(1.0 + q * q); }
  else if (adf < ab) { double q = adf / ab; rt = ab * sqrt(1.0 + q * q); }
  else rt = ab * sqrt(2.0);
  int sgn1;
  if (sm < 0.0) { rt1 = 0.5 * (sm - rt); sgn1 = -1; rt2 = (acmx / rt1) * acmn - (b / rt1) * b; }
  else if (sm > 0.0) { rt1 = 0.5 * (sm + rt); sgn1 = 1; rt2 = (acmx / rt1) * acmn - (b / rt1) * b; }
  else { rt1 = 0.5 * rt; rt2 = -0.5 * rt; sgn1 = 1; }
  double cs; int sgn2;
  if (df >= 0.0) { cs = df + rt; sgn2 = 1; } else { cs = df - rt; sgn2 = -1; }
  double acs = fabs(cs);
  if (acs > ab) { double ct = -tb / cs; sn1 = 1.0 / sqrt(1.0 + ct * ct); cs1 = ct * sn1; }
  else {
    if (ab == 0.0) { cs1 = 1.0; sn1 = 0.0; }
    else { double tn = -cs / tb; cs1 = 1.0 / sqrt(1.0 + tn * tn); sn1 = tn * cs1; }
  }
  if (sgn1 == sgn2) { double tn = cs1; cs1 = -sn1; sn1 = tn; }
}

// dsteqr COMPZ='I', n=16, faithful port (1-based d[1..16], e[1..15]).
// Arrays in LDS; Z XOR-swizzled; rotation apply fused (identical order).
static __device__ void dsteqr16_lds(double* dd, double* ee, double* zz, int sw) {
  const int n = 16;
#define ZM(i, j) zz[((((i)-1) << 4) + ((j)-1)) ^ sw]
#define D_(i) dd[(i)]
#define E_(i) ee[(i)]
  for (int i = 1; i <= n; ++i)
    for (int j = 1; j <= n; ++j) ZM(i, j) = (i == j) ? 1.0 : 0.0;
  const double eps = EPS_D, eps2 = eps * eps, safmin = 2.2250738585072014e-308;
  int nmaxit = n * 30, jtot = 0, l1 = 1;
  while (l1 <= n) {
    if (l1 > 1) E_(l1 - 1) = 0.0;
    int m = n;
    for (int mm = l1; mm <= n - 1; ++mm) {
      double tst = fabs(E_(mm));
      if (tst == 0.0) { m = mm; break; }
      if (tst <= (sqrt(fabs(D_(mm))) * sqrt(fabs(D_(mm + 1)))) * eps) { E_(mm) = 0.0; m = mm; break; }
    }
    int l = l1, lsv = l, lend = m, lendsv = m;
    l1 = m + 1;
    if (lend == l) continue;
    double anorm = 0.0;
    for (int i = l; i <= lend; ++i) anorm = fmax(anorm, fabs(D_(i)));
    for (int i = l; i <= lend - 1; ++i) anorm = fmax(anorm, fabs(E_(i)));
    if (anorm == 0.0) continue;
    if (fabs(D_(lend)) < fabs(D_(l))) { lend = lsv; l = lendsv; }
    if (lend > l) {  // QL
      for (;;) {
        int m2 = lend;
        if (l != lend) {
          for (int mm = l; mm <= lend - 1; ++mm) {
            double tst = E_(mm) * E_(mm);
            if (tst <= (eps2 * fabs(D_(mm))) * fabs(D_(mm + 1)) + safmin) { m2 = mm; break; }
          }
        }
        if (m2 < lend) E_(m2) = 0.0;
        double p = D_(l);
        if (m2 == l) { D_(l) = p; ++l; if (l > lend) break; continue; }
        if (m2 == l + 1) {
          double rt1, rt2, c, s;
          dlaev2d(D_(l), E_(l), D_(l + 1), rt1, rt2, c, s);
          for (int i = 1; i <= n; ++i) {
            double tmp = ZM(i, l + 1);
            ZM(i, l + 1) = c * tmp - s * ZM(i, l);
            ZM(i, l) = s * tmp + c * ZM(i, l);
          }
          D_(l) = rt1; D_(l + 1) = rt2; E_(l) = 0.0;
          l += 2; if (l > lend) break; continue;
        }
        if (jtot == nmaxit) break;
        ++jtot;
        double g = (D_(l + 1) - p) / (2.0 * E_(l));
        double r = dlapy2d(g, 1.0);
        g = D_(m2) - p + E_(l) / (g + fsign(r, g));
        double s = 1.0, c = 1.0; p = 0.0;
        for (int i = m2 - 1; i >= l; --i) {
          double f = s * E_(i), bb = c * E_(i);
          dlartgd(g, f, c, s, r);
          if (i != m2 - 1) E_(i + 1) = r;
          g = D_(i + 1) - p;
          r = (D_(i) - g) * s + 2.0 * c * bb;
          p = s * r;
          D_(i + 1) = g + p;
          g = c * r - bb;
          double cj = c, sj = -s;
          for (int i2 = 1; i2 <= n; ++i2) {
            double tmp = ZM(i2, i + 1);
            ZM(i2, i + 1) = cj * tmp - sj * ZM(i2, i);
            ZM(i2, i) = sj * tmp + cj * ZM(i2, i);
          }
        }
        D_(l) -= p; E_(l) = g;
      }
    } else {  // QR
      for (;;) {
        int m2 = lend;
        if (l != lend) {
          for (int mm = l; mm >= lend + 1; --mm) {
            double tst = E_(mm - 1) * E_(mm - 1);
            if (tst <= (eps2 * fabs(D_(mm))) * fabs(D_(mm - 1)) + safmin) { m2 = mm; break; }
          }
        }
        if (m2 > lend) E_(m2 - 1) = 0.0;
        double p = D_(l);
        if (m2 == l) { D_(l) = p; --l; if (l < lend) break; continue; }
        if (m2 == l - 1) {
          double rt1, rt2, c, s;
          dlaev2d(D_(l - 1), E_(l - 1), D_(l), rt1, rt2, c, s);
          for (int i = 1; i <= n; ++i) {
            double tmp = ZM(i, l);
            ZM(i, l) = c * tmp - s * ZM(i, l - 1);
            ZM(i, l - 1) = s * tmp + c * ZM(i, l - 1);
          }
          D_(l - 1) = rt1; D_(l) = rt2; E_(l - 1) = 0.0;
          l -= 2; if (l < lend) break; continue;
        }
        if (jtot == nmaxit) break;
        ++jtot;
        double g = (D_(l - 1) - p) / (2.0 * E_(l - 1));
        double r = dlapy2d(g, 1.0);
        g = D_(m2) - p + E_(l - 1) / (g + fsign(r, g));
        double s = 1.0, c = 1.0; p = 0.0;
        for (int i = m2; i <= l - 1; ++i) {
          double f = s * E_(i), bb = c * E_(i);
          dlartgd(g, f, c, s, r);
          if (i != m2) E_(i - 1) = r;
          g = D_(i) - p;
          r = (D_(i + 1) - g) * s + 2.0 * c * bb;
          p = s * r;
          D_(i) = g + p;
          g = c * r - bb;
          double cj = c, sj = s;
          for (int i2 = 1; i2 <= n; ++i2) {
            double tmp = ZM(i2, i + 1);
            ZM(i2, i + 1) = cj * tmp - sj * ZM(i2, i);
            ZM(i2, i) = sj * tmp + cj * ZM(i2, i);
          }
        }
        D_(l) -= p; E_(l - 1) = g;
      }
    }
  }
  for (int ii = 2; ii <= n; ++ii) {
    int i = ii - 1, k = i;
    double p = D_(i);
    for (int j = ii; j <= n; ++j)
      if (D_(j) < p) { k = j; p = D_(j); }
    if (k != i) {
      D_(k) = D_(i); D_(i) = p;
      for (int r = 1; r <= n; ++r) { double t = ZM(r, i); ZM(r, i) = ZM(r, k); ZM(r, k) = t; }
    }
  }
#undef ZM
#undef D_
#undef E_
}

static __device__ void dlamrg_dev(int n1v, int n2v, const double* a, int strd1, int strd2, int* index) {
  int n1sv = n1v, n2sv = n2v;
  int ind1 = (strd1 > 0) ? 1 : n1v;
  int ind2 = (strd2 > 0) ? n1v + 1 : n1v + n2v;
  int i = 1;
  while (n1sv > 0 && n2sv > 0) {
    if (a[ind1] <= a[ind2]) { index[i++] = ind1; ind1 += strd1; --n1sv; }
    else { index[i++] = ind2; ind2 += strd2; --n2sv; }
  }
  if (n1sv == 0) { while (n2sv > 0) { index[i++] = ind2; ind2 += strd2; --n2sv; } }
  else { while (n1sv > 0) { index[i++] = ind1; ind1 += strd1; --n1sv; } }
}

// -------------------------------- kernels ----------------------------------

__global__ __launch_bounds__(256) void pos_kernel(const float* __restrict__ w,
                                                  const float* __restrict__ bias,
                                                  float* __restrict__ posT) {
  int idx = blockIdx.x * 256 + threadIdx.x;
  if (idx >= 512 * 256) return;
  int d = idx / 256, n = idx % 256;
  int i = n / 16, j = n % 16;
  double step = 1.0 / 15.0;
  float gi = (i == 15) ? 1.0f : (float)(i * step);
  float gj = (j == 15) ? 1.0f : (float)(j * step);
  float v = gi * w[0 * 512 + d] + gj * w[1 * 512 + d] + (1.0f - gi) * w[2 * 512 + d] +
            (1.0f - gj) * w[3 * 512 + d] + bias[d];
  posT[(size_t)d * 256 + n] = v;
}

__global__ __launch_bounds__(256) void stats_kernel(const float* __restrict__ x,
                                                    const float* __restrict__ posT,
                                                    float* mean_o, float* rstd_o, int addpos) {
  int b = blockIdx.x, t = threadIdx.x;
  __shared__ double r1[256], r2[256];
  double s = 0.0, ss = 0.0;
  const float* xb = x + (size_t)b * 131072;
  for (int i = t; i < 131072; i += 256) {
    float v = xb[i];
    if (addpos) v += posT[i];
    s += v; ss += (double)v * v;
  }
  r1[t] = s; r2[t] = ss; __syncthreads();
  for (int o = 128; o > 0; o >>= 1) { if (t < o) { r1[t] += r1[t + o]; r2[t] += r2[t + o]; } __syncthreads(); }
  if (t == 0) {
    double m = r1[0] / 131072.0;
    double var = r2[0] / 131072.0 - m * m;
    mean_o[b] = (float)m;
    rstd_o[b] = 1.0f / sqrtf((float)var + 1e-5f);
  }
}

__global__ __launch_bounds__(256) void tln_kernel(const float* __restrict__ x,
                                                  const float* __restrict__ posT,
                                                  const float* __restrict__ g,
                                                  const float* __restrict__ be,
                                                  const float* m1, const float* r1,
                                                  const float* m2, const float* r2,
                                                  float* __restrict__ fnp,
                                                  float* __restrict__ fpln) {
  int b = blockIdx.x, dt = blockIdx.y, nt = blockIdx.z;
  __shared__ float t1[32][33], t2[32][33];
  int t = threadIdx.x;
  const float* xb = x + (size_t)b * 131072;
  for (int l = 0; l < 4; ++l) {
    int idx = t + l * 256;
    int row = idx >> 5, col = idx & 31;
    int dd = dt * 32 + row, nn = nt * 32 + col;
    float v = xb[(size_t)dd * 256 + nn];
    t1[row][col] = v;
    t2[row][col] = v + posT[(size_t)dd * 256 + nn];
  }
  __syncthreads();
  float mm1 = m1[b], rr1 = r1[b], mm2 = m2[b], rr2 = r2[b];
  for (int l = 0; l < 4; ++l) {
    int idx = t + l * 256;
    int row = idx >> 5, col = idx & 31;
    int nn = nt * 32 + row, dd = dt * 32 + col;
    float gg = g[(size_t)nn * 512 + dd], bb = be[(size_t)nn * 512 + dd];
    size_t o = (size_t)b * 131072 + (size_t)nn * 512 + dd;
    fnp[o] = (t1[col][row] - mm1) * rr1 * gg + bb;
    fpln[o] = (t2[col][row] - mm2) * rr2 * gg + bb;
  }
}

__global__ __launch_bounds__(256) void gemm_f32(const float* __restrict__ A,
                                                const float* __restrict__ Bm,
                                                const float* __restrict__ bias,
                                                const float* __restrict__ base,
                                                float* __restrict__ C, int M, int Nc, int Kd,
                                                int bt, int act, int addb) {
  __shared__ float As[16][65];
  __shared__ float Bs[16][65];
  int bm = blockIdx.x * 64, bn = blockIdx.y * 64;
  int t = threadIdx.x;
  int tx = t & 15, ty = t >> 4;
  float acc[4][4] = {};
  for (int k0 = 0; k0 < Kd; k0 += 16) {
    for (int l = 0; l < 4; ++l) {
      int idx = t + l * 256;
      { int r = idx >> 4, kk = idx & 15;
        float v = 0.f;
        if (bm + r < M && k0 + kk < Kd) v = A[(size_t)(bm + r) * Kd + k0 + kk];
        As[kk][r] = v; }
      if (bt == 0) {
        int kk = idx >> 6, nn = idx & 63;
        float v = 0.f;
        if (k0 + kk < Kd && bn + nn < Nc) v = Bm[(size_t)(k0 + kk) * Nc + bn + nn];
        Bs[kk][nn] = v;
      } else {
        int nn = idx >> 4, kk = idx & 15;
        float v = 0.f;
        if (bn + nn < Nc && k0 + kk < Kd) v = Bm[(size_t)(bn + nn) * Kd + k0 + kk];
        Bs[kk][nn] = v;
      }
    }
    __syncthreads();
#pragma unroll
    for (int kk = 0; kk < 16; ++kk) {
      float a0[4], b0[4];
#pragma unroll
      for (int q = 0; q < 4; ++q) a0[q] = As[kk][ty * 4 + q];
#pragma unroll
      for (int q = 0; q < 4; ++q) b0[q] = Bs[kk][tx * 4 + q];
#pragma unroll
      for (int q = 0; q < 4; ++q)
#pragma unroll
        for (int p = 0; p < 4; ++p) acc[q][p] += a0[q] * b0[p];
    }
    __syncthreads();
  }
  for (int q = 0; q < 4; ++q) {
    int r = bm + ty * 4 + q;
    if (r >= M) continue;
    for (int p = 0; p < 4; ++p) {
      int c = bn + tx * 4 + p;
      if (c >= Nc) continue;
      float v = acc[q][p];
      if (bias) v += bias[c];
      if (act == 1) v = fmaxf(v, 0.f);
      if (addb) v += base[(size_t)r * Nc + c];
      C[(size_t)r * Nc + c] = v;
    }
  }
}

// 128x128 tile, 8x8 acc/thread. M%128==0, Nc%128==0, Kd%16==0.
__global__ __launch_bounds__(256) void gemm_f32_big(const float* __restrict__ A,
                                                    const float* __restrict__ Bm,
                                                    const float* __restrict__ bias,
                                                    const float* __restrict__ base,
                                                    float* __restrict__ C, int M, int Nc, int Kd,
                                                    int bt, int act, int addb) {
  __shared__ float As[16][128];
  __shared__ float Bs[16][128];
  int bm = blockIdx.x * 128, bn = blockIdx.y * 128;
  int t = threadIdx.x;
  int tx = t & 15, ty = t >> 4;
  int lrow = t >> 1, lseg = (t & 1) * 8;
  float acc[8][8] = {};
  for (int k0 = 0; k0 < Kd; k0 += 16) {
    {
      const float* src = A + (size_t)(bm + lrow) * Kd + k0 + lseg;
      float4 p0 = *(const float4*)src;
      float4 p1 = *(const float4*)(src + 4);
      As[lseg + 0][lrow] = p0.x; As[lseg + 1][lrow] = p0.y;
      As[lseg + 2][lrow] = p0.z; As[lseg + 3][lrow] = p0.w;
      As[lseg + 4][lrow] = p1.x; As[lseg + 5][lrow] = p1.y;
      As[lseg + 6][lrow] = p1.z; As[lseg + 7][lrow] = p1.w;
    }
    if (bt == 0) {
      int bk = t >> 4, bcol = (t & 15) * 8;
      const float* src = Bm + (size_t)(k0 + bk) * Nc + bn + bcol;
      float4 p0 = *(const float4*)src;
      float4 p1 = *(const float4*)(src + 4);
      *(float4*)&Bs[bk][bcol] = p0;
      *(float4*)&Bs[bk][bcol + 4] = p1;
    } else {
      const float* src = Bm + (size_t)(bn + lrow) * Kd + k0 + lseg;
      float4 p0 = *(const float4*)src;
      float4 p1 = *(const float4*)(src + 4);
      Bs[lseg + 0][lrow] = p0.x; Bs[lseg + 1][lrow] = p0.y;
      Bs[lseg + 2][lrow] = p0.z; Bs[lseg + 3][lrow] = p0.w;
      Bs[lseg + 4][lrow] = p1.x; Bs[lseg + 5][lrow] = p1.y;
      Bs[lseg + 6][lrow] = p1.z; Bs[lseg + 7][lrow] = p1.w;
    }
    __syncthreads();
#pragma unroll
    for (int kk = 0; kk < 16; ++kk) {
      float a0[8], b0[8];
#pragma unroll
      for (int q = 0; q < 8; ++q) a0[q] = As[kk][ty * 8 + q];
#pragma unroll
      for (int p = 0; p < 8; ++p) b0[p] = Bs[kk][tx * 8 + p];
#pragma unroll
      for (int q = 0; q < 8; ++q)
#pragma unroll
        for (int p = 0; p < 8; ++p) acc[q][p] += a0[q] * b0[p];
    }
    __syncthreads();
  }
  for (int q = 0; q < 8; ++q) {
    int r = bm + ty * 8 + q;
    float* Cr = C + (size_t)r * Nc + bn + tx * 8;
    const float* baser = base + (size_t)r * Nc + bn + tx * 8;
#pragma unroll
    for (int p = 0; p < 8; ++p) {
      float vv = acc[q][p];
      if (bias) vv += bias[bn + tx * 8 + p];
      if (act == 1) vv = fmaxf(vv, 0.f);
      if (addb) vv += baser[p];
      Cr[p] = vv;
    }
  }
}

__global__ __launch_bounds__(256) void rowln_kernel(const float* __restrict__ in,
                                                    const float* __restrict__ g,
                                                    const float* __restrict__ be,
                                                    float* __restrict__ out) {
  int r = blockIdx.x, t = threadIdx.x;
  __shared__ double s1[256], s2[256];
  const float* row = in + (size_t)r * 512;
  float v0 = row[t], v1 = row[t + 256];
  s1[t] = (double)v0 + (double)v1;
  s2[t] = (double)v0 * v0 + (double)v1 * v1;
  __syncthreads();
  for (int o = 128; o > 0; o >>= 1) { if (t < o) { s1[t] += s1[t + o]; s2[t] += s2[t + o]; } __syncthreads(); }
  double m = s1[0] / 512.0, var = s2[0] / 512.0 - m * m;
  float rstd = 1.0f / sqrtf((float)var + 1e-5f);
  float mf = (float)m;
  out[(size_t)r * 512 + t] = (v0 - mf) * rstd * g[t] + be[t];
  out[(size_t)r * 512 + t + 256] = (v1 - mf) * rstd * g[t + 256] + be[t + 256];
}

__global__ __launch_bounds__(256) void xnorm_kernel(float* kno) {
  int r = blockIdx.x, t = threadIdx.x;
  __shared__ double s1[256];
  float* row = kno + (size_t)r * 512;
  float v0 = row[t], v1 = row[t + 256];
  s1[t] = (double)v0 * v0 + (double)v1 * v1;
  __syncthreads();
  for (int o = 128; o > 0; o >>= 1) { if (t < o) s1[t] += s1[t + o]; __syncthreads(); }
  float nrm = fmaxf((float)sqrt(s1[0]), 1e-12f);
  row[t] = v0 / nrm; row[t + 256] = v1 / nrm;
}

__global__ __launch_bounds__(256) void cov_kernel(const float* __restrict__ xn, double* __restrict__ cov) {
  int b = blockIdx.x, it = blockIdx.y, jt = blockIdx.z;
  __shared__ float Xi[64][65], Xj[64][65];
  int t = threadIdx.x;
  int tx = t & 15, ty = t >> 4;
  double acc[4][4] = {};
  const float* xb = xn + (size_t)b * 131072;
  for (int f0 = 0; f0 < 512; f0 += 64) {
    for (int l = 0; l < 16; ++l) {
      int idx = t + l * 256;
      int r = idx >> 6, ff = idx & 63;
      Xi[r][ff] = xb[(size_t)(it * 64 + r) * 512 + f0 + ff];
      Xj[r][ff] = xb[(size_t)(jt * 64 + r) * 512 + f0 + ff];
    }
    __syncthreads();
    for (int ff = 0; ff < 64; ++ff) {
      double a0[4], b0[4];
#pragma unroll
      for (int q = 0; q < 4; ++q) { a0[q] = (double)Xi[ty * 4 + q][ff]; b0[q] = (double)Xj[tx * 4 + q][ff]; }
#pragma unroll
      for (int q = 0; q < 4; ++q)
#pragma unroll
        for (int p = 0; p < 4; ++p) acc[q][p] += a0[q] * b0[p];
    }
    __syncthreads();
  }
  double* cb = cov + (size_t)b * 65536;
  for (int q = 0; q < 4; ++q)
    for (int p = 0; p < 4; ++p)
      cb[(size_t)(it * 64 + ty * 4 + q) * 256 + jt * 64 + tx * 4 + p] = acc[q][p];
}

// Fused-lazy Householder tridiagonalization. Defers each step's rank-2 update
// and applies it during the NEXT step's matvec pass (one full-matrix R+W pass
// per step instead of matvec-read + rank2-R/W). Per-element expressions and
// all reduction thread-mappings identical to the proven R2 wave-parallel
// kernel -> bit-identical output. 1024 threads = 16 waves.
__global__ __launch_bounds__(1024) void dsytrd_kernel(double* Aall, double* dE, double* eE,
                                                      double* tauE) {
  int b = blockIdx.x, t = threadIdx.x;
  int lane = t & 63, wid = t >> 6;
  double* A = Aall + (size_t)b * 65536;
  __shared__ double buf0[256], buf1[256], buf2[256], buf3[256];
  __shared__ double v2[256];
  __shared__ double redw[16];
  const int n = 256;
  double* v = buf0; double* w = buf1;    // current reflector / w-vector
  double* vp = buf2; double* wp = buf3;  // pending rank-2 from previous step
  int pend = 0;
  for (int i = 0; i < n - 1; ++i) {
    // Phase 0: corrected column i -> v2 (apply pending rank-2 to column i).
    // Expression identical to R2's rank-2 element update.
    for (int r = i + t; r < n; r += 1024) {
      double a = A[(size_t)r * 256 + i];
      if (pend) {
        a = a - (vp[r] * wp[i] + wp[r] * vp[i]);
        A[(size_t)r * 256 + i] = a;
      }
      v2[r] = a;
    }
    __syncthreads();  // B0
    // Phase 1: norm below subdiagonal (R2 mapping r = i+2+t)
    double s = 0.0;
    for (int r = i + 2 + t; r < n; r += 1024) { double xv = v2[r]; s += xv * xv; }
    for (int o = 1; o < 64; o <<= 1) s += __shfl_xor(s, o);
    if (lane == 0) redw[wid] = s;
    __syncthreads();  // B1
    double xns = 0.0;
    for (int k = 0; k < 16; ++k) xns += redw[k];
    double alpha = v2[i + 1];
    double tau, beta, scl;
    if (xns == 0.0) { tau = 0.0; beta = alpha; scl = 0.0; }
    else {
      double xnorm = sqrt(xns);
      double rr = dlapy2d(alpha, xnorm);
      beta = (alpha >= 0.0) ? -rr : rr;
      tau = (beta - alpha) / beta;
      scl = 1.0 / (alpha - beta);
    }
    if (tau != 0.0) {
      // v setup (R2 mapping r = i+1+t)
      for (int r = i + 1 + t; r < n; r += 1024) {
        double vr = (r == i + 1) ? 1.0 : v2[r] * scl;
        v[r] = vr;
        if (r >= i + 2) A[(size_t)r * 256 + i] = vr;
      }
      __syncthreads();  // B2
      // Fused pass: apply pending rank-2 to trailing square and matvec.
      // Wave per row (r = i+1+wid stride 16), lanes over columns (stride 64).
      for (int r = i + 1 + wid; r < n; r += 16) {
        double* Ar = A + (size_t)r * 256;
        double acc = 0.0;
        if (pend) {
          double vpr = vp[r], wpr = wp[r];
          for (int c = i + 1 + lane; c < n; c += 64) {
            double a = Ar[c] - (vpr * wp[c] + wpr * vp[c]);
            Ar[c] = a;
            acc += a * v[c];
          }
        } else {
          for (int c = i + 1 + lane; c < n; c += 64) acc += Ar[c] * v[c];
        }
        for (int o = 1; o < 64; o <<= 1) acc += __shfl_xor(acc, o);
        if (lane == 0) w[r] = tau * acc;
      }
      __syncthreads();  // B3
      // dot = w.v (R2 mapping)
      double sd = 0.0;
      for (int r = i + 1 + t; r < n; r += 1024) sd += w[r] * v[r];
      for (int o = 1; o < 64; o <<= 1) sd += __shfl_xor(sd, o);
      if (lane == 0) redw[wid] = sd;
      __syncthreads();  // B4
      double dot = 0.0;
      for (int k = 0; k < 16; ++k) dot += redw[k];
      double alpha2 = -0.5 * tau * dot;
      for (int r = i + 1 + t; r < n; r += 1024) w[r] += alpha2 * v[r];
      // rank-2 deferred to next step
    } else if (pend) {
      // no new reflector: flush pending rank-2 into trailing square now
      for (int r = i + 1 + wid; r < n; r += 16) {
        double* Ar = A + (size_t)r * 256;
        double vpr = vp[r], wpr = wp[r];
        for (int c = i + 1 + lane; c < n; c += 64)
          Ar[c] = Ar[c] - (vpr * wp[c] + wpr * vp[c]);
      }
    }
    if (t == 0) { eE[b * 256 + i] = beta; tauE[b * 256 + i] = tau; }
    __syncthreads();  // B5: orders w-update/A-writes before next Phase 0
    if (tau != 0.0) {
      double* tv = v; v = vp; vp = tv;
      double* tw = w; w = wp; wp = tw;
      pend = 1;
    } else {
      pend = 0;
    }
  }
  // dE from diagonal; apply last pending rank-2 to A[n-1][n-1] (same expr).
  for (int r = t; r < n; r += 1024) {
    double dd = A[(size_t)r * 256 + r];
    if (pend && r == n - 1) dd = dd - (vp[r] * wp[r] + wp[r] * vp[r]);
    dE[b * 256 + r] = dd;
  }
}

__global__ __launch_bounds__(64) void tear_kernel(double* dE, const double* eE) {
  int b = threadIdx.x;
  if (b >= 64) return;
  for (int m = 1; m < 16; ++m) {
    int p = m * 16 - 1;
    double ae = fabs(eE[b * 256 + p]);
    dE[b * 256 + p] -= ae;
    dE[b * 256 + p + 1] -= ae;
  }
}

// One leaf per thread; Z (16x16) + d/e in LDS, XOR-swizzled.
__global__ __launch_bounds__(64) void leaf_kernel(double* dE, double* eE, double* Qe, int* indxq) {
  __shared__ double Zs[LPB * 256];
  __shared__ double des[LPB * 33];
  int t = threadIdx.x;
  int g = blockIdx.x * LPB + t;
  if (t >= LPB || g >= 1024) return;
  int b = g >> 4, lf = g & 15, off = lf * 16;
  double* zz = Zs + t * 256;
  double* dd = des + t * 33;
  double* ee = dd + 16;
  int sw = t & 15;
  for (int i = 1; i <= 16; ++i) dd[i] = dE[b * 256 + off + i - 1];
  for (int i = 1; i <= 15; ++i) ee[i] = eE[b * 256 + off + i - 1];
  ee[16] = 0.0;
  dsteqr16_lds(dd, ee, zz, sw);
  for (int i = 1; i <= 16; ++i) dE[b * 256 + off + i - 1] = dd[i];
  double* Qb = Qe + (size_t)b * 65536;
  for (int r = 0; r < 16; ++r)
    for (int c = 0; c < 16; ++c) Qb[(size_t)(off + r) * 256 + off + c] = zz[((r << 4) + c) ^ sw];
  for (int i = 0; i < 16; ++i) indxq[b * 256 + off + i] = i + 1;
}

// dlaed2 deflation scan. Block per (b, merge): serial scan on thread 0 with
// all arrays in LDS; Givens rotations deferred to a list (scan never reads Q
// after z extraction) and applied block-parallel row-partitioned afterwards.
__global__ __launch_bounds__(256) void merge_scan_kernel(int nm, int nmerge, double* Qsrc, double* dE,
                                                         const double* eE, int* indxq,
                                                         double* dlamda_g, double* w_g, double* rho_g,
                                                         int* surv_g, int* defl_g, int* Kb) {
  int b = blockIdx.x, mg = blockIdx.y;
  int off = mg * nm, n1 = nm / 2, n2 = nm - n1;
  double* Q = Qsrc + (size_t)b * 65536;
  double* dg = dE + b * 256 + off;
  int* iqg = indxq + b * 256 + off;
  int t = threadIdx.x;

  __shared__ double dl[257], zl[257], dlamA[257], wl2[257];
  __shared__ int iq[257], indxc[257], indxl[257], indxpl[257];
  __shared__ double rotc[256], rots[256];
  __shared__ int rotp[256], rotn[256];
  __shared__ int sh_nrot, sh_K, sh_zero;

  for (int ii = 1 + t; ii <= nm; ii += 256) { dl[ii] = dg[ii - 1]; iq[ii] = iqg[ii - 1]; }
  __syncthreads();

  if (t == 0) {
    double rho = eE[b * 256 + off + n1 - 1];
    for (int j = 1; j <= n1; ++j) zl[j] = Q[(size_t)(off + n1 - 1) * 256 + off + j - 1];
    for (int j = 1; j <= n2; ++j) zl[n1 + j] = Q[(size_t)(off + n1) * 256 + off + n1 + j - 1];
    if (rho < 0.0)
      for (int j = n1 + 1; j <= nm; ++j) zl[j] = -zl[j];
    double tconst = 1.0 / sqrt(2.0);
    for (int j = 1; j <= nm; ++j) zl[j] *= tconst;
    rho = fabs(2.0 * rho);
    rho_g[b * nmerge + mg] = rho;
    for (int i = n1 + 1; i <= nm; ++i) iq[i] += n1;
    for (int i = 1; i <= nm; ++i) dlamA[i] = dl[iq[i]];
    dlamrg_dev(n1, n2, dlamA, 1, 1, indxc);
    for (int i = 1; i <= nm; ++i) indxl[i] = iq[indxc[i]];
    int imax = 1, jmax = 1;
    for (int i = 2; i <= nm; ++i) {
      if (fabs(zl[i]) > fabs(zl[imax])) imax = i;
      if (fabs(dl[i]) > fabs(dl[jmax])) jmax = i;
    }
    double tol = 8.0 * EPS_D * fmax(fabs(dl[jmax]), fabs(zl[imax]));
    if (rho * fabs(zl[imax]) <= tol) {
      sh_K = 0; sh_zero = 1; sh_nrot = 0;
    } else {
      sh_zero = 0;
      int nrot = 0;
      int K = 0, K2 = nm + 1, pj = 0, j = 1;
      bool havepj = false;
      for (j = 1; j <= nm; ++j) {
        int nj = indxl[j];
        if (rho * fabs(zl[nj]) <= tol) {
          K2--; indxpl[K2] = nj;
          if (j == nm) break;
        } else { pj = nj; havepj = true; break; }
      }
      if (havepj) {
        for (;;) {
          j = j + 1;
          if (j > nm) break;
          int nj = indxl[j];
          if (rho * fabs(zl[nj]) <= tol) { K2--; indxpl[K2] = nj; }
          else {
            double s_ = zl[pj], c_ = zl[nj];
            double tau_ = dlapy2d(c_, s_);
            double t_ = dl[nj] - dl[pj];
            c_ = c_ / tau_; s_ = -s_ / tau_;
            if (fabs(t_ * c_ * s_) <= tol) {
              zl[nj] = tau_; zl[pj] = 0.0;
              rotp[nrot] = pj; rotn[nrot] = nj; rotc[nrot] = c_; rots[nrot] = s_; ++nrot;
              double t2 = dl[pj] * c_ * c_ + dl[nj] * s_ * s_;
              dl[nj] = dl[pj] * s_ * s_ + dl[nj] * c_ * c_;
              dl[pj] = t2;
              K2--;
              int i_ = 1;
              for (;;) {
                if (K2 + i_ <= nm) {
                  if (dl[pj] < dl[indxpl[K2 + i_]]) {
                    indxpl[K2 + i_ - 1] = indxpl[K2 + i_];
                    indxpl[K2 + i_] = pj;
                    i_++;
                  } else { indxpl[K2 + i_ - 1] = pj; break; }
                } else { indxpl[K2 + i_ - 1] = pj; break; }
              }
              pj = nj;
            } else {
              K++; dlamA[K] = dl[pj]; wl2[K] = zl[pj]; indxpl[K] = pj; pj = nj;
            }
          }
        }
        K++; dlamA[K] = dl[pj]; wl2[K] = zl[pj]; indxpl[K] = pj;
      }
      sh_K = K; sh_nrot = nrot;
    }
  }
  __syncthreads();
  int nrot = sh_nrot, K = sh_K;
  // apply deferred rotations in order; rows partitioned across threads
  for (int r = t; r < nm; r += 256) {
    size_t rowb = (size_t)(off + r) * 256;
    for (int k = 0; k < nrot; ++k) {
      int cp = off + rotp[k] - 1, cn = off + rotn[k] - 1;
      double c_ = rotc[k], s_ = rots[k];
      double x = Q[rowb + cp], y = Q[rowb + cn];
      Q[rowb + cp] = c_ * x + s_ * y;
      Q[rowb + cn] = c_ * y - s_ * x;
    }
  }
  if (sh_zero) {
    if (t == 0) Kb[b * nmerge + mg] = 0;
    for (int j = 1 + t; j <= nm; j += 256) {
      int il = indxl[j];
      defl_g[b * 256 + off + j - 1] = il;
      dg[j - 1] = dl[il];
      iqg[j - 1] = j;
    }
  } else {
    if (t == 0) Kb[b * nmerge + mg] = K;
    for (int i = 1 + t; i <= K; i += 256) {
      dlamda_g[b * 256 + off + i - 1] = dlamA[i];
      w_g[b * 256 + off + i - 1] = wl2[i];
      surv_g[b * 256 + off + i - 1] = indxpl[i];
    }
    for (int jj = K + 1 + t; jj <= nm; jj += 256) {
      defl_g[b * 256 + off + jj - 1] = indxpl[jj];
      dg[jj - 1] = dl[indxpl[jj]];
    }
  }
}

// secular solver (dlaed4-equivalent, bisection)
__global__ __launch_bounds__(256) void secular_kernel(int nm, int nmerge, const double* dlamda_g,
                                                      const double* w_g, const double* rho_g,
                                                      const int* Kb, double* dE, double* tau_g,
                                                      int* orig_g) {
  int b = blockIdx.x, pos = threadIdx.x;
  int mg = pos / nm, jl = pos % nm + 1;
  int K = Kb[b * nmerge + mg];
  if (jl > K) return;
  int base = b * 256 + mg * nm;
  const double* dl = dlamda_g + base;
  const double* w = w_g + base;
  double rho = rho_g[b * nmerge + mg];
  int orig; double lo, hi;
  if (jl < K) {
    double dj = dl[jl - 1], dj1 = dl[jl];
    double mid = (dj + dj1) * 0.5;
    double acc = 0.0;
    for (int i = 0; i < K; ++i) acc += w[i] * w[i] / (dl[i] - mid);
    double fmid = 1.0 + rho * acc;
    if (fmid > 0.0) { orig = jl; lo = 0.0; hi = mid - dj; }
    else { orig = jl + 1; lo = mid - dj1; hi = 0.0; }
  } else {
    orig = K;
    double zs = 0.0;
    for (int i = 0; i < K; ++i) zs += w[i] * w[i];
    lo = 0.0; hi = rho * zs;
  }
  double dorig = dl[orig - 1];
  for (int it = 0; it < 100; ++it) {
    double tm = 0.5 * (lo + hi);
    if (tm == lo || tm == hi) break;
    double acc = 0.0;
    for (int i = 0; i < K; ++i) acc += w[i] * w[i] / ((dl[i] - dorig) - tm);
    double g = 1.0 + rho * acc;
    if (g > 0.0) hi = tm; else lo = tm;
  }
  double tau = 0.5 * (lo + hi);
  tau_g[base + jl - 1] = tau;
  orig_g[base + jl - 1] = orig;
  dE[base + jl - 1] = dorig + tau;
}

__global__ __launch_bounds__(256) void zhat_kernel(int nm, int nmerge, const double* dlamda_g,
                                                   const double* w_g, const double* tau_g,
                                                   const int* orig_g, const int* Kb, double* zhat_g) {
  int b = blockIdx.x, pos = threadIdx.x;
  int mg = pos / nm, il = pos % nm + 1;
  int K = Kb[b * nmerge + mg];
  if (il > K) return;
  int base = b * 256 + mg * nm;
  const double* dl = dlamda_g + base;
  double di = dl[il - 1];
  double p = (di - dl[orig_g[base + il - 1] - 1]) - tau_g[base + il - 1];
  for (int jj = 1; jj <= K; ++jj) {
    if (jj == il) continue;
    double del = (di - dl[orig_g[base + jj - 1] - 1]) - tau_g[base + jj - 1];
    p *= del / (di - dl[jj - 1]);
  }
  double val = sqrt(fmax(-p, 0.0));
  zhat_g[base + il - 1] = fsign(val, w_g[base + il - 1]);
}

__global__ __launch_bounds__(256) void coeff_kernel(int nm, int nmerge, const double* dlamda_g,
                                                    const double* zhat_g, const double* tau_g,
                                                    const int* orig_g, const int* Kb, double* Cbuf) {
  int b = blockIdx.x, pos = threadIdx.x;
  int mg = pos / nm, jl = pos % nm + 1;
  int K = Kb[b * nmerge + mg];
  if (jl > K) return;
  int off = mg * nm, base = b * 256 + off;
  double* C = Cbuf + (size_t)b * 65536;
  const double* dl = dlamda_g + base;
  if (K == 1) { C[(size_t)off * 256 + off + jl - 1] = 1.0; return; }
  double dorig = dl[orig_g[base + jl - 1] - 1];
  double tau = tau_g[base + jl - 1];
  double ss = 0.0;
  for (int i = 1; i <= K; ++i) {
    double del = (dl[i - 1] - dorig) - tau;
    double ci = zhat_g[base + i - 1] / del;
    C[(size_t)(off + i - 1) * 256 + off + jl - 1] = ci;
    ss += ci * ci;
  }
  double inv = 1.0 / sqrt(ss);
  for (int i = 1; i <= K; ++i) C[(size_t)(off + i - 1) * 256 + off + jl - 1] *= inv;
}

__global__ __launch_bounds__(64) void dlamrg_kernel(int nm, int nmerge, const double* dE,
                                                    const int* Kb, int* indxq) {
  int gid = blockIdx.x * 64 + threadIdx.x;
  if (gid >= 64 * nmerge) return;
  int b = gid / nmerge, mg = gid % nmerge;
  int off = mg * nm;
  int K = Kb[b * nmerge + mg];
  int* iqg = indxq + b * 256 + off;
  if (K == 0) return;  // identity already set by scan
  const double* dg = dE + b * 256 + off;
  int n1sv = K, n2sv = nm - K;
  int ind1 = 1, ind2 = nm;
  int i = 1;
  int idx[257];
  while (n1sv > 0 && n2sv > 0) {
    if (dg[ind1 - 1] <= dg[ind2 - 1]) { idx[i++] = ind1; ind1++; n1sv--; }
    else { idx[i++] = ind2; ind2--; n2sv--; }
  }
  if (n1sv == 0) { while (n2sv > 0) { idx[i++] = ind2; ind2--; n2sv--; } }
  else { while (n1sv > 0) { idx[i++] = ind1; ind1++; n1sv--; } }
  for (int t = 1; t <= nm; ++t) iqg[t - 1] = idx[t];
}

__global__ __launch_bounds__(256) void merge_gemm_kernel(int nm, int nmerge, const double* Qsrc,
                                                         const double* Cbuf, const int* surv_g,
                                                         const int* Kb, double* Qdst) {
  int b = blockIdx.x, mg = blockIdx.y;
  int tcnt = nm / 32;
  int rt = blockIdx.z / tcnt, ct = blockIdx.z % tcnt;
  int off = mg * nm;
  int K = Kb[b * nmerge + mg];
  if (ct * 32 >= K) return;
  __shared__ double Qs[32][33];
  __shared__ double Cs[32][33];
  __shared__ int svs[32];
  int t = threadIdx.x;
  int tc = t & 31, tr = t >> 5;
  const double* Qsb = Qsrc + (size_t)b * 65536;
  const double* Cb = Cbuf + (size_t)b * 65536;
  double acc[4] = {0, 0, 0, 0};
  int r0 = off + rt * 32, c0 = off + ct * 32;
  for (int i0 = 0; i0 < K; i0 += 32) {
    if (t < 32) svs[t] = (i0 + t < K) ? surv_g[b * 256 + off + i0 + t] : 0;
    __syncthreads();
    for (int l = 0; l < 4; ++l) {
      int idx = t + l * 256;
      int r = idx >> 5, ii = idx & 31;
      int sc = svs[ii];
      Qs[r][ii] = (sc > 0) ? Qsb[(size_t)(r0 + r) * 256 + off + sc - 1] : 0.0;
      Cs[r][ii] = (i0 + r < K && ct * 32 + ii < K) ? Cb[(size_t)(off + i0 + r) * 256 + c0 + ii] : 0.0;
    }
    __syncthreads();
    for (int ii = 0; ii < 32; ++ii) {
      double cv = Cs[ii][tc];
#pragma unroll
      for (int q = 0; q < 4; ++q) acc[q] += Qs[tr * 4 + q][ii] * cv;
    }
    __syncthreads();
  }
  if (ct * 32 + tc < K) {
    double* Qd = Qdst + (size_t)b * 65536;
    for (int q = 0; q < 4; ++q) Qd[(size_t)(r0 + tr * 4 + q) * 256 + c0 + tc] = acc[q];
  }
}

// deflated-column copy, row-parallel (each thread owns rows; loops columns)
__global__ __launch_bounds__(256) void defl_copy_kernel(int nm, int nmerge, const double* Qsrc,
                                                        const int* defl_g, const int* Kb,
                                                        double* Qdst) {
  int b = blockIdx.x, mg = blockIdx.y;
  int off = mg * nm;
  int K = Kb[b * nmerge + mg];
  int t = threadIdx.x;
  const double* Qs = Qsrc + (size_t)b * 65536;
  double* Qd = Qdst + (size_t)b * 65536;
  for (int r = t; r < nm; r += 256) {
    const double* Qsr = Qs + (size_t)(off + r) * 256;
    double* Qdr = Qd + (size_t)(off + r) * 256;
    for (int jl = K + 1; jl <= nm; ++jl)
      Qdr[off + jl - 1] = Qsr[off + defl_g[b * 256 + off + jl - 1] - 1];
  }
}

// gather ranks 2..9, apply Householder back-transform, emit E (f32, [b][s][n])
__global__ __launch_bounds__(256) void dormtr_kernel(const double* Aall, const double* tauE,
                                                     const double* Qe, const int* indxq, float* E) {
  int b = blockIdx.x, t = threadIdx.x;
  const double* A = Aall + (size_t)b * 65536;
  __shared__ double U[256][8];
  __shared__ double wred[32][8];
  __shared__ double wfin[8];
  __shared__ int sel[8];
  if (t < 8) sel[t] = indxq[b * 256 + 1 + t] - 1;
  __syncthreads();
  for (int i = t; i < 256 * 8; i += 256) {
    int r = i >> 3, c = i & 7;
    U[r][c] = Qe[(size_t)b * 65536 + (size_t)r * 256 + sel[c]];
  }
  __syncthreads();
  int lane = t & 31, col = t >> 5;
  for (int s = 254; s >= 0; --s) {
    double tv = tauE[b * 256 + s];
    if (tv == 0.0) continue;
    double acc = (lane == 0) ? U[s + 1][col] : 0.0;
    for (int r = s + 2 + lane; r < 256; r += 32) acc += A[(size_t)r * 256 + s] * U[r][col];
    wred[lane][col] = acc;
    __syncthreads();
    if (t < 8) { double a = 0.0; for (int l2 = 0; l2 < 32; ++l2) a += wred[l2][t]; wfin[t] = a; }
    __syncthreads();
    double wc = wfin[col] * tv;
    if (lane == 0) U[s + 1][col] -= wc;
    for (int r = s + 2 + lane; r < 256; r += 32) U[r][col] -= A[(size_t)r * 256 + s] * wc;
    __syncthreads();
  }
  for (int i = t; i < 8 * 256; i += 256) {
    int s = i >> 8, nn = i & 255;
    E[((size_t)b * 8 + s) * 256 + nn] = (float)U[nn][s];
  }
}

// z = E2 . fnp, coalesced streaming of fnp rows; per-output accumulation order
// identical to the original column-wise version (ascending n) -> bit-identical.
__global__ __launch_bounds__(256) void zproj_kernel(const float* __restrict__ fnp,
                                                    const float* __restrict__ E2,
                                                    float* __restrict__ z) {
  int b = blockIdx.x, t = threadIdx.x;
  __shared__ float er[8][256];
  for (int i = t; i < 8 * 256; i += 256) er[i >> 8][i & 255] = E2[(size_t)b * 2048 + i];
  __syncthreads();
  for (int d0 = 0; d0 < 512; d0 += 256) {
    int d = d0 + t;
    float a0 = 0.f, a1 = 0.f, a2 = 0.f, a3 = 0.f, a4 = 0.f, a5 = 0.f, a6 = 0.f, a7 = 0.f;
    for (int n = 0; n < 256; ++n) {
      float f = fnp[((size_t)b * 256 + n) * 512 + d];
      a0 += er[0][n] * f; a1 += er[1][n] * f; a2 += er[2][n] * f; a3 += er[3][n] * f;
      a4 += er[4][n] * f; a5 += er[5][n] * f; a6 += er[6][n] * f; a7 += er[7][n] * f;
    }
    z[((size_t)b * 8 + 0) * 512 + d] = a0;
    z[((size_t)b * 8 + 1) * 512 + d] = a1;
    z[((size_t)b * 8 + 2) * 512 + d] = a2;
    z[((size_t)b * 8 + 3) * 512 + d] = a3;
    z[((size_t)b * 8 + 4) * 512 + d] = a4;
    z[((size_t)b * 8 + 5) * 512 + d] = a5;
    z[((size_t)b * 8 + 6) * 512 + d] = a6;
    z[((size_t)b * 8 + 7) * 512 + d] = a7;
  }
}

__global__ __launch_bounds__(64) void d2_kernel(const float* __restrict__ z,
                                                const float* __restrict__ ts, double* sdist,
                                                int* idxr) {
  int row = blockIdx.x;
  int lane = threadIdx.x;
  const float* zr = z + (size_t)row * 512;
  const float* tr = ts + (size_t)lane * 512;
  double zz = 0, zt = 0, tt = 0;
  for (int d = 0; d < 512; ++d) {
    double zv = zr[d], tv = tr[d];
    zz += zv * zv; zt += zv * tv; tt += tv * tv;
  }
  double d2 = zz + tt - 2.0 * zt;
  int best = lane; double bv = d2;
  for (int off = 32; off > 0; off >>= 1) {
    double ov = __shfl_down(bv, off);
    int oi = __shfl_down(best, off);
    if (ov < bv || (ov == bv && oi < best)) { bv = ov; best = oi; }
  }
  if (lane == 0) { sdist[row] = bv; idxr[row] = best; }
}

__global__ __launch_bounds__(64) void order_kernel(const double* sdist, const int* idxr, int* fidx,
                                                   float* out_idx) {
  int b = threadIdx.x;
  if (b >= 64) return;
  double sd[8]; int ord[8];
  for (int s = 0; s < 8; ++s) { sd[s] = sdist[b * 8 + s]; ord[s] = s; }
  for (int a = 1; a < 8; ++a) {
    double kv = sd[a]; int ko = ord[a]; int c = a - 1;
    while (c >= 0 && sd[c] > kv) { sd[c + 1] = sd[c]; ord[c + 1] = ord[c]; --c; }
    sd[c + 1] = kv; ord[c + 1] = ko;
  }
  for (int s = 0; s < 8; ++s) {
    int fi = idxr[ord[s]];  // cross-batch quirk: always batch 0's argmins
    fidx[b * 8 + s] = fi;
    out_idx[b * 8 + s] = (float)fi;
  }
}

__global__ __launch_bounds__(256) void slots0_kernel(const float* z, const float* emb,
                                                     const int* fidx, float* slots) {
  int i = blockIdx.x * 256 + threadIdx.x;
  if (i >= 512 * 512) return;
  int t = i / 512, d = i % 512;
  float zv = z[i];
  float zq = emb[fidx[t] * 512 + d];
  slots[i] = zv + (zq - zv);
}

__global__ __launch_bounds__(256) void qloss_kernel(const float* z, const float* ts, const int* fidx,
                                                    float* out) {
  __shared__ double red[256];
  int t = threadIdx.x;
  double acc = 0.0;
  for (int i = t; i < 512 * 512; i += 256) {
    int r = i / 512, d = i % 512;
    float diff = ts[fidx[r] * 512 + d] - z[i];
    acc += (double)diff * (double)diff;
  }
  red[t] = acc; __syncthreads();
  for (int o = 128; o > 0; o >>= 1) { if (t < o) red[t] += red[t + o]; __syncthreads(); }
  if (t == 0) {
    float a = (float)(red[0] / 64.0);
    out[0] = a + 0.99f * a;
  }
}

__global__ __launch_bounds__(256) void dots_kernel(const float* __restrict__ q,
                                                   const float* __restrict__ k,
                                                   float* __restrict__ dots) {
  int b = blockIdx.x, jt = blockIdx.y;
  __shared__ float qs[8][513];
  __shared__ float kc[64][33];
  int t = threadIdx.x;
  for (int i = t; i < 8 * 512; i += 256) qs[i / 512][i % 512] = q[((size_t)b * 8 + i / 512) * 512 + i % 512];
  int j = t % 64, ig = t / 64;
  float acc0 = 0.f, acc1 = 0.f;
  for (int d0 = 0; d0 < 512; d0 += 32) {
    __syncthreads();
    for (int l = 0; l < 8; ++l) {
      int idx = t + l * 256;
      int r = idx >> 5, dd = idx & 31;
      kc[r][dd] = k[((size_t)b * 256 + jt * 64 + r) * 512 + d0 + dd];
    }
    __syncthreads();
    for (int dd = 0; dd < 32; ++dd) {
      float kv = kc[j][dd];
      acc0 += qs[ig * 2][d0 + dd] * kv;
      acc1 += qs[ig * 2 + 1][d0 + dd] * kv;
    }
  }
  const float scale = (float)(1.0 / sqrt(512.0));
  dots[((size_t)b * 8 + ig * 2) * 256 + jt * 64 + j] = acc0 * scale;
  dots[((size_t)b * 8 + ig * 2 + 1) * 256 + jt * 64 + j] = acc1 * scale;
}

__global__ __launch_bounds__(256) void softmax_kernel(const float* dots, float* attn) {
  int b = blockIdx.x, j = threadIdx.x;
  float v[8]; float mx = -1e30f;
  for (int i = 0; i < 8; ++i) { v[i] = dots[((size_t)b * 8 + i) * 256 + j]; mx = fmaxf(mx, v[i]); }
  float s = 0.f;
  for (int i = 0; i < 8; ++i) { v[i] = expf(v[i] - mx); s += v[i]; }
  for (int i = 0; i < 8; ++i) attn[((size_t)b * 8 + i) * 256 + j] = v[i] / s;
}

__global__ __launch_bounds__(64) void asum_kernel(const float* attn, float* asum) {
  int bi = blockIdx.x, lane = threadIdx.x;
  float s = 0.f;
  for (int j = lane; j < 256; j += 64) s += attn[(size_t)bi * 256 + j] + 1e-8f;
  for (int off = 32; off > 0; off >>= 1) s += __shfl_down(s, off);
  if (lane == 0) asum[bi] = s;
}

__global__ __launch_bounds__(256) void updates_kernel(const float* attn, const float* asum,
                                                      const float* v, float* upd) {
  int b = blockIdx.x;
  __shared__ float at[8][257];
  int t = threadIdx.x;
  for (int i = t; i < 8 * 256; i += 256) {
    int ii = i / 256, j = i % 256;
    at[ii][j] = (attn[((size_t)b * 8 + ii) * 256 + j] + 1e-8f) / asum[b * 8 + ii];
  }
  __syncthreads();
  for (int d = t; d < 512; d += 256) {
    float acc[8] = {0, 0, 0, 0, 0, 0, 0, 0};
    for (int j = 0; j < 256; ++j) {
      float vv = v[((size_t)b * 256 + j) * 512 + d];
#pragma unroll
      for (int ii = 0; ii < 8; ++ii) acc[ii] += at[ii][j] * vv;
    }
    for (int ii = 0; ii < 8; ++ii) upd[((size_t)b * 8 + ii) * 512 + d] = acc[ii];
  }
}

__global__ __launch_bounds__(256) void gru_kernel(const float* gi, const float* gh, const float* h,
                                                  float* out) {
  int i = blockIdx.x * 256 + threadIdx.x;
  if (i >= 512 * 512) return;
  int t = i / 512, d = i % 512;
  const float* gir = gi + (size_t)t * 1536;
  const float* ghr = gh + (size_t)t * 1536;
  float r = 1.f / (1.f + expf(-(gir[d] + ghr[d])));
  float zg = 1.f / (1.f + expf(-(gir[512 + d] + ghr[512 + d])));
  float n = tanhf(gir[1024 + d] + r * ghr[1024 + d]);
  out[i] = (1.f - zg) * n + zg * h[i];
}

__global__ __launch_bounds__(64) void feats_kernel(const float* slots, const float* dposT,
                                                   float* out) {
  int blk = blockIdx.x;  // bs*512 + d
  int bs = blk >> 9, d = blk & 511;
  float s = slots[(size_t)bs * 512 + d];
  const float* dp = dposT + (size_t)d * 256;
  int n0 = threadIdx.x * 4;
  float4 o;
  o.x = s + dp[n0]; o.y = s + dp[n0 + 1]; o.z = s + dp[n0 + 2]; o.w = s + dp[n0 + 3];
  *(float4*)(out + (size_t)blk * 256 + n0) = o;
}

// ------------------------------ host driver --------------------------------

extern "C" void kernel_launch(void* const* d_in, const int* in_sizes, int n_in, void* d_out,
                              int out_size, void* d_ws, size_t ws_size, hipStream_t stream) {
  const float* x = (const float*)d_in[0];
  const float* enc_pos_w = (const float*)d_in[1];
  const float* enc_pos_b = (const float*)d_in[2];
  const float* enc_norm_g = (const float*)d_in[3];
  const float* enc_norm_b = (const float*)d_in[4];
  const float* enc_mlp_w1 = (const float*)d_in[5];
  const float* enc_mlp_b1 = (const float*)d_in[6];
  const float* enc_mlp_w2 = (const float*)d_in[7];
  const float* enc_mlp_b2 = (const float*)d_in[8];
  const float* anch_w1 = (const float*)d_in[9];
  const float* anch_b1 = (const float*)d_in[10];
  const float* anch_w2 = (const float*)d_in[11];
  const float* anch_b2 = (const float*)d_in[12];
  const float* wq = (const float*)d_in[13];
  const float* bq = (const float*)d_in[14];
  const float* wk = (const float*)d_in[15];
  const float* bk = (const float*)d_in[16];
  const float* wv = (const float*)d_in[17];
  const float* bv = (const float*)d_in[18];
  const float* gru_wih = (const float*)d_in[19];
  const float* gru_whh = (const float*)d_in[20];
  const float* gru_bih = (const float*)d_in[21];
  const float* gru_bhh = (const float*)d_in[22];
  const float* mlp_w1 = (const float*)d_in[23];
  const float* mlp_b1 = (const float*)d_in[24];
  const float* mlp_w2 = (const float*)d_in[25];
  const float* mlp_b2 = (const float*)d_in[26];
  const float* ni_g = (const float*)d_in[27];
  const float* ni_b = (const float*)d_in[28];
  const float* ns_g = (const float*)d_in[29];
  const float* ns_b = (const float*)d_in[30];
  const float* npf_g = (const float*)d_in[31];
  const float* npf_b = (const float*)d_in[32];
  const float* emb = (const float*)d_in[33];
  const float* dec_pos_w = (const float*)d_in[34];
  const float* dec_pos_b = (const float*)d_in[35];

  float* out = (float*)d_out;
  const size_t FEATS = (size_t)512 * 512 * 256;  // 67108864
  float* out_slots = out + FEATS;
  float* out_idx = out + FEATS + 262144;
  float* out_qloss = out + FEATS + 262144 + 512;

  // workspace layout
  char* ws = (char*)d_ws;
  size_t off = 0;
  auto alloc = [&](size_t bytes) { size_t o = off; off = (off + bytes + 255) & ~(size_t)255; return (void*)(ws + o); };
  const size_t S = (size_t)64 * 256 * 512 * 4;  // 33554432
  float* fnp = (float*)alloc(S);
  float* R2 = (float*)alloc(S);  // kno/xn -> later Cbuf(f64)
  float* R3 = (float*)alloc(S);  // fpln -> later covA(f64)
  float* R4 = (float*)alloc(S);  // h1 -> later Qe(f64)
  float* R5 = (float*)alloc(S);  // fp -> later Q2(f64)
  float* kbuf = (float*)alloc(S);
  float* vbuf = (float*)alloc(S);
  float* posT = (float*)alloc(512 * 256 * 4);
  float* dposT = (float*)alloc(512 * 256 * 4);
  float* m1 = (float*)alloc(64 * 4);
  float* r1 = (float*)alloc(64 * 4);
  float* m2 = (float*)alloc(64 * 4);
  float* r2 = (float*)alloc(64 * 4);
  double* dE = (double*)alloc(64 * 256 * 8);
  double* eE = (double*)alloc(64 * 256 * 8);
  double* tauE = (double*)alloc(64 * 256 * 8);
  double* dlamda_g = (double*)alloc(64 * 256 * 8);
  double* w_g = (double*)alloc(64 * 256 * 8);
  double* zhat_g = (double*)alloc(64 * 256 * 8);
  double* tau_g = (double*)alloc(64 * 256 * 8);
  double* rho_g = (double*)alloc(64 * 8 * 8);
  int* indxq = (int*)alloc(64 * 256 * 4);
  int* surv_g = (int*)alloc(64 * 256 * 4);
  int* defl_g = (int*)alloc(64 * 256 * 4);
  int* orig_g = (int*)alloc(64 * 256 * 4);
  int* Kb = (int*)alloc(64 * 8 * 4);
  int* fidx = (int*)alloc(512 * 4);
  float* E = (float*)alloc(64 * 8 * 256 * 4);
  float* Eh = (float*)alloc(64 * 8 * 256 * 4);
  float* E2 = (float*)alloc(64 * 8 * 256 * 4);
  float* z = (float*)alloc(512 * 512 * 4);
  float* tslots = (float*)alloc(64 * 512 * 4);
  double* sdist = (double*)alloc(512 * 8);
  int* idxr = (int*)alloc(512 * 4);
  float* sA = (float*)alloc(512 * 512 * 4);
  float* sB = (float*)alloc(512 * 512 * 4);
  float* lnbuf = (float*)alloc(512 * 512 * 4);
  float* qbuf = (float*)alloc(512 * 512 * 4);
  float* dotsb = (float*)alloc(64 * 8 * 256 * 4);
  float* attnb = (float*)alloc(64 * 8 * 256 * 4);
  float* asumb = (float*)alloc(64 * 8 * 4);
  float* updb = (float*)alloc(512 * 512 * 4);
  float* gib = (float*)alloc((size_t)512 * 1536 * 4);
  float* ghb = (float*)alloc((size_t)512 * 1536 * 4);
  float* hidb = (float*)alloc(512 * 512 * 4);
  (void)ws_size; (void)in_sizes; (void)n_in; (void)out_size;

  auto gemm = [&](const float* A, const float* Bm, const float* bias, const float* base, float* C,
                  int M, int Nc, int Kd, int bt, int act, int addb) {
    if ((M % 128) == 0 && (Nc % 128) == 0 && (Kd % 16) == 0) {
      dim3 g(M / 128, Nc / 128);
      gemm_f32_big<<<g, 256, 0, stream>>>(A, Bm, bias, base, C, M, Nc, Kd, bt, act, addb);
    } else {
      dim3 g((M + 63) / 64, (Nc + 63) / 64);
      gemm_f32<<<g, 256, 0, stream>>>(A, Bm, bias, base, C, M, Nc, Kd, bt, act, addb);
    }
  };

  // positional embeddings (transposed [d][n])
  pos_kernel<<<(131072 + 255) / 256, 256, 0, stream>>>(enc_pos_w, enc_pos_b, posT);
  pos_kernel<<<(131072 + 255) / 256, 256, 0, stream>>>(dec_pos_w, dec_pos_b, dposT);
  // batch LN stats over (N,D)
  stats_kernel<<<64, 256, 0, stream>>>(x, posT, m1, r1, 0);
  stats_kernel<<<64, 256, 0, stream>>>(x, posT, m2, r2, 1);
  // transpose + LN -> fnp, fpln
  tln_kernel<<<dim3(64, 16, 8), 256, 0, stream>>>(x, posT, enc_norm_g, enc_norm_b, m1, r1, m2, r2,
                                                  fnp, R3);
  // k_nopos
  gemm(fnp, wk, bk, nullptr, R2, 16384, 512, 512, 0, 0, 0);
  // encoder MLP + ni LN -> fp (R5)
  gemm(R3, enc_mlp_w1, enc_mlp_b1, nullptr, R4, 16384, 512, 512, 0, 1, 0);
  gemm(R4, enc_mlp_w2, enc_mlp_b2, nullptr, R5, 16384, 512, 512, 0, 0, 0);
  rowln_kernel<<<16384, 256, 0, stream>>>(R5, ni_g, ni_b, R5);
  gemm(R5, wk, bk, nullptr, kbuf, 16384, 512, 512, 0, 0, 0);
  gemm(R5, wv, bv, nullptr, vbuf, 16384, 512, 512, 0, 0, 0);
  // xn + cov (f64) into R3 region
  xnorm_kernel<<<16384, 256, 0, stream>>>(R2);
  double* covA = (double*)R3;
  cov_kernel<<<dim3(64, 4, 4), 256, 0, stream>>>(R2, covA);
  // eigensolver buffers
  double* Qe = (double*)R4;
  double* Q2 = (double*)R5;
  double* Cbuf = (double*)R2;
  hipMemsetAsync(Qe, 0, S, stream);
  hipMemsetAsync(Q2, 0, S, stream);
  dsytrd_kernel<<<64, 1024, 0, stream>>>(covA, dE, eE, tauE);
  tear_kernel<<<1, 64, 0, stream>>>(dE, eE);
  leaf_kernel<<<(1024 + LPB - 1) / LPB, LPB, 0, stream>>>(dE, eE, Qe, indxq);
  for (int L = 0; L < 4; ++L) {
    int nm = 32 << L;
    int nmerge = 256 / nm;
    double* src = (L % 2 == 0) ? Qe : Q2;
    double* dst = (L % 2 == 0) ? Q2 : Qe;
    int gScan = (64 * nmerge + 63) / 64;
    merge_scan_kernel<<<dim3(64, nmerge), 256, 0, stream>>>(nm, nmerge, src, dE, eE, indxq,
                                                            dlamda_g, w_g, rho_g, surv_g, defl_g, Kb);
    secular_kernel<<<64, 256, 0, stream>>>(nm, nmerge, dlamda_g, w_g, rho_g, Kb, dE, tau_g, orig_g);
    zhat_kernel<<<64, 256, 0, stream>>>(nm, nmerge, dlamda_g, w_g, tau_g, orig_g, Kb, zhat_g);
    coeff_kernel<<<64, 256, 0, stream>>>(nm, nmerge, dlamda_g, zhat_g, tau_g, orig_g, Kb, Cbuf);
    int tcnt = nm / 32;
    merge_gemm_kernel<<<dim3(64, nmerge, tcnt * tcnt), 256, 0, stream>>>(nm, nmerge, src, Cbuf,
                                                                         surv_g, Kb, dst);
    defl_copy_kernel<<<dim3(64, nmerge), 256, 0, stream>>>(nm, nmerge, src, defl_g, Kb, dst);
    dlamrg_kernel<<<gScan, 64, 0, stream>>>(nm, nmerge, dE, Kb, indxq);
  }
  // final eigvecs in Qe; back-transform ranks 2..9 -> E
  dormtr_kernel<<<64, 256, 0, stream>>>(covA, tauE, Qe, indxq, E);
  // anchor MLP
  gemm(E, anch_w1, anch_b1, nullptr, Eh, 512, 256, 256, 0, 1, 0);
  gemm(Eh, anch_w2, anch_b2, nullptr, E2, 512, 256, 256, 0, 0, 0);
  // z projection
  zproj_kernel<<<64, 256, 0, stream>>>(fnp, E2, z);
  // template slots + quantization
  gemm(emb, wq, bq, nullptr, tslots, 64, 512, 512, 0, 0, 0);
  d2_kernel<<<512, 64, 0, stream>>>(z, tslots, sdist, idxr);
  order_kernel<<<1, 64, 0, stream>>>(sdist, idxr, fidx, out_idx);
  slots0_kernel<<<1024, 256, 0, stream>>>(z, emb, fidx, sA);
  qloss_kernel<<<1, 256, 0, stream>>>(z, tslots, fidx, out_qloss);
  // slot attention iterations
  for (int it = 0; it < 3; ++it) {
    rowln_kernel<<<512, 256, 0, stream>>>(sA, ns_g, ns_b, lnbuf);
    gemm(lnbuf, wq, bq, nullptr, qbuf, 512, 512, 512, 0, 0, 0);
    dots_kernel<<<dim3(64, 4), 256, 0, stream>>>(qbuf, kbuf, dotsb);
    softmax_kernel<<<64, 256, 0, stream>>>(dotsb, attnb);
    asum_kernel<<<512, 64, 0, stream>>>(attnb, asumb);
    updates_kernel<<<64, 256, 0, stream>>>(attnb, asumb, vbuf, updb);
    gemm(updb, gru_wih, gru_bih, nullptr, gib, 512, 1536, 512, 1, 0, 0);
    gemm(sA, gru_whh, gru_bhh, nullptr, ghb, 512, 1536, 512, 1, 0, 0);
    gru_kernel<<<1024, 256, 0, stream>>>(gib, ghb, sA, sB);
    rowln_kernel<<<512, 256, 0, stream>>>(sB, npf_g, npf_b, lnbuf);
    gemm(lnbuf, mlp_w1, mlp_b1, nullptr, hidb, 512, 512, 512, 0, 1, 0);
    gemm(hidb, mlp_w2, mlp_b2, sB, sA, 512, 512, 512, 0, 0, 1);
  }
  // outputs
  feats_kernel<<<262144, 64, 0, stream>>>(sA, dposT, out);
  hipMemcpyAsync(out_slots, sA, 262144 * 4, hipMemcpyDeviceToDevice, stream);
}

// Round 6
// 14083.916 us; speedup vs baseline: 1.2832x; 1.0111x over previous
//
#include <hip/hip_runtime.h>
#include <math.h>
#include <stdint.h>

// ---------------------------------------------------------------------------
// SlotAttention forward. Correctness-first implementation.
// Core difficulty: replicate LAPACK dsyevd (numpy eigh) including eigenvector
// SIGN conventions: dsytd2 + D&C (tear -> dsteqr(16) leaves -> dlaed1/2/3
// merges) + reflector back-transform of the 8 needed columns. All f64.
// R1: leaf_kernel arrays scratch->LDS (swizzled) + fused rotation apply.
// R2: dsytrd wave-parallel matvec/rank-2; 128x128 f32 GEMM (bit-identical k).
// R3: merge_scan block-per-merge LDS + deferred rotations; zproj coalesced.
// R5: fused-lazy dsytrd (1 pending) - bit-identical to R2, passed.
// R6: TWO-deep lazy dsytrd (write trailing matrix every other step; read-steps
//     correct in registers with the same fl-op sequence -> bit-identical);
//     gemm_f32_big 4+4 split tiles (bank-conflict-free, same k-order);
//     GEMM routing: big path only when >=128 blocks (utilization).
// ---------------------------------------------------------------------------

#define NB 64
#define ND 512
#define NN_ 256
#define NSL 8
#define LPB 24  // leaves per block in leaf_kernel; LDS = 24*(256+33)*8 = 55.5KB

static __device__ __forceinline__ double fsign(double a, double b) {
  return (b >= 0.0) ? fabs(a) : -fabs(a);
}
static __device__ __forceinline__ double dlapy2d(double x, double y) {
  double ax = fabs(x), ay = fabs(y);
  double w = ax > ay ? ax : ay, z = ax > ay ? ay : ax;
  if (z == 0.0) return w;
  double q = z / w;
  return w * sqrt(1.0 + q * q);
}
#define EPS_D 1.1102230246251565e-16

// LAPACK >= 3.10 dlartg convention (modern numpy/OpenBLAS)
static __device__ void dlartgd(double f, double g, double& cs, double& sn, double& r) {
  if (g == 0.0) { cs = 1.0; sn = 0.0; r = f; }
  else if (f == 0.0) { cs = 0.0; sn = fsign(1.0, g); r = fabs(g); }
  else {
    double f1 = fabs(f);
    double d = sqrt(f * f + g * g);
    cs = f1 / d;
    r = fsign(d, f);
    sn = g / r;
  }
}

static __device__ void dlaev2d(double a, double b, double c, double& rt1, double& rt2,
                               double& cs1, double& sn1) {
  double sm = a + c, df = a - c, adf = fabs(df), tb = b + b, ab = fabs(tb);
  double acmx, acmn;
  if (fabs(a) > fabs(c)) { acmx = a; acmn = c; } else { acmx = c; acmn = a; }
  double rt;
  if (adf > ab) { double q = ab / adf; rt = adf * sqrt(1.0 + q * q); }
  else if (adf < ab) { double q = adf / ab; rt = ab * sqrt(1.0 + q * q); }
  else rt = ab * sqrt(2.0);
  int sgn1;
  if (sm < 0.0) { rt1 = 0.5 * (sm - rt); sgn1 = -1; rt2 = (acmx / rt1) * acmn - (b / rt1) * b; }
  else if (sm > 0.0) { rt1 = 0.5 * (sm + rt); sgn1 = 1; rt2 = (acmx / rt1) * acmn - (b / rt1) * b; }
  else { rt1 = 0.5 * rt; rt2 = -0.5 * rt; sgn1 = 1; }
  double cs; int sgn2;
  if (df >= 0.0) { cs = df + rt; sgn2 = 1; } else { cs = df - rt; sgn2 = -1; }
  double acs = fabs(cs);
  if (acs > ab) { double ct = -tb / cs; sn1 = 1.0 / sqrt(1.0 + ct * ct); cs1 = ct * sn1; }
  else {
    if (ab == 0.0) { cs1 = 1.0; sn1 = 0.0; }
    else { double tn = -cs / tb; cs1 = 1.0 / sqrt(1.0 + tn * tn); sn1 = tn * cs1; }
  }
  if (sgn1 == sgn2) { double tn = cs1; cs1 = -sn1; sn1 = tn; }
}

// dsteqr COMPZ='I', n=16, faithful port (1-based d[1..16], e[1..15]).
// Arrays in LDS; Z XOR-swizzled; rotation apply fused (identical order).
static __device__ void dsteqr16_lds(double* dd, double* ee, double* zz, int sw) {
  const int n = 16;
#define ZM(i, j) zz[((((i)-1) << 4) + ((j)-1)) ^ sw]
#define D_(i) dd[(i)]
#define E_(i) ee[(i)]
  for (int i = 1; i <= n; ++i)
    for (int j = 1; j <= n; ++j) ZM(i, j) = (i == j) ? 1.0 : 0.0;
  const double eps = EPS_D, eps2 = eps * eps, safmin = 2.2250738585072014e-308;
  int nmaxit = n * 30, jtot = 0, l1 = 1;
  while (l1 <= n) {
    if (l1 > 1) E_(l1 - 1) = 0.0;
    int m = n;
    for (int mm = l1; mm <= n - 1; ++mm) {
      double tst = fabs(E_(mm));
      if (tst == 0.0) { m = mm; break; }
      if (tst <= (sqrt(fabs(D_(mm))) * sqrt(fabs(D_(mm + 1)))) * eps) { E_(mm) = 0.0; m = mm; break; }
    }
    int l = l1, lsv = l, lend = m, lendsv = m;
    l1 = m + 1;
    if (lend == l) continue;
    double anorm = 0.0;
    for (int i = l; i <= lend; ++i) anorm = fmax(anorm, fabs(D_(i)));
    for (int i = l; i <= lend - 1; ++i) anorm = fmax(anorm, fabs(E_(i)));
    if (anorm == 0.0) continue;
    if (fabs(D_(lend)) < fabs(D_(l))) { lend = lsv; l = lendsv; }
    if (lend > l) {  // QL
      for (;;) {
        int m2 = lend;
        if (l != lend) {
          for (int mm = l; mm <= lend - 1; ++mm) {
            double tst = E_(mm) * E_(mm);
            if (tst <= (eps2 * fabs(D_(mm))) * fabs(D_(mm + 1)) + safmin) { m2 = mm; break; }
          }
        }
        if (m2 < lend) E_(m2) = 0.0;
        double p = D_(l);
        if (m2 == l) { D_(l) = p; ++l; if (l > lend) break; continue; }
        if (m2 == l + 1) {
          double rt1, rt2, c, s;
          dlaev2d(D_(l), E_(l), D_(l + 1), rt1, rt2, c, s);
          for (int i = 1; i <= n; ++i) {
            double tmp = ZM(i, l + 1);
            ZM(i, l + 1) = c * tmp - s * ZM(i, l);
            ZM(i, l) = s * tmp + c * ZM(i, l);
          }
          D_(l) = rt1; D_(l + 1) = rt2; E_(l) = 0.0;
          l += 2; if (l > lend) break; continue;
        }
        if (jtot == nmaxit) break;
        ++jtot;
        double g = (D_(l + 1) - p) / (2.0 * E_(l));
        double r = dlapy2d(g, 1.0);
        g = D_(m2) - p + E_(l) / (g + fsign(r, g));
        double s = 1.0, c = 1.0; p = 0.0;
        for (int i = m2 - 1; i >= l; --i) {
          double f = s * E_(i), bb = c * E_(i);
          dlartgd(g, f, c, s, r);
          if (i != m2 - 1) E_(i + 1) = r;
          g = D_(i + 1) - p;
          r = (D_(i) - g) * s + 2.0 * c * bb;
          p = s * r;
          D_(i + 1) = g + p;
          g = c * r - bb;
          double cj = c, sj = -s;
          for (int i2 = 1; i2 <= n; ++i2) {
            double tmp = ZM(i2, i + 1);
            ZM(i2, i + 1) = cj * tmp - sj * ZM(i2, i);
            ZM(i2, i) = sj * tmp + cj * ZM(i2, i);
          }
        }
        D_(l) -= p; E_(l) = g;
      }
    } else {  // QR
      for (;;) {
        int m2 = lend;
        if (l != lend) {
          for (int mm = l; mm >= lend + 1; --mm) {
            double tst = E_(mm - 1) * E_(mm - 1);
            if (tst <= (eps2 * fabs(D_(mm))) * fabs(D_(mm - 1)) + safmin) { m2 = mm; break; }
          }
        }
        if (m2 > lend) E_(m2 - 1) = 0.0;
        double p = D_(l);
        if (m2 == l) { D_(l) = p; --l; if (l < lend) break; continue; }
        if (m2 == l - 1) {
          double rt1, rt2, c, s;
          dlaev2d(D_(l - 1), E_(l - 1), D_(l), rt1, rt2, c, s);
          for (int i = 1; i <= n; ++i) {
            double tmp = ZM(i, l);
            ZM(i, l) = c * tmp - s * ZM(i, l - 1);
            ZM(i, l - 1) = s * tmp + c * ZM(i, l - 1);
          }
          D_(l - 1) = rt1; D_(l) = rt2; E_(l - 1) = 0.0;
          l -= 2; if (l < lend) break; continue;
        }
        if (jtot == nmaxit) break;
        ++jtot;
        double g = (D_(l - 1) - p) / (2.0 * E_(l - 1));
        double r = dlapy2d(g, 1.0);
        g = D_(m2) - p + E_(l - 1) / (g + fsign(r, g));
        double s = 1.0, c = 1.0; p = 0.0;
        for (int i = m2; i <= l - 1; ++i) {
          double f = s * E_(i), bb = c * E_(i);
          dlartgd(g, f, c, s, r);
          if (i != m2) E_(i - 1) = r;
          g = D_(i) - p;
          r = (D_(i + 1) - g) * s + 2.0 * c * bb;
          p = s * r;
          D_(i) = g + p;
          g = c * r - bb;
          double cj = c, sj = s;
          for (int i2 = 1; i2 <= n; ++i2) {
            double tmp = ZM(i2, i + 1);
            ZM(i2, i + 1) = cj * tmp - sj * ZM(i2, i);
            ZM(i2, i) = sj * tmp + cj * ZM(i2, i);
          }
        }
        D_(l) -= p; E_(l - 1) = g;
      }
    }
  }
  for (int ii = 2; ii <= n; ++ii) {
    int i = ii - 1, k = i;
    double p = D_(i);
    for (int j = ii; j <= n; ++j)
      if (D_(j) < p) { k = j; p = D_(j); }
    if (k != i) {
      D_(k) = D_(i); D_(i) = p;
      for (int r = 1; r <= n; ++r) { double t = ZM(r, i); ZM(r, i) = ZM(r, k); ZM(r, k) = t; }
    }
  }
#undef ZM
#undef D_
#undef E_
}

static __device__ void dlamrg_dev(int n1v, int n2v, const double* a, int strd1, int strd2, int* index) {
  int n1sv = n1v, n2sv = n2v;
  int ind1 = (strd1 > 0) ? 1 : n1v;
  int ind2 = (strd2 > 0) ? n1v + 1 : n1v + n2v;
  int i = 1;
  while (n1sv > 0 && n2sv > 0) {
    if (a[ind1] <= a[ind2]) { index[i++] = ind1; ind1 += strd1; --n1sv; }
    else { index[i++] = ind2; ind2 += strd2; --n2sv; }
  }
  if (n1sv == 0) { while (n2sv > 0) { index[i++] = ind2; ind2 += strd2; --n2sv; } }
  else { while (n1sv > 0) { index[i++] = ind1; ind1 += strd1; --n1sv; } }
}

// -------------------------------- kernels ----------------------------------

__global__ __launch_bounds__(256) void pos_kernel(const float* __restrict__ w,
                                                  const float* __restrict__ bias,
                                                  float* __restrict__ posT) {
  int idx = blockIdx.x * 256 + threadIdx.x;
  if (idx >= 512 * 256) return;
  int d = idx / 256, n = idx % 256;
  int i = n / 16, j = n % 16;
  double step = 1.0 / 15.0;
  float gi = (i == 15) ? 1.0f : (float)(i * step);
  float gj = (j == 15) ? 1.0f : (float)(j * step);
  float v = gi * w[0 * 512 + d] + gj * w[1 * 512 + d] + (1.0f - gi) * w[2 * 512 + d] +
            (1.0f - gj) * w[3 * 512 + d] + bias[d];
  posT[(size_t)d * 256 + n] = v;
}

__global__ __launch_bounds__(256) void stats_kernel(const float* __restrict__ x,
                                                    const float* __restrict__ posT,
                                                    float* mean_o, float* rstd_o, int addpos) {
  int b = blockIdx.x, t = threadIdx.x;
  __shared__ double r1[256], r2[256];
  double s = 0.0, ss = 0.0;
  const float* xb = x + (size_t)b * 131072;
  for (int i = t; i < 131072; i += 256) {
    float v = xb[i];
    if (addpos) v += posT[i];
    s += v; ss += (double)v * v;
  }
  r1[t] = s; r2[t] = ss; __syncthreads();
  for (int o = 128; o > 0; o >>= 1) { if (t < o) { r1[t] += r1[t + o]; r2[t] += r2[t + o]; } __syncthreads(); }
  if (t == 0) {
    double m = r1[0] / 131072.0;
    double var = r2[0] / 131072.0 - m * m;
    mean_o[b] = (float)m;
    rstd_o[b] = 1.0f / sqrtf((float)var + 1e-5f);
  }
}

__global__ __launch_bounds__(256) void tln_kernel(const float* __restrict__ x,
                                                  const float* __restrict__ posT,
                                                  const float* __restrict__ g,
                                                  const float* __restrict__ be,
                                                  const float* m1, const float* r1,
                                                  const float* m2, const float* r2,
                                                  float* __restrict__ fnp,
                                                  float* __restrict__ fpln) {
  int b = blockIdx.x, dt = blockIdx.y, nt = blockIdx.z;
  __shared__ float t1[32][33], t2[32][33];
  int t = threadIdx.x;
  const float* xb = x + (size_t)b * 131072;
  for (int l = 0; l < 4; ++l) {
    int idx = t + l * 256;
    int row = idx >> 5, col = idx & 31;
    int dd = dt * 32 + row, nn = nt * 32 + col;
    float v = xb[(size_t)dd * 256 + nn];
    t1[row][col] = v;
    t2[row][col] = v + posT[(size_t)dd * 256 + nn];
  }
  __syncthreads();
  float mm1 = m1[b], rr1 = r1[b], mm2 = m2[b], rr2 = r2[b];
  for (int l = 0; l < 4; ++l) {
    int idx = t + l * 256;
    int row = idx >> 5, col = idx & 31;
    int nn = nt * 32 + row, dd = dt * 32 + col;
    float gg = g[(size_t)nn * 512 + dd], bb = be[(size_t)nn * 512 + dd];
    size_t o = (size_t)b * 131072 + (size_t)nn * 512 + dd;
    fnp[o] = (t1[col][row] - mm1) * rr1 * gg + bb;
    fpln[o] = (t2[col][row] - mm2) * rr2 * gg + bb;
  }
}

__global__ __launch_bounds__(256) void gemm_f32(const float* __restrict__ A,
                                                const float* __restrict__ Bm,
                                                const float* __restrict__ bias,
                                                const float* __restrict__ base,
                                                float* __restrict__ C, int M, int Nc, int Kd,
                                                int bt, int act, int addb) {
  __shared__ float As[16][65];
  __shared__ float Bs[16][65];
  int bm = blockIdx.x * 64, bn = blockIdx.y * 64;
  int t = threadIdx.x;
  int tx = t & 15, ty = t >> 4;
  float acc[4][4] = {};
  for (int k0 = 0; k0 < Kd; k0 += 16) {
    for (int l = 0; l < 4; ++l) {
      int idx = t + l * 256;
      { int r = idx >> 4, kk = idx & 15;
        float v = 0.f;
        if (bm + r < M && k0 + kk < Kd) v = A[(size_t)(bm + r) * Kd + k0 + kk];
        As[kk][r] = v; }
      if (bt == 0) {
        int kk = idx >> 6, nn = idx & 63;
        float v = 0.f;
        if (k0 + kk < Kd && bn + nn < Nc) v = Bm[(size_t)(k0 + kk) * Nc + bn + nn];
        Bs[kk][nn] = v;
      } else {
        int nn = idx >> 4, kk = idx & 15;
        float v = 0.f;
        if (bn + nn < Nc && k0 + kk < Kd) v = Bm[(size_t)(bn + nn) * Kd + k0 + kk];
        Bs[kk][nn] = v;
      }
    }
    __syncthreads();
#pragma unroll
    for (int kk = 0; kk < 16; ++kk) {
      float a0[4], b0[4];
#pragma unroll
      for (int q = 0; q < 4; ++q) a0[q] = As[kk][ty * 4 + q];
#pragma unroll
      for (int q = 0; q < 4; ++q) b0[q] = Bs[kk][tx * 4 + q];
#pragma unroll
      for (int q = 0; q < 4; ++q)
#pragma unroll
        for (int p = 0; p < 4; ++p) acc[q][p] += a0[q] * b0[p];
    }
    __syncthreads();
  }
  for (int q = 0; q < 4; ++q) {
    int r = bm + ty * 4 + q;
    if (r >= M) continue;
    for (int p = 0; p < 4; ++p) {
      int c = bn + tx * 4 + p;
      if (c >= Nc) continue;
      float v = acc[q][p];
      if (bias) v += bias[c];
      if (act == 1) v = fmaxf(v, 0.f);
      if (addb) v += base[(size_t)r * Nc + c];
      C[(size_t)r * Nc + c] = v;
    }
  }
}

// 128x128 tile, 8x8 acc/thread via 4+4 split sub-tiles (rows ty*4 & 64+ty*4,
// cols tx*4 & 64+tx*4) -> 16B LDS reads at 16B stride = 2-way bank alias
// (free) instead of the 32B-stride 4-way conflict. Per-output k-accumulation
// unchanged (ascending k, single accumulator) -> bit-identical results.
// M%128==0, Nc%128==0, Kd%16==0.
__global__ __launch_bounds__(256) void gemm_f32_big(const float* __restrict__ A,
                                                    const float* __restrict__ Bm,
                                                    const float* __restrict__ bias,
                                                    const float* __restrict__ base,
                                                    float* __restrict__ C, int M, int Nc, int Kd,
                                                    int bt, int act, int addb) {
  __shared__ float As[16][128];
  __shared__ float Bs[16][128];
  int bm = blockIdx.x * 128, bn = blockIdx.y * 128;
  int t = threadIdx.x;
  int tx = t & 15, ty = t >> 4;
  int lrow = t >> 1, lseg = (t & 1) * 8;
  float acc[8][8] = {};
  for (int k0 = 0; k0 < Kd; k0 += 16) {
    {
      const float* src = A + (size_t)(bm + lrow) * Kd + k0 + lseg;
      float4 p0 = *(const float4*)src;
      float4 p1 = *(const float4*)(src + 4);
      As[lseg + 0][lrow] = p0.x; As[lseg + 1][lrow] = p0.y;
      As[lseg + 2][lrow] = p0.z; As[lseg + 3][lrow] = p0.w;
      As[lseg + 4][lrow] = p1.x; As[lseg + 5][lrow] = p1.y;
      As[lseg + 6][lrow] = p1.z; As[lseg + 7][lrow] = p1.w;
    }
    if (bt == 0) {
      int bk = t >> 4, bcol = (t & 15) * 8;
      const float* src = Bm + (size_t)(k0 + bk) * Nc + bn + bcol;
      float4 p0 = *(const float4*)src;
      float4 p1 = *(const float4*)(src + 4);
      *(float4*)&Bs[bk][bcol] = p0;
      *(float4*)&Bs[bk][bcol + 4] = p1;
    } else {
      const float* src = Bm + (size_t)(bn + lrow) * Kd + k0 + lseg;
      float4 p0 = *(const float4*)src;
      float4 p1 = *(const float4*)(src + 4);
      Bs[lseg + 0][lrow] = p0.x; Bs[lseg + 1][lrow] = p0.y;
      Bs[lseg + 2][lrow] = p0.z; Bs[lseg + 3][lrow] = p0.w;
      Bs[lseg + 4][lrow] = p1.x; Bs[lseg + 5][lrow] = p1.y;
      Bs[lseg + 6][lrow] = p1.z; Bs[lseg + 7][lrow] = p1.w;
    }
    __syncthreads();
#pragma unroll
    for (int kk = 0; kk < 16; ++kk) {
      float a0[8], b0[8];
#pragma unroll
      for (int q = 0; q < 4; ++q) { a0[q] = As[kk][ty * 4 + q]; a0[4 + q] = As[kk][64 + ty * 4 + q]; }
#pragma unroll
      for (int p = 0; p < 4; ++p) { b0[p] = Bs[kk][tx * 4 + p]; b0[4 + p] = Bs[kk][64 + tx * 4 + p]; }
#pragma unroll
      for (int q = 0; q < 8; ++q)
#pragma unroll
        for (int p = 0; p < 8; ++p) acc[q][p] += a0[q] * b0[p];
    }
    __syncthreads();
  }
  for (int q = 0; q < 8; ++q) {
    int r = bm + ((q < 4) ? (ty * 4 + q) : (64 + ty * 4 + (q - 4)));
#pragma unroll
    for (int p = 0; p < 8; ++p) {
      int c = bn + ((p < 4) ? (tx * 4 + p) : (64 + tx * 4 + (p - 4)));
      float vv = acc[q][p];
      if (bias) vv += bias[c];
      if (act == 1) vv = fmaxf(vv, 0.f);
      if (addb) vv += base[(size_t)r * Nc + c];
      C[(size_t)r * Nc + c] = vv;
    }
  }
}

__global__ __launch_bounds__(256) void rowln_kernel(const float* __restrict__ in,
                                                    const float* __restrict__ g,
                                                    const float* __restrict__ be,
                                                    float* __restrict__ out) {
  int r = blockIdx.x, t = threadIdx.x;
  __shared__ double s1[256], s2[256];
  const float* row = in + (size_t)r * 512;
  float v0 = row[t], v1 = row[t + 256];
  s1[t] = (double)v0 + (double)v1;
  s2[t] = (double)v0 * v0 + (double)v1 * v1;
  __syncthreads();
  for (int o = 128; o > 0; o >>= 1) { if (t < o) { s1[t] += s1[t + o]; s2[t] += s2[t + o]; } __syncthreads(); }
  double m = s1[0] / 512.0, var = s2[0] / 512.0 - m * m;
  float rstd = 1.0f / sqrtf((float)var + 1e-5f);
  float mf = (float)m;
  out[(size_t)r * 512 + t] = (v0 - mf) * rstd * g[t] + be[t];
  out[(size_t)r * 512 + t + 256] = (v1 - mf) * rstd * g[t + 256] + be[t + 256];
}

__global__ __launch_bounds__(256) void xnorm_kernel(float* kno) {
  int r = blockIdx.x, t = threadIdx.x;
  __shared__ double s1[256];
  float* row = kno + (size_t)r * 512;
  float v0 = row[t], v1 = row[t + 256];
  s1[t] = (double)v0 * v0 + (double)v1 * v1;
  __syncthreads();
  for (int o = 128; o > 0; o >>= 1) { if (t < o) s1[t] += s1[t + o]; __syncthreads(); }
  float nrm = fmaxf((float)sqrt(s1[0]), 1e-12f);
  row[t] = v0 / nrm; row[t + 256] = v1 / nrm;
}

__global__ __launch_bounds__(256) void cov_kernel(const float* __restrict__ xn, double* __restrict__ cov) {
  int b = blockIdx.x, it = blockIdx.y, jt = blockIdx.z;
  __shared__ float Xi[64][65], Xj[64][65];
  int t = threadIdx.x;
  int tx = t & 15, ty = t >> 4;
  double acc[4][4] = {};
  const float* xb = xn + (size_t)b * 131072;
  for (int f0 = 0; f0 < 512; f0 += 64) {
    for (int l = 0; l < 16; ++l) {
      int idx = t + l * 256;
      int r = idx >> 6, ff = idx & 63;
      Xi[r][ff] = xb[(size_t)(it * 64 + r) * 512 + f0 + ff];
      Xj[r][ff] = xb[(size_t)(jt * 64 + r) * 512 + f0 + ff];
    }
    __syncthreads();
    for (int ff = 0; ff < 64; ++ff) {
      double a0[4], b0[4];
#pragma unroll
      for (int q = 0; q < 4; ++q) { a0[q] = (double)Xi[ty * 4 + q][ff]; b0[q] = (double)Xj[tx * 4 + q][ff]; }
#pragma unroll
      for (int q = 0; q < 4; ++q)
#pragma unroll
        for (int p = 0; p < 4; ++p) acc[q][p] += a0[q] * b0[p];
    }
    __syncthreads();
  }
  double* cb = cov + (size_t)b * 65536;
  for (int q = 0; q < 4; ++q)
    for (int p = 0; p < 4; ++p)
      cb[(size_t)(it * 64 + ty * 4 + q) * 256 + jt * 64 + tx * 4 + p] = acc[q][p];
}

// Two-deep lazy Householder tridiagonalization. Up to TWO pending rank-2
// updates; trailing matrix written only when two are pending (every other
// step). Read-steps correct in registers with the same fl-op sequence the
// write-through path produces (fl(fl(a-u1)-u2)) -> bit-identical to R5/R2.
// Each u_k is applied exactly once per element: columns finalize at their
// Phase 0 (active pendings applied there); flush passes cover cols >= f+1
// which excludes all finalized columns. 1024 threads = 16 waves.
__global__ __launch_bounds__(1024) void dsytrd_kernel(double* Aall, double* dE, double* eE,
                                                      double* tauE) {
  int b = blockIdx.x, t = threadIdx.x;
  int lane = t & 63, wid = t >> 6;
  double* A = Aall + (size_t)b * 65536;
  __shared__ double bufA[256], bufB[256], bufC[256], bufD[256], bufE[256], bufF[256];
  __shared__ double v2[256];
  __shared__ double redw[16];
  const int n = 256;
  double* v = bufA;   double* w = bufB;    // current reflector / w-vector
  double* vp1 = bufC; double* wp1 = bufD;  // older pending
  double* vp2 = bufE; double* wp2 = bufF;  // newer pending
  int cnt = 0;
  for (int i = 0; i < n - 1; ++i) {
    // Phase 0: corrected column i -> v2 (+ write). Older pending first —
    // identical per-element fl sequence as write-through.
    for (int r = i + t; r < n; r += 1024) {
      double a = A[(size_t)r * 256 + i];
      if (cnt >= 1) {
        a = a - (vp1[r] * wp1[i] + wp1[r] * vp1[i]);
        if (cnt == 2) a = a - (vp2[r] * wp2[i] + wp2[r] * vp2[i]);
        A[(size_t)r * 256 + i] = a;
      }
      v2[r] = a;
    }
    __syncthreads();  // B0
    // norm below subdiagonal (R2 mapping r = i+2+t)
    double s = 0.0;
    for (int r = i + 2 + t; r < n; r += 1024) { double xv = v2[r]; s += xv * xv; }
    for (int o = 1; o < 64; o <<= 1) s += __shfl_xor(s, o);
    if (lane == 0) redw[wid] = s;
    __syncthreads();  // B1
    double xns = 0.0;
    for (int k = 0; k < 16; ++k) xns += redw[k];
    double alpha = v2[i + 1];
    double tau, beta, scl;
    if (xns == 0.0) { tau = 0.0; beta = alpha; scl = 0.0; }
    else {
      double xnorm = sqrt(xns);
      double rr = dlapy2d(alpha, xnorm);
      beta = (alpha >= 0.0) ? -rr : rr;
      tau = (beta - alpha) / beta;
      scl = 1.0 / (alpha - beta);
    }
    if (tau != 0.0) {
      int dow = (cnt == 2);
      // v setup (R2 mapping r = i+1+t)
      for (int r = i + 1 + t; r < n; r += 1024) {
        double vr = (r == i + 1) ? 1.0 : v2[r] * scl;
        v[r] = vr;
        if (r >= i + 2) A[(size_t)r * 256 + i] = vr;
      }
      __syncthreads();  // B2
      // Phase E: apply pendings (write only when two) + matvec.
      // Wave per row (stride 16), lanes over columns (stride 64).
      for (int r = i + 1 + wid; r < n; r += 16) {
        double* Ar = A + (size_t)r * 256;
        double acc = 0.0;
        if (cnt == 2) {
          double v1r = vp1[r], w1r = wp1[r], v2r = vp2[r], w2r = wp2[r];
          for (int c = i + 1 + lane; c < n; c += 64) {
            double a = Ar[c] - (v1r * wp1[c] + w1r * vp1[c]);
            a = a - (v2r * wp2[c] + w2r * vp2[c]);
            Ar[c] = a;
            acc += a * v[c];
          }
        } else if (cnt == 1) {
          double v1r = vp1[r], w1r = wp1[r];
          for (int c = i + 1 + lane; c < n; c += 64) {
            double a = Ar[c] - (v1r * wp1[c] + w1r * vp1[c]);
            acc += a * v[c];
          }
        } else {
          for (int c = i + 1 + lane; c < n; c += 64) acc += Ar[c] * v[c];
        }
        for (int o = 1; o < 64; o <<= 1) acc += __shfl_xor(acc, o);
        if (lane == 0) w[r] = tau * acc;
      }
      __syncthreads();  // B3
      // dot = w.v (R2 mapping)
      double sd = 0.0;
      for (int r = i + 1 + t; r < n; r += 1024) sd += w[r] * v[r];
      for (int o = 1; o < 64; o <<= 1) sd += __shfl_xor(sd, o);
      if (lane == 0) redw[wid] = sd;
      __syncthreads();  // B4
      double dot = 0.0;
      for (int k = 0; k < 16; ++k) dot += redw[k];
      double alpha2 = -0.5 * tau * dot;
      for (int r = i + 1 + t; r < n; r += 1024) w[r] += alpha2 * v[r];
      if (t == 0) { eE[b * 256 + i] = beta; tauE[b * 256 + i] = tau; }
      __syncthreads();  // B5
      // rotate pendings (uniform per-thread bookkeeping)
      if (dow) {
        double* tv = v; v = vp1; vp1 = tv;
        double* tw = w; w = wp1; wp1 = tw;
        cnt = 1;  // p1,p2 applied; current becomes the only pending
      } else if (cnt == 0) {
        double* tv = v; v = vp1; vp1 = tv;
        double* tw = w; w = wp1; wp1 = tw;
        cnt = 1;
      } else {  // cnt == 1 read-step: current becomes newer pending
        double* tv = v; v = vp2; vp2 = tv;
        double* tw = w; w = wp2; wp2 = tw;
        cnt = 2;
      }
    } else {
      // no new reflector: flush any pendings into trailing square now
      if (cnt >= 1) {
        for (int r = i + 1 + wid; r < n; r += 16) {
          double* Ar = A + (size_t)r * 256;
          double v1r = vp1[r], w1r = wp1[r];
          double v2r = (cnt == 2) ? vp2[r] : 0.0, w2r = (cnt == 2) ? wp2[r] : 0.0;
          for (int c = i + 1 + lane; c < n; c += 64) {
            double a = Ar[c] - (v1r * wp1[c] + w1r * vp1[c]);
            if (cnt == 2) a = a - (v2r * wp2[c] + w2r * vp2[c]);
            Ar[c] = a;
          }
        }
      }
      if (t == 0) { eE[b * 256 + i] = beta; tauE[b * 256 + i] = tau; }
      __syncthreads();
      cnt = 0;
    }
  }
  // dE from diagonal; last element may still carry pending corrections.
  for (int r = t; r < n; r += 1024) {
    double dd = A[(size_t)r * 256 + r];
    if (r == n - 1) {
      if (cnt >= 1) dd = dd - (vp1[r] * wp1[r] + wp1[r] * vp1[r]);
      if (cnt == 2) dd = dd - (vp2[r] * wp2[r] + wp2[r] * vp2[r]);
    }
    dE[b * 256 + r] = dd;
  }
}

__global__ __launch_bounds__(64) void tear_kernel(double* dE, const double* eE) {
  int b = threadIdx.x;
  if (b >= 64) return;
  for (int m = 1; m < 16; ++m) {
    int p = m * 16 - 1;
    double ae = fabs(eE[b * 256 + p]);
    dE[b * 256 + p] -= ae;
    dE[b * 256 + p + 1] -= ae;
  }
}

// One leaf per thread; Z (16x16) + d/e in LDS, XOR-swizzled.
__global__ __launch_bounds__(64) void leaf_kernel(double* dE, double* eE, double* Qe, int* indxq) {
  __shared__ double Zs[LPB * 256];
  __shared__ double des[LPB * 33];
  int t = threadIdx.x;
  int g = blockIdx.x * LPB + t;
  if (t >= LPB || g >= 1024) return;
  int b = g >> 4, lf = g & 15, off = lf * 16;
  double* zz = Zs + t * 256;
  double* dd = des + t * 33;
  double* ee = dd + 16;
  int sw = t & 15;
  for (int i = 1; i <= 16; ++i) dd[i] = dE[b * 256 + off + i - 1];
  for (int i = 1; i <= 15; ++i) ee[i] = eE[b * 256 + off + i - 1];
  ee[16] = 0.0;
  dsteqr16_lds(dd, ee, zz, sw);
  for (int i = 1; i <= 16; ++i) dE[b * 256 + off + i - 1] = dd[i];
  double* Qb = Qe + (size_t)b * 65536;
  for (int r = 0; r < 16; ++r)
    for (int c = 0; c < 16; ++c) Qb[(size_t)(off + r) * 256 + off + c] = zz[((r << 4) + c) ^ sw];
  for (int i = 0; i < 16; ++i) indxq[b * 256 + off + i] = i + 1;
}

// dlaed2 deflation scan. Block per (b, merge): serial scan on thread 0 with
// all arrays in LDS; Givens rotations deferred to a list (scan never reads Q
// after z extraction) and applied block-parallel row-partitioned afterwards.
__global__ __launch_bounds__(256) void merge_scan_kernel(int nm, int nmerge, double* Qsrc, double* dE,
                                                         const double* eE, int* indxq,
                                                         double* dlamda_g, double* w_g, double* rho_g,
                                                         int* surv_g, int* defl_g, int* Kb) {
  int b = blockIdx.x, mg = blockIdx.y;
  int off = mg * nm, n1 = nm / 2, n2 = nm - n1;
  double* Q = Qsrc + (size_t)b * 65536;
  double* dg = dE + b * 256 + off;
  int* iqg = indxq + b * 256 + off;
  int t = threadIdx.x;

  __shared__ double dl[257], zl[257], dlamA[257], wl2[257];
  __shared__ int iq[257], indxc[257], indxl[257], indxpl[257];
  __shared__ double rotc[256], rots[256];
  __shared__ int rotp[256], rotn[256];
  __shared__ int sh_nrot, sh_K, sh_zero;

  for (int ii = 1 + t; ii <= nm; ii += 256) { dl[ii] = dg[ii - 1]; iq[ii] = iqg[ii - 1]; }
  __syncthreads();

  if (t == 0) {
    double rho = eE[b * 256 + off + n1 - 1];
    for (int j = 1; j <= n1; ++j) zl[j] = Q[(size_t)(off + n1 - 1) * 256 + off + j - 1];
    for (int j = 1; j <= n2; ++j) zl[n1 + j] = Q[(size_t)(off + n1) * 256 + off + n1 + j - 1];
    if (rho < 0.0)
      for (int j = n1 + 1; j <= nm; ++j) zl[j] = -zl[j];
    double tconst = 1.0 / sqrt(2.0);
    for (int j = 1; j <= nm; ++j) zl[j] *= tconst;
    rho = fabs(2.0 * rho);
    rho_g[b * nmerge + mg] = rho;
    for (int i = n1 + 1; i <= nm; ++i) iq[i] += n1;
    for (int i = 1; i <= nm; ++i) dlamA[i] = dl[iq[i]];
    dlamrg_dev(n1, n2, dlamA, 1, 1, indxc);
    for (int i = 1; i <= nm; ++i) indxl[i] = iq[indxc[i]];
    int imax = 1, jmax = 1;
    for (int i = 2; i <= nm; ++i) {
      if (fabs(zl[i]) > fabs(zl[imax])) imax = i;
      if (fabs(dl[i]) > fabs(dl[jmax])) jmax = i;
    }
    double tol = 8.0 * EPS_D * fmax(fabs(dl[jmax]), fabs(zl[imax]));
    if (rho * fabs(zl[imax]) <= tol) {
      sh_K = 0; sh_zero = 1; sh_nrot = 0;
    } else {
      sh_zero = 0;
      int nrot = 0;
      int K = 0, K2 = nm + 1, pj = 0, j = 1;
      bool havepj = false;
      for (j = 1; j <= nm; ++j) {
        int nj = indxl[j];
        if (rho * fabs(zl[nj]) <= tol) {
          K2--; indxpl[K2] = nj;
          if (j == nm) break;
        } else { pj = nj; havepj = true; break; }
      }
      if (havepj) {
        for (;;) {
          j = j + 1;
          if (j > nm) break;
          int nj = indxl[j];
          if (rho * fabs(zl[nj]) <= tol) { K2--; indxpl[K2] = nj; }
          else {
            double s_ = zl[pj], c_ = zl[nj];
            double tau_ = dlapy2d(c_, s_);
            double t_ = dl[nj] - dl[pj];
            c_ = c_ / tau_; s_ = -s_ / tau_;
            if (fabs(t_ * c_ * s_) <= tol) {
              zl[nj] = tau_; zl[pj] = 0.0;
              rotp[nrot] = pj; rotn[nrot] = nj; rotc[nrot] = c_; rots[nrot] = s_; ++nrot;
              double t2 = dl[pj] * c_ * c_ + dl[nj] * s_ * s_;
              dl[nj] = dl[pj] * s_ * s_ + dl[nj] * c_ * c_;
              dl[pj] = t2;
              K2--;
              int i_ = 1;
              for (;;) {
                if (K2 + i_ <= nm) {
                  if (dl[pj] < dl[indxpl[K2 + i_]]) {
                    indxpl[K2 + i_ - 1] = indxpl[K2 + i_];
                    indxpl[K2 + i_] = pj;
                    i_++;
                  } else { indxpl[K2 + i_ - 1] = pj; break; }
                } else { indxpl[K2 + i_ - 1] = pj; break; }
              }
              pj = nj;
            } else {
              K++; dlamA[K] = dl[pj]; wl2[K] = zl[pj]; indxpl[K] = pj; pj = nj;
            }
          }
        }
        K++; dlamA[K] = dl[pj]; wl2[K] = zl[pj]; indxpl[K] = pj;
      }
      sh_K = K; sh_nrot = nrot;
    }
  }
  __syncthreads();
  int nrot = sh_nrot, K = sh_K;
  // apply deferred rotations in order; rows partitioned across threads
  for (int r = t; r < nm; r += 256) {
    size_t rowb = (size_t)(off + r) * 256;
    for (int k = 0; k < nrot; ++k) {
      int cp = off + rotp[k] - 1, cn = off + rotn[k] - 1;
      double c_ = rotc[k], s_ = rots[k];
      double x = Q[rowb + cp], y = Q[rowb + cn];
      Q[rowb + cp] = c_ * x + s_ * y;
      Q[rowb + cn] = c_ * y - s_ * x;
    }
  }
  if (sh_zero) {
    if (t == 0) Kb[b * nmerge + mg] = 0;
    for (int j = 1 + t; j <= nm; j += 256) {
      int il = indxl[j];
      defl_g[b * 256 + off + j - 1] = il;
      dg[j - 1] = dl[il];
      iqg[j - 1] = j;
    }
  } else {
    if (t == 0) Kb[b * nmerge + mg] = K;
    for (int i = 1 + t; i <= K; i += 256) {
      dlamda_g[b * 256 + off + i - 1] = dlamA[i];
      w_g[b * 256 + off + i - 1] = wl2[i];
      surv_g[b * 256 + off + i - 1] = indxpl[i];
    }
    for (int jj = K + 1 + t; jj <= nm; jj += 256) {
      defl_g[b * 256 + off + jj - 1] = indxpl[jj];
      dg[jj - 1] = dl[indxpl[jj]];
    }
  }
}

// secular solver (dlaed4-equivalent, bisection)
__global__ __launch_bounds__(256) void secular_kernel(int nm, int nmerge, const double* dlamda_g,
                                                      const double* w_g, const double* rho_g,
                                                      const int* Kb, double* dE, double* tau_g,
                                                      int* orig_g) {
  int b = blockIdx.x, pos = threadIdx.x;
  int mg = pos / nm, jl = pos % nm + 1;
  int K = Kb[b * nmerge + mg];
  if (jl > K) return;
  int base = b * 256 + mg * nm;
  const double* dl = dlamda_g + base;
  const double* w = w_g + base;
  double rho = rho_g[b * nmerge + mg];
  int orig; double lo, hi;
  if (jl < K) {
    double dj = dl[jl - 1], dj1 = dl[jl];
    double mid = (dj + dj1) * 0.5;
    double acc = 0.0;
    for (int i = 0; i < K; ++i) acc += w[i] * w[i] / (dl[i] - mid);
    double fmid = 1.0 + rho * acc;
    if (fmid > 0.0) { orig = jl; lo = 0.0; hi = mid - dj; }
    else { orig = jl + 1; lo = mid - dj1; hi = 0.0; }
  } else {
    orig = K;
    double zs = 0.0;
    for (int i = 0; i < K; ++i) zs += w[i] * w[i];
    lo = 0.0; hi = rho * zs;
  }
  double dorig = dl[orig - 1];
  for (int it = 0; it < 100; ++it) {
    double tm = 0.5 * (lo + hi);
    if (tm == lo || tm == hi) break;
    double acc = 0.0;
    for (int i = 0; i < K; ++i) acc += w[i] * w[i] / ((dl[i] - dorig) - tm);
    double g = 1.0 + rho * acc;
    if (g > 0.0) hi = tm; else lo = tm;
  }
  double tau = 0.5 * (lo + hi);
  tau_g[base + jl - 1] = tau;
  orig_g[base + jl - 1] = orig;
  dE[base + jl - 1] = dorig + tau;
}

__global__ __launch_bounds__(256) void zhat_kernel(int nm, int nmerge, const double* dlamda_g,
                                                   const double* w_g, const double* tau_g,
                                                   const int* orig_g, const int* Kb, double* zhat_g) {
  int b = blockIdx.x, pos = threadIdx.x;
  int mg = pos / nm, il = pos % nm + 1;
  int K = Kb[b * nmerge + mg];
  if (il > K) return;
  int base = b * 256 + mg * nm;
  const double* dl = dlamda_g + base;
  double di = dl[il - 1];
  double p = (di - dl[orig_g[base + il - 1] - 1]) - tau_g[base + il - 1];
  for (int jj = 1; jj <= K; ++jj) {
    if (jj == il) continue;
    double del = (di - dl[orig_g[base + jj - 1] - 1]) - tau_g[base + jj - 1];
    p *= del / (di - dl[jj - 1]);
  }
  double val = sqrt(fmax(-p, 0.0));
  zhat_g[base + il - 1] = fsign(val, w_g[base + il - 1]);
}

__global__ __launch_bounds__(256) void coeff_kernel(int nm, int nmerge, const double* dlamda_g,
                                                    const double* zhat_g, const double* tau_g,
                                                    const int* orig_g, const int* Kb, double* Cbuf) {
  int b = blockIdx.x, pos = threadIdx.x;
  int mg = pos / nm, jl = pos % nm + 1;
  int K = Kb[b * nmerge + mg];
  if (jl > K) return;
  int off = mg * nm, base = b * 256 + off;
  double* C = Cbuf + (size_t)b * 65536;
  const double* dl = dlamda_g + base;
  if (K == 1) { C[(size_t)off * 256 + off + jl - 1] = 1.0; return; }
  double dorig = dl[orig_g[base + jl - 1] - 1];
  double tau = tau_g[base + jl - 1];
  double ss = 0.0;
  for (int i = 1; i <= K; ++i) {
    double del = (dl[i - 1] - dorig) - tau;
    double ci = zhat_g[base + i - 1] / del;
    C[(size_t)(off + i - 1) * 256 + off + jl - 1] = ci;
    ss += ci * ci;
  }
  double inv = 1.0 / sqrt(ss);
  for (int i = 1; i <= K; ++i) C[(size_t)(off + i - 1) * 256 + off + jl - 1] *= inv;
}

__global__ __launch_bounds__(64) void dlamrg_kernel(int nm, int nmerge, const double* dE,
                                                    const int* Kb, int* indxq) {
  int gid = blockIdx.x * 64 + threadIdx.x;
  if (gid >= 64 * nmerge) return;
  int b = gid / nmerge, mg = gid % nmerge;
  int off = mg * nm;
  int K = Kb[b * nmerge + mg];
  int* iqg = indxq + b * 256 + off;
  if (K == 0) return;  // identity already set by scan
  const double* dg = dE + b * 256 + off;
  int n1sv = K, n2sv = nm - K;
  int ind1 = 1, ind2 = nm;
  int i = 1;
  int idx[257];
  while (n1sv > 0 && n2sv > 0) {
    if (dg[ind1 - 1] <= dg[ind2 - 1]) { idx[i++] = ind1; ind1++; n1sv--; }
    else { idx[i++] = ind2; ind2--; n2sv--; }
  }
  if (n1sv == 0) { while (n2sv > 0) { idx[i++] = ind2; ind2--; n2sv--; } }
  else { while (n1sv > 0) { idx[i++] = ind1; ind1++; n1sv--; } }
  for (int t = 1; t <= nm; ++t) iqg[t - 1] = idx[t];
}

__global__ __launch_bounds__(256) void merge_gemm_kernel(int nm, int nmerge, const double* Qsrc,
                                                         const double* Cbuf, const int* surv_g,
                                                         const int* Kb, double* Qdst) {
  int b = blockIdx.x, mg = blockIdx.y;
  int tcnt = nm / 32;
  int rt = blockIdx.z / tcnt, ct = blockIdx.z % tcnt;
  int off = mg * nm;
  int K = Kb[b * nmerge + mg];
  if (ct * 32 >= K) return;
  __shared__ double Qs[32][33];
  __shared__ double Cs[32][33];
  __shared__ int svs[32];
  int t = threadIdx.x;
  int tc = t & 31, tr = t >> 5;
  const double* Qsb = Qsrc + (size_t)b * 65536;
  const double* Cb = Cbuf + (size_t)b * 65536;
  double acc[4] = {0, 0, 0, 0};
  int r0 = off + rt * 32, c0 = off + ct * 32;
  for (int i0 = 0; i0 < K; i0 += 32) {
    if (t < 32) svs[t] = (i0 + t < K) ? surv_g[b * 256 + off + i0 + t] : 0;
    __syncthreads();
    for (int l = 0; l < 4; ++l) {
      int idx = t + l * 256;
      int r = idx >> 5, ii = idx & 31;
      int sc = svs[ii];
      Qs[r][ii] = (sc > 0) ? Qsb[(size_t)(r0 + r) * 256 + off + sc - 1] : 0.0;
      Cs[r][ii] = (i0 + r < K && ct * 32 + ii < K) ? Cb[(size_t)(off + i0 + r) * 256 + c0 + ii] : 0.0;
    }
    __syncthreads();
    for (int ii = 0; ii < 32; ++ii) {
      double cv = Cs[ii][tc];
#pragma unroll
      for (int q = 0; q < 4; ++q) acc[q] += Qs[tr * 4 + q][ii] * cv;
    }
    __syncthreads();
  }
  if (ct * 32 + tc < K) {
    double* Qd = Qdst + (size_t)b * 65536;
    for (int q = 0; q < 4; ++q) Qd[(size_t)(r0 + tr * 4 + q) * 256 + c0 + tc] = acc[q];
  }
}

// deflated-column copy, row-parallel (each thread owns rows; loops columns)
__global__ __launch_bounds__(256) void defl_copy_kernel(int nm, int nmerge, const double* Qsrc,
                                                        const int* defl_g, const int* Kb,
                                                        double* Qdst) {
  int b = blockIdx.x, mg = blockIdx.y;
  int off = mg * nm;
  int K = Kb[b * nmerge + mg];
  int t = threadIdx.x;
  const double* Qs = Qsrc + (size_t)b * 65536;
  double* Qd = Qdst + (size_t)b * 65536;
  for (int r = t; r < nm; r += 256) {
    const double* Qsr = Qs + (size_t)(off + r) * 256;
    double* Qdr = Qd + (size_t)(off + r) * 256;
    for (int jl = K + 1; jl <= nm; ++jl)
      Qdr[off + jl - 1] = Qsr[off + defl_g[b * 256 + off + jl - 1] - 1];
  }
}

// gather ranks 2..9, apply Householder back-transform, emit E (f32, [b][s][n])
__global__ __launch_bounds__(256) void dormtr_kernel(const double* Aall, const double* tauE,
                                                     const double* Qe, const int* indxq, float* E) {
  int b = blockIdx.x, t = threadIdx.x;
  const double* A = Aall + (size_t)b * 65536;
  __shared__ double U[256][8];
  __shared__ double wred[32][8];
  __shared__ double wfin[8];
  __shared__ int sel[8];
  if (t < 8) sel[t] = indxq[b * 256 + 1 + t] - 1;
  __syncthreads();
  for (int i = t; i < 256 * 8; i += 256) {
    int r = i >> 3, c = i & 7;
    U[r][c] = Qe[(size_t)b * 65536 + (size_t)r * 256 + sel[c]];
  }
  __syncthreads();
  int lane = t & 31, col = t >> 5;
  for (int s = 254; s >= 0; --s) {
    double tv = tauE[b * 256 + s];
    if (tv == 0.0) continue;
    double acc = (lane == 0) ? U[s + 1][col] : 0.0;
    for (int r = s + 2 + lane; r < 256; r += 32) acc += A[(size_t)r * 256 + s] * U[r][col];
    wred[lane][col] = acc;
    __syncthreads();
    if (t < 8) { double a = 0.0; for (int l2 = 0; l2 < 32; ++l2) a += wred[l2][t]; wfin[t] = a; }
    __syncthreads();
    double wc = wfin[col] * tv;
    if (lane == 0) U[s + 1][col] -= wc;
    for (int r = s + 2 + lane; r < 256; r += 32) U[r][col] -= A[(size_t)r * 256 + s] * wc;
    __syncthreads();
  }
  for (int i = t; i < 8 * 256; i += 256) {
    int s = i >> 8, nn = i & 255;
    E[((size_t)b * 8 + s) * 256 + nn] = (float)U[nn][s];
  }
}

// z = E2 . fnp, coalesced streaming of fnp rows; per-output accumulation order
// identical to the original column-wise version (ascending n) -> bit-identical.
__global__ __launch_bounds__(256) void zproj_kernel(const float* __restrict__ fnp,
                                                    const float* __restrict__ E2,
                                                    float* __restrict__ z) {
  int b = blockIdx.x, t = threadIdx.x;
  __shared__ float er[8][256];
  for (int i = t; i < 8 * 256; i += 256) er[i >> 8][i & 255] = E2[(size_t)b * 2048 + i];
  __syncthreads();
  for (int d0 = 0; d0 < 512; d0 += 256) {
    int d = d0 + t;
    float a0 = 0.f, a1 = 0.f, a2 = 0.f, a3 = 0.f, a4 = 0.f, a5 = 0.f, a6 = 0.f, a7 = 0.f;
    for (int n = 0; n < 256; ++n) {
      float f = fnp[((size_t)b * 256 + n) * 512 + d];
      a0 += er[0][n] * f; a1 += er[1][n] * f; a2 += er[2][n] * f; a3 += er[3][n] * f;
      a4 += er[4][n] * f; a5 += er[5][n] * f; a6 += er[6][n] * f; a7 += er[7][n] * f;
    }
    z[((size_t)b * 8 + 0) * 512 + d] = a0;
    z[((size_t)b * 8 + 1) * 512 + d] = a1;
    z[((size_t)b * 8 + 2) * 512 + d] = a2;
    z[((size_t)b * 8 + 3) * 512 + d] = a3;
    z[((size_t)b * 8 + 4) * 512 + d] = a4;
    z[((size_t)b * 8 + 5) * 512 + d] = a5;
    z[((size_t)b * 8 + 6) * 512 + d] = a6;
    z[((size_t)b * 8 + 7) * 512 + d] = a7;
  }
}

__global__ __launch_bounds__(64) void d2_kernel(const float* __restrict__ z,
                                                const float* __restrict__ ts, double* sdist,
                                                int* idxr) {
  int row = blockIdx.x;
  int lane = threadIdx.x;
  const float* zr = z + (size_t)row * 512;
  const float* tr = ts + (size_t)lane * 512;
  double zz = 0, zt = 0, tt = 0;
  for (int d = 0; d < 512; ++d) {
    double zv = zr[d], tv = tr[d];
    zz += zv * zv; zt += zv * tv; tt += tv * tv;
  }
  double d2 = zz + tt - 2.0 * zt;
  int best = lane; double bv = d2;
  for (int off = 32; off > 0; off >>= 1) {
    double ov = __shfl_down(bv, off);
    int oi = __shfl_down(best, off);
    if (ov < bv || (ov == bv && oi < best)) { bv = ov; best = oi; }
  }
  if (lane == 0) { sdist[row] = bv; idxr[row] = best; }
}

__global__ __launch_bounds__(64) void order_kernel(const double* sdist, const int* idxr, int* fidx,
                                                   float* out_idx) {
  int b = threadIdx.x;
  if (b >= 64) return;
  double sd[8]; int ord[8];
  for (int s = 0; s < 8; ++s) { sd[s] = sdist[b * 8 + s]; ord[s] = s; }
  for (int a = 1; a < 8; ++a) {
    double kv = sd[a]; int ko = ord[a]; int c = a - 1;
    while (c >= 0 && sd[c] > kv) { sd[c + 1] = sd[c]; ord[c + 1] = ord[c]; --c; }
    sd[c + 1] = kv; ord[c + 1] = ko;
  }
  for (int s = 0; s < 8; ++s) {
    int fi = idxr[ord[s]];  // cross-batch quirk: always batch 0's argmins
    fidx[b * 8 + s] = fi;
    out_idx[b * 8 + s] = (float)fi;
  }
}

__global__ __launch_bounds__(256) void slots0_kernel(const float* z, const float* emb,
                                                     const int* fidx, float* slots) {
  int i = blockIdx.x * 256 + threadIdx.x;
  if (i >= 512 * 512) return;
  int t = i / 512, d = i % 512;
  float zv = z[i];
  float zq = emb[fidx[t] * 512 + d];
  slots[i] = zv + (zq - zv);
}

__global__ __launch_bounds__(256) void qloss_kernel(const float* z, const float* ts, const int* fidx,
                                                    float* out) {
  __shared__ double red[256];
  int t = threadIdx.x;
  double acc = 0.0;
  for (int i = t; i < 512 * 512; i += 256) {
    int r = i / 512, d = i % 512;
    float diff = ts[fidx[r] * 512 + d] - z[i];
    acc += (double)diff * (double)diff;
  }
  red[t] = acc; __syncthreads();
  for (int o = 128; o > 0; o >>= 1) { if (t < o) red[t] += red[t + o]; __syncthreads(); }
  if (t == 0) {
    float a = (float)(red[0] / 64.0);
    out[0] = a + 0.99f * a;
  }
}

__global__ __launch_bounds__(256) void dots_kernel(const float* __restrict__ q,
                                                   const float* __restrict__ k,
                                                   float* __restrict__ dots) {
  int b = blockIdx.x, jt = blockIdx.y;
  __shared__ float qs[8][513];
  __shared__ float kc[64][33];
  int t = threadIdx.x;
  for (int i = t; i < 8 * 512; i += 256) qs[i / 512][i % 512] = q[((size_t)b * 8 + i / 512) * 512 + i % 512];
  int j = t % 64, ig = t / 64;
  float acc0 = 0.f, acc1 = 0.f;
  for (int d0 = 0; d0 < 512; d0 += 32) {
    __syncthreads();
    for (int l = 0; l < 8; ++l) {
      int idx = t + l * 256;
      int r = idx >> 5, dd = idx & 31;
      kc[r][dd] = k[((size_t)b * 256 + jt * 64 + r) * 512 + d0 + dd];
    }
    __syncthreads();
    for (int dd = 0; dd < 32; ++dd) {
      float kv = kc[j][dd];
      acc0 += qs[ig * 2][d0 + dd] * kv;
      acc1 += qs[ig * 2 + 1][d0 + dd] * kv;
    }
  }
  const float scale = (float)(1.0 / sqrt(512.0));
  dots[((size_t)b * 8 + ig * 2) * 256 + jt * 64 + j] = acc0 * scale;
  dots[((size_t)b * 8 + ig * 2 + 1) * 256 + jt * 64 + j] = acc1 * scale;
}

__global__ __launch_bounds__(256) void softmax_kernel(const float* dots, float* attn) {
  int b = blockIdx.x, j = threadIdx.x;
  float v[8]; float mx = -1e30f;
  for (int i = 0; i < 8; ++i) { v[i] = dots[((size_t)b * 8 + i) * 256 + j]; mx = fmaxf(mx, v[i]); }
  float s = 0.f;
  for (int i = 0; i < 8; ++i) { v[i] = expf(v[i] - mx); s += v[i]; }
  for (int i = 0; i < 8; ++i) attn[((size_t)b * 8 + i) * 256 + j] = v[i] / s;
}

__global__ __launch_bounds__(64) void asum_kernel(const float* attn, float* asum) {
  int bi = blockIdx.x, lane = threadIdx.x;
  float s = 0.f;
  for (int j = lane; j < 256; j += 64) s += attn[(size_t)bi * 256 + j] + 1e-8f;
  for (int off = 32; off > 0; off >>= 1) s += __shfl_down(s, off);
  if (lane == 0) asum[bi] = s;
}

__global__ __launch_bounds__(256) void updates_kernel(const float* attn, const float* asum,
                                                      const float* v, float* upd) {
  int b = blockIdx.x;
  __shared__ float at[8][257];
  int t = threadIdx.x;
  for (int i = t; i < 8 * 256; i += 256) {
    int ii = i / 256, j = i % 256;
    at[ii][j] = (attn[((size_t)b * 8 + ii) * 256 + j] + 1e-8f) / asum[b * 8 + ii];
  }
  __syncthreads();
  for (int d = t; d < 512; d += 256) {
    float acc[8] = {0, 0, 0, 0, 0, 0, 0, 0};
    for (int j = 0; j < 256; ++j) {
      float vv = v[((size_t)b * 256 + j) * 512 + d];
#pragma unroll
      for (int ii = 0; ii < 8; ++ii) acc[ii] += at[ii][j] * vv;
    }
    for (int ii = 0; ii < 8; ++ii) upd[((size_t)b * 8 + ii) * 512 + d] = acc[ii];
  }
}

__global__ __launch_bounds__(256) void gru_kernel(const float* gi, const float* gh, const float* h,
                                                  float* out) {
  int i = blockIdx.x * 256 + threadIdx.x;
  if (i >= 512 * 512) return;
  int t = i / 512, d = i % 512;
  const float* gir = gi + (size_t)t * 1536;
  const float* ghr = gh + (size_t)t * 1536;
  float r = 1.f / (1.f + expf(-(gir[d] + ghr[d])));
  float zg = 1.f / (1.f + expf(-(gir[512 + d] + ghr[512 + d])));
  float n = tanhf(gir[1024 + d] + r * ghr[1024 + d]);
  out[i] = (1.f - zg) * n + zg * h[i];
}

__global__ __launch_bounds__(64) void feats_kernel(const float* slots, const float* dposT,
                                                   float* out) {
  int blk = blockIdx.x;  // bs*512 + d
  int bs = blk >> 9, d = blk & 511;
  float s = slots[(size_t)bs * 512 + d];
  const float* dp = dposT + (size_t)d * 256;
  int n0 = threadIdx.x * 4;
  float4 o;
  o.x = s + dp[n0]; o.y = s + dp[n0 + 1]; o.z = s + dp[n0 + 2]; o.w = s + dp[n0 + 3];
  *(float4*)(out + (size_t)blk * 256 + n0) = o;
}

// ------------------------------ host driver --------------------------------

extern "C" void kernel_launch(void* const* d_in, const int* in_sizes, int n_in, void* d_out,
                              int out_size, void* d_ws, size_t ws_size, hipStream_t stream) {
  const float* x = (const float*)d_in[0];
  const float* enc_pos_w = (const float*)d_in[1];
  const float* enc_pos_b = (const float*)d_in[2];
  const float* enc_norm_g = (const float*)d_in[3];
  const float* enc_norm_b = (const float*)d_in[4];
  const float* enc_mlp_w1 = (const float*)d_in[5];
  const float* enc_mlp_b1 = (const float*)d_in[6];
  const float* enc_mlp_w2 = (const float*)d_in[7];
  const float* enc_mlp_b2 = (const float*)d_in[8];
  const float* anch_w1 = (const float*)d_in[9];
  const float* anch_b1 = (const float*)d_in[10];
  const float* anch_w2 = (const float*)d_in[11];
  const float* anch_b2 = (const float*)d_in[12];
  const float* wq = (const float*)d_in[13];
  const float* bq = (const float*)d_in[14];
  const float* wk = (const float*)d_in[15];
  const float* bk = (const float*)d_in[16];
  const float* wv = (const float*)d_in[17];
  const float* bv = (const float*)d_in[18];
  const float* gru_wih = (const float*)d_in[19];
  const float* gru_whh = (const float*)d_in[20];
  const float* gru_bih = (const float*)d_in[21];
  const float* gru_bhh = (const float*)d_in[22];
  const float* mlp_w1 = (const float*)d_in[23];
  const float* mlp_b1 = (const float*)d_in[24];
  const float* mlp_w2 = (const float*)d_in[25];
  const float* mlp_b2 = (const float*)d_in[26];
  const float* ni_g = (const float*)d_in[27];
  const float* ni_b = (const float*)d_in[28];
  const float* ns_g = (const float*)d_in[29];
  const float* ns_b = (const float*)d_in[30];
  const float* npf_g = (const float*)d_in[31];
  const float* npf_b = (const float*)d_in[32];
  const float* emb = (const float*)d_in[33];
  const float* dec_pos_w = (const float*)d_in[34];
  const float* dec_pos_b = (const float*)d_in[35];

  float* out = (float*)d_out;
  const size_t FEATS = (size_t)512 * 512 * 256;  // 67108864
  float* out_slots = out + FEATS;
  float* out_idx = out + FEATS + 262144;
  float* out_qloss = out + FEATS + 262144 + 512;

  // workspace layout
  char* ws = (char*)d_ws;
  size_t off = 0;
  auto alloc = [&](size_t bytes) { size_t o = off; off = (off + bytes + 255) & ~(size_t)255; return (void*)(ws + o); };
  const size_t S = (size_t)64 * 256 * 512 * 4;  // 33554432
  float* fnp = (float*)alloc(S);
  float* R2 = (float*)alloc(S);  // kno/xn -> later Cbuf(f64)
  float* R3 = (float*)alloc(S);  // fpln -> later covA(f64)
  float* R4 = (float*)alloc(S);  // h1 -> later Qe(f64)
  float* R5 = (float*)alloc(S);  // fp -> later Q2(f64)
  float* kbuf = (float*)alloc(S);
  float* vbuf = (float*)alloc(S);
  float* posT = (float*)alloc(512 * 256 * 4);
  float* dposT = (float*)alloc(512 * 256 * 4);
  float* m1 = (float*)alloc(64 * 4);
  float* r1 = (float*)alloc(64 * 4);
  float* m2 = (float*)alloc(64 * 4);
  float* r2 = (float*)alloc(64 * 4);
  double* dE = (double*)alloc(64 * 256 * 8);
  double* eE = (double*)alloc(64 * 256 * 8);
  double* tauE = (double*)alloc(64 * 256 * 8);
  double* dlamda_g = (double*)alloc(64 * 256 * 8);
  double* w_g = (double*)alloc(64 * 256 * 8);
  double* zhat_g = (double*)alloc(64 * 256 * 8);
  double* tau_g = (double*)alloc(64 * 256 * 8);
  double* rho_g = (double*)alloc(64 * 8 * 8);
  int* indxq = (int*)alloc(64 * 256 * 4);
  int* surv_g = (int*)alloc(64 * 256 * 4);
  int* defl_g = (int*)alloc(64 * 256 * 4);
  int* orig_g = (int*)alloc(64 * 256 * 4);
  int* Kb = (int*)alloc(64 * 8 * 4);
  int* fidx = (int*)alloc(512 * 4);
  float* E = (float*)alloc(64 * 8 * 256 * 4);
  float* Eh = (float*)alloc(64 * 8 * 256 * 4);
  float* E2 = (float*)alloc(64 * 8 * 256 * 4);
  float* z = (float*)alloc(512 * 512 * 4);
  float* tslots = (float*)alloc(64 * 512 * 4);
  double* sdist = (double*)alloc(512 * 8);
  int* idxr = (int*)alloc(512 * 4);
  float* sA = (float*)alloc(512 * 512 * 4);
  float* sB = (float*)alloc(512 * 512 * 4);
  float* lnbuf = (float*)alloc(512 * 512 * 4);
  float* qbuf = (float*)alloc(512 * 512 * 4);
  float* dotsb = (float*)alloc(64 * 8 * 256 * 4);
  float* attnb = (float*)alloc(64 * 8 * 256 * 4);
  float* asumb = (float*)alloc(64 * 8 * 4);
  float* updb = (float*)alloc(512 * 512 * 4);
  float* gib = (float*)alloc((size_t)512 * 1536 * 4);
  float* ghb = (float*)alloc((size_t)512 * 1536 * 4);
  float* hidb = (float*)alloc(512 * 512 * 4);
  (void)ws_size; (void)in_sizes; (void)n_in; (void)out_size;

  auto gemm = [&](const float* A, const float* Bm, const float* bias, const float* base, float* C,
                  int M, int Nc, int Kd, int bt, int act, int addb) {
    // big path only when it yields enough blocks to fill the chip; else the
    // 64-tile kernel (more blocks). Both accumulate ascending-k with a single
    // accumulator per output -> identical results either way.
    if ((M % 128) == 0 && (Nc % 128) == 0 && (Kd % 16) == 0 &&
        (M / 128) * (Nc / 128) >= 128) {
      dim3 g(M / 128, Nc / 128);
      gemm_f32_big<<<g, 256, 0, stream>>>(A, Bm, bias, base, C, M, Nc, Kd, bt, act, addb);
    } else {
      dim3 g((M + 63) / 64, (Nc + 63) / 64);
      gemm_f32<<<g, 256, 0, stream>>>(A, Bm, bias, base, C, M, Nc, Kd, bt, act, addb);
    }
  };

  // positional embeddings (transposed [d][n])
  pos_kernel<<<(131072 + 255) / 256, 256, 0, stream>>>(enc_pos_w, enc_pos_b, posT);
  pos_kernel<<<(131072 + 255) / 256, 256, 0, stream>>>(dec_pos_w, dec_pos_b, dposT);
  // batch LN stats over (N,D)
  stats_kernel<<<64, 256, 0, stream>>>(x, posT, m1, r1, 0);
  stats_kernel<<<64, 256, 0, stream>>>(x, posT, m2, r2, 1);
  // transpose + LN -> fnp, fpln
  tln_kernel<<<dim3(64, 16, 8), 256, 0, stream>>>(x, posT, enc_norm_g, enc_norm_b, m1, r1, m2, r2,
                                                  fnp, R3);
  // k_nopos
  gemm(fnp, wk, bk, nullptr, R2, 16384, 512, 512, 0, 0, 0);
  // encoder MLP + ni LN -> fp (R5)
  gemm(R3, enc_mlp_w1, enc_mlp_b1, nullptr, R4, 16384, 512, 512, 0, 1, 0);
  gemm(R4, enc_mlp_w2, enc_mlp_b2, nullptr, R5, 16384, 512, 512, 0, 0, 0);
  rowln_kernel<<<16384, 256, 0, stream>>>(R5, ni_g, ni_b, R5);
  gemm(R5, wk, bk, nullptr, kbuf, 16384, 512, 512, 0, 0, 0);
  gemm(R5, wv, bv, nullptr, vbuf, 16384, 512, 512, 0, 0, 0);
  // xn + cov (f64) into R3 region
  xnorm_kernel<<<16384, 256, 0, stream>>>(R2);
  double* covA = (double*)R3;
  cov_kernel<<<dim3(64, 4, 4), 256, 0, stream>>>(R2, covA);
  // eigensolver buffers
  double* Qe = (double*)R4;
  double* Q2 = (double*)R5;
  double* Cbuf = (double*)R2;
  hipMemsetAsync(Qe, 0, S, stream);
  hipMemsetAsync(Q2, 0, S, stream);
  dsytrd_kernel<<<64, 1024, 0, stream>>>(covA, dE, eE, tauE);
  tear_kernel<<<1, 64, 0, stream>>>(dE, eE);
  leaf_kernel<<<(1024 + LPB - 1) / LPB, LPB, 0, stream>>>(dE, eE, Qe, indxq);
  for (int L = 0; L < 4; ++L) {
    int nm = 32 << L;
    int nmerge = 256 / nm;
    double* src = (L % 2 == 0) ? Qe : Q2;
    double* dst = (L % 2 == 0) ? Q2 : Qe;
    int gScan = (64 * nmerge + 63) / 64;
    merge_scan_kernel<<<dim3(64, nmerge), 256, 0, stream>>>(nm, nmerge, src, dE, eE, indxq,
                                                            dlamda_g, w_g, rho_g, surv_g, defl_g, Kb);
    secular_kernel<<<64, 256, 0, stream>>>(nm, nmerge, dlamda_g, w_g, rho_g, Kb, dE, tau_g, orig_g);
    zhat_kernel<<<64, 256, 0, stream>>>(nm, nmerge, dlamda_g, w_g, tau_g, orig_g, Kb, zhat_g);
    coeff_kernel<<<64, 256, 0, stream>>>(nm, nmerge, dlamda_g, zhat_g, tau_g, orig_g, Kb, Cbuf);
    int tcnt = nm / 32;
    merge_gemm_kernel<<<dim3(64, nmerge, tcnt * tcnt), 256, 0, stream>>>(nm, nmerge, src, Cbuf,
                                                                         surv_g, Kb, dst);
    defl_copy_kernel<<<dim3(64, nmerge), 256, 0, stream>>>(nm, nmerge, src, defl_g, Kb, dst);
    dlamrg_kernel<<<gScan, 64, 0, stream>>>(nm, nmerge, dE, Kb, indxq);
  }
  // final eigvecs in Qe; back-transform ranks 2..9 -> E
  dormtr_kernel<<<64, 256, 0, stream>>>(covA, tauE, Qe, indxq, E);
  // anchor MLP
  gemm(E, anch_w1, anch_b1, nullptr, Eh, 512, 256, 256, 0, 1, 0);
  gemm(Eh, anch_w2, anch_b2, nullptr, E2, 512, 256, 256, 0, 0, 0);
  // z projection
  zproj_kernel<<<64, 256, 0, stream>>>(fnp, E2, z);
  // template slots + quantization
  gemm(emb, wq, bq, nullptr, tslots, 64, 512, 512, 0, 0, 0);
  d2_kernel<<<512, 64, 0, stream>>>(z, tslots, sdist, idxr);
  order_kernel<<<1, 64, 0, stream>>>(sdist, idxr, fidx, out_idx);
  slots0_kernel<<<1024, 256, 0, stream>>>(z, emb, fidx, sA);
  qloss_kernel<<<1, 256, 0, stream>>>(z, tslots, fidx, out_qloss);
  // slot attention iterations
  for (int it = 0; it < 3; ++it) {
    rowln_kernel<<<512, 256, 0, stream>>>(sA, ns_g, ns_b, lnbuf);
    gemm(lnbuf, wq, bq, nullptr, qbuf, 512, 512, 512, 0, 0, 0);
    dots_kernel<<<dim3(64, 4), 256, 0, stream>>>(qbuf, kbuf, dotsb);
    softmax_kernel<<<64, 256, 0, stream>>>(dotsb, attnb);
    asum_kernel<<<512, 64, 0, stream>>>(attnb, asumb);
    updates_kernel<<<64, 256, 0, stream>>>(attnb, asumb, vbuf, updb);
    gemm(updb, gru_wih, gru_bih, nullptr, gib, 512, 1536, 512, 1, 0, 0);
    gemm(sA, gru_whh, gru_bhh, nullptr, ghb, 512, 1536, 512, 1, 0, 0);
    gru_kernel<<<1024, 256, 0, stream>>>(gib, ghb, sA, sB);
    rowln_kernel<<<512, 256, 0, stream>>>(sB, npf_g, npf_b, lnbuf);
    gemm(lnbuf, mlp_w1, mlp_b1, nullptr, hidb, 512, 512, 512, 0, 1, 0);
    gemm(hidb, mlp_w2, mlp_b2, sB, sA, 512, 512, 512, 0, 0, 1);
  }
  // outputs
  feats_kernel<<<262144, 64, 0, stream>>>(sA, dposT, out);
  hipMemcpyAsync(out_slots, sA, 262144 * 4, hipMemcpyDeviceToDevice, stream);
}

// Round 7
// 14029.118 us; speedup vs baseline: 1.2882x; 1.0039x over previous
//
#include <hip/hip_runtime.h>
#include <math.h>
#include <stdint.h>

// ---------------------------------------------------------------------------
// SlotAttention forward. Correctness-first implementation.
// Core difficulty: replicate LAPACK dsyevd (numpy eigh) including eigenvector
// SIGN conventions: dsytd2 + D&C (tear -> dsteqr(16) leaves -> dlaed1/2/3
// merges) + reflector back-transform of the 8 needed columns. All f64.
// R1: leaf_kernel arrays scratch->LDS (swizzled) + fused rotation apply.
// R2: dsytrd wave-parallel matvec/rank-2; 128x128 f32 GEMM (bit-identical k).
// R3: merge_scan block-per-merge LDS + deferred rotations; zproj coalesced.
// R5: fused-lazy dsytrd (1 pending). R6: two-deep lazy + 4+4 split GEMM.
// R7: gemm_f32_big BK=32 (half the barriers; same ascending-k accumulation ->
//     bit-identical); dsytrd Phase 0 reads ROW i (coalesced; A is bitwise
//     symmetric, corrections commute bitwise) and writes dE inline.
// ---------------------------------------------------------------------------

#define NB 64
#define ND 512
#define NN_ 256
#define NSL 8
#define LPB 24  // leaves per block in leaf_kernel; LDS = 24*(256+33)*8 = 55.5KB

static __device__ __forceinline__ double fsign(double a, double b) {
  return (b >= 0.0) ? fabs(a) : -fabs(a);
}
static __device__ __forceinline__ double dlapy2d(double x, double y) {
  double ax = fabs(x), ay = fabs(y);
  double w = ax > ay ? ax : ay, z = ax > ay ? ay : ax;
  if (z == 0.0) return w;
  double q = z / w;
  return w * sqrt(1.0 + q * q);
}
#define EPS_D 1.1102230246251565e-16

// LAPACK >= 3.10 dlartg convention (modern numpy/OpenBLAS)
static __device__ void dlartgd(double f, double g, double& cs, double& sn, double& r) {
  if (g == 0.0) { cs = 1.0; sn = 0.0; r = f; }
  else if (f == 0.0) { cs = 0.0; sn = fsign(1.0, g); r = fabs(g); }
  else {
    double f1 = fabs(f);
    double d = sqrt(f * f + g * g);
    cs = f1 / d;
    r = fsign(d, f);
    sn = g / r;
  }
}

static __device__ void dlaev2d(double a, double b, double c, double& rt1, double& rt2,
                               double& cs1, double& sn1) {
  double sm = a + c, df = a - c, adf = fabs(df), tb = b + b, ab = fabs(tb);
  double acmx, acmn;
  if (fabs(a) > fabs(c)) { acmx = a; acmn = c; } else { acmx = c; acmn = a; }
  double rt;
  if (adf > ab) { double q = ab / adf; rt = adf * sqrt(1.0 + q * q); }
  else if (adf < ab) { double q = adf / ab; rt = ab * sqrt(1.0 + q * q); }
  else rt = ab * sqrt(2.0);
  int sgn1;
  if (sm < 0.0) { rt1 = 0.5 * (sm - rt); sgn1 = -1; rt2 = (acmx / rt1) * acmn - (b / rt1) * b; }
  else if (sm > 0.0) { rt1 = 0.5 * (sm + rt); sgn1 = 1; rt2 = (acmx / rt1) * acmn - (b / rt1) * b; }
  else { rt1 = 0.5 * rt; rt2 = -0.5 * rt; sgn1 = 1; }
  double cs; int sgn2;
  if (df >= 0.0) { cs = df + rt; sgn2 = 1; } else { cs = df - rt; sgn2 = -1; }
  double acs = fabs(cs);
  if (acs > ab) { double ct = -tb / cs; sn1 = 1.0 / sqrt(1.0 + ct * ct); cs1 = ct * sn1; }
  else {
    if (ab == 0.0) { cs1 = 1.0; sn1 = 0.0; }
    else { double tn = -cs / tb; cs1 = 1.0 / sqrt(1.0 + tn * tn); sn1 = tn * cs1; }
  }
  if (sgn1 == sgn2) { double tn = cs1; cs1 = -sn1; sn1 = tn; }
}

// dsteqr COMPZ='I', n=16, faithful port (1-based d[1..16], e[1..15]).
// Arrays in LDS; Z XOR-swizzled; rotation apply fused (identical order).
static __device__ void dsteqr16_lds(double* dd, double* ee, double* zz, int sw) {
  const int n = 16;
#define ZM(i, j) zz[((((i)-1) << 4) + ((j)-1)) ^ sw]
#define D_(i) dd[(i)]
#define E_(i) ee[(i)]
  for (int i = 1; i <= n; ++i)
    for (int j = 1; j <= n; ++j) ZM(i, j) = (i == j) ? 1.0 : 0.0;
  const double eps = EPS_D, eps2 = eps * eps, safmin = 2.2250738585072014e-308;
  int nmaxit = n * 30, jtot = 0, l1 = 1;
  while (l1 <= n) {
    if (l1 > 1) E_(l1 - 1) = 0.0;
    int m = n;
    for (int mm = l1; mm <= n - 1; ++mm) {
      double tst = fabs(E_(mm));
      if (tst == 0.0) { m = mm; break; }
      if (tst <= (sqrt(fabs(D_(mm))) * sqrt(fabs(D_(mm + 1)))) * eps) { E_(mm) = 0.0; m = mm; break; }
    }
    int l = l1, lsv = l, lend = m, lendsv = m;
    l1 = m + 1;
    if (lend == l) continue;
    double anorm = 0.0;
    for (int i = l; i <= lend; ++i) anorm = fmax(anorm, fabs(D_(i)));
    for (int i = l; i <= lend - 1; ++i) anorm = fmax(anorm, fabs(E_(i)));
    if (anorm == 0.0) continue;
    if (fabs(D_(lend)) < fabs(D_(l))) { lend = lsv; l = lendsv; }
    if (lend > l) {  // QL
      for (;;) {
        int m2 = lend;
        if (l != lend) {
          for (int mm = l; mm <= lend - 1; ++mm) {
            double tst = E_(mm) * E_(mm);
            if (tst <= (eps2 * fabs(D_(mm))) * fabs(D_(mm + 1)) + safmin) { m2 = mm; break; }
          }
        }
        if (m2 < lend) E_(m2) = 0.0;
        double p = D_(l);
        if (m2 == l) { D_(l) = p; ++l; if (l > lend) break; continue; }
        if (m2 == l + 1) {
          double rt1, rt2, c, s;
          dlaev2d(D_(l), E_(l), D_(l + 1), rt1, rt2, c, s);
          for (int i = 1; i <= n; ++i) {
            double tmp = ZM(i, l + 1);
            ZM(i, l + 1) = c * tmp - s * ZM(i, l);
            ZM(i, l) = s * tmp + c * ZM(i, l);
          }
          D_(l) = rt1; D_(l + 1) = rt2; E_(l) = 0.0;
          l += 2; if (l > lend) break; continue;
        }
        if (jtot == nmaxit) break;
        ++jtot;
        double g = (D_(l + 1) - p) / (2.0 * E_(l));
        double r = dlapy2d(g, 1.0);
        g = D_(m2) - p + E_(l) / (g + fsign(r, g));
        double s = 1.0, c = 1.0; p = 0.0;
        for (int i = m2 - 1; i >= l; --i) {
          double f = s * E_(i), bb = c * E_(i);
          dlartgd(g, f, c, s, r);
          if (i != m2 - 1) E_(i + 1) = r;
          g = D_(i + 1) - p;
          r = (D_(i) - g) * s + 2.0 * c * bb;
          p = s * r;
          D_(i + 1) = g + p;
          g = c * r - bb;
          double cj = c, sj = -s;
          for (int i2 = 1; i2 <= n; ++i2) {
            double tmp = ZM(i2, i + 1);
            ZM(i2, i + 1) = cj * tmp - sj * ZM(i2, i);
            ZM(i2, i) = sj * tmp + cj * ZM(i2, i);
          }
        }
        D_(l) -= p; E_(l) = g;
      }
    } else {  // QR
      for (;;) {
        int m2 = lend;
        if (l != lend) {
          for (int mm = l; mm >= lend + 1; --mm) {
            double tst = E_(mm - 1) * E_(mm - 1);
            if (tst <= (eps2 * fabs(D_(mm))) * fabs(D_(mm - 1)) + safmin) { m2 = mm; break; }
          }
        }
        if (m2 > lend) E_(m2 - 1) = 0.0;
        double p = D_(l);
        if (m2 == l) { D_(l) = p; --l; if (l < lend) break; continue; }
        if (m2 == l - 1) {
          double rt1, rt2, c, s;
          dlaev2d(D_(l - 1), E_(l - 1), D_(l), rt1, rt2, c, s);
          for (int i = 1; i <= n; ++i) {
            double tmp = ZM(i, l);
            ZM(i, l) = c * tmp - s * ZM(i, l - 1);
            ZM(i, l - 1) = s * tmp + c * ZM(i, l - 1);
          }
          D_(l - 1) = rt1; D_(l) = rt2; E_(l - 1) = 0.0;
          l -= 2; if (l < lend) break; continue;
        }
        if (jtot == nmaxit) break;
        ++jtot;
        double g = (D_(l - 1) - p) / (2.0 * E_(l - 1));
        double r = dlapy2d(g, 1.0);
        g = D_(m2) - p + E_(l - 1) / (g + fsign(r, g));
        double s = 1.0, c = 1.0; p = 0.0;
        for (int i = m2; i <= l - 1; ++i) {
          double f = s * E_(i), bb = c * E_(i);
          dlartgd(g, f, c, s, r);
          if (i != m2) E_(i - 1) = r;
          g = D_(i) - p;
          r = (D_(i + 1) - g) * s + 2.0 * c * bb;
          p = s * r;
          D_(i) = g + p;
          g = c * r - bb;
          double cj = c, sj = s;
          for (int i2 = 1; i2 <= n; ++i2) {
            double tmp = ZM(i2, i + 1);
            ZM(i2, i + 1) = cj * tmp - sj * ZM(i2, i);
            ZM(i2, i) = sj * tmp + cj * ZM(i2, i);
          }
        }
        D_(l) -= p; E_(l - 1) = g;
      }
    }
  }
  for (int ii = 2; ii <= n; ++ii) {
    int i = ii - 1, k = i;
    double p = D_(i);
    for (int j = ii; j <= n; ++j)
      if (D_(j) < p) { k = j; p = D_(j); }
    if (k != i) {
      D_(k) = D_(i); D_(i) = p;
      for (int r = 1; r <= n; ++r) { double t = ZM(r, i); ZM(r, i) = ZM(r, k); ZM(r, k) = t; }
    }
  }
#undef ZM
#undef D_
#undef E_
}

static __device__ void dlamrg_dev(int n1v, int n2v, const double* a, int strd1, int strd2, int* index) {
  int n1sv = n1v, n2sv = n2v;
  int ind1 = (strd1 > 0) ? 1 : n1v;
  int ind2 = (strd2 > 0) ? n1v + 1 : n1v + n2v;
  int i = 1;
  while (n1sv > 0 && n2sv > 0) {
    if (a[ind1] <= a[ind2]) { index[i++] = ind1; ind1 += strd1; --n1sv; }
    else { index[i++] = ind2; ind2 += strd2; --n2sv; }
  }
  if (n1sv == 0) { while (n2sv > 0) { index[i++] = ind2; ind2 += strd2; --n2sv; } }
  else { while (n1sv > 0) { index[i++] = ind1; ind1 += strd1; --n1sv; } }
}

// -------------------------------- kernels ----------------------------------

__global__ __launch_bounds__(256) void pos_kernel(const float* __restrict__ w,
                                                  const float* __restrict__ bias,
                                                  float* __restrict__ posT) {
  int idx = blockIdx.x * 256 + threadIdx.x;
  if (idx >= 512 * 256) return;
  int d = idx / 256, n = idx % 256;
  int i = n / 16, j = n % 16;
  double step = 1.0 / 15.0;
  float gi = (i == 15) ? 1.0f : (float)(i * step);
  float gj = (j == 15) ? 1.0f : (float)(j * step);
  float v = gi * w[0 * 512 + d] + gj * w[1 * 512 + d] + (1.0f - gi) * w[2 * 512 + d] +
            (1.0f - gj) * w[3 * 512 + d] + bias[d];
  posT[(size_t)d * 256 + n] = v;
}

__global__ __launch_bounds__(256) void stats_kernel(const float* __restrict__ x,
                                                    const float* __restrict__ posT,
                                                    float* mean_o, float* rstd_o, int addpos) {
  int b = blockIdx.x, t = threadIdx.x;
  __shared__ double r1[256], r2[256];
  double s = 0.0, ss = 0.0;
  const float* xb = x + (size_t)b * 131072;
  for (int i = t; i < 131072; i += 256) {
    float v = xb[i];
    if (addpos) v += posT[i];
    s += v; ss += (double)v * v;
  }
  r1[t] = s; r2[t] = ss; __syncthreads();
  for (int o = 128; o > 0; o >>= 1) { if (t < o) { r1[t] += r1[t + o]; r2[t] += r2[t + o]; } __syncthreads(); }
  if (t == 0) {
    double m = r1[0] / 131072.0;
    double var = r2[0] / 131072.0 - m * m;
    mean_o[b] = (float)m;
    rstd_o[b] = 1.0f / sqrtf((float)var + 1e-5f);
  }
}

__global__ __launch_bounds__(256) void tln_kernel(const float* __restrict__ x,
                                                  const float* __restrict__ posT,
                                                  const float* __restrict__ g,
                                                  const float* __restrict__ be,
                                                  const float* m1, const float* r1,
                                                  const float* m2, const float* r2,
                                                  float* __restrict__ fnp,
                                                  float* __restrict__ fpln) {
  int b = blockIdx.x, dt = blockIdx.y, nt = blockIdx.z;
  __shared__ float t1[32][33], t2[32][33];
  int t = threadIdx.x;
  const float* xb = x + (size_t)b * 131072;
  for (int l = 0; l < 4; ++l) {
    int idx = t + l * 256;
    int row = idx >> 5, col = idx & 31;
    int dd = dt * 32 + row, nn = nt * 32 + col;
    float v = xb[(size_t)dd * 256 + nn];
    t1[row][col] = v;
    t2[row][col] = v + posT[(size_t)dd * 256 + nn];
  }
  __syncthreads();
  float mm1 = m1[b], rr1 = r1[b], mm2 = m2[b], rr2 = r2[b];
  for (int l = 0; l < 4; ++l) {
    int idx = t + l * 256;
    int row = idx >> 5, col = idx & 31;
    int nn = nt * 32 + row, dd = dt * 32 + col;
    float gg = g[(size_t)nn * 512 + dd], bb = be[(size_t)nn * 512 + dd];
    size_t o = (size_t)b * 131072 + (size_t)nn * 512 + dd;
    fnp[o] = (t1[col][row] - mm1) * rr1 * gg + bb;
    fpln[o] = (t2[col][row] - mm2) * rr2 * gg + bb;
  }
}

__global__ __launch_bounds__(256) void gemm_f32(const float* __restrict__ A,
                                                const float* __restrict__ Bm,
                                                const float* __restrict__ bias,
                                                const float* __restrict__ base,
                                                float* __restrict__ C, int M, int Nc, int Kd,
                                                int bt, int act, int addb) {
  __shared__ float As[16][65];
  __shared__ float Bs[16][65];
  int bm = blockIdx.x * 64, bn = blockIdx.y * 64;
  int t = threadIdx.x;
  int tx = t & 15, ty = t >> 4;
  float acc[4][4] = {};
  for (int k0 = 0; k0 < Kd; k0 += 16) {
    for (int l = 0; l < 4; ++l) {
      int idx = t + l * 256;
      { int r = idx >> 4, kk = idx & 15;
        float v = 0.f;
        if (bm + r < M && k0 + kk < Kd) v = A[(size_t)(bm + r) * Kd + k0 + kk];
        As[kk][r] = v; }
      if (bt == 0) {
        int kk = idx >> 6, nn = idx & 63;
        float v = 0.f;
        if (k0 + kk < Kd && bn + nn < Nc) v = Bm[(size_t)(k0 + kk) * Nc + bn + nn];
        Bs[kk][nn] = v;
      } else {
        int nn = idx >> 4, kk = idx & 15;
        float v = 0.f;
        if (bn + nn < Nc && k0 + kk < Kd) v = Bm[(size_t)(bn + nn) * Kd + k0 + kk];
        Bs[kk][nn] = v;
      }
    }
    __syncthreads();
#pragma unroll
    for (int kk = 0; kk < 16; ++kk) {
      float a0[4], b0[4];
#pragma unroll
      for (int q = 0; q < 4; ++q) a0[q] = As[kk][ty * 4 + q];
#pragma unroll
      for (int q = 0; q < 4; ++q) b0[q] = Bs[kk][tx * 4 + q];
#pragma unroll
      for (int q = 0; q < 4; ++q)
#pragma unroll
        for (int p = 0; p < 4; ++p) acc[q][p] += a0[q] * b0[p];
    }
    __syncthreads();
  }
  for (int q = 0; q < 4; ++q) {
    int r = bm + ty * 4 + q;
    if (r >= M) continue;
    for (int p = 0; p < 4; ++p) {
      int c = bn + tx * 4 + p;
      if (c >= Nc) continue;
      float v = acc[q][p];
      if (bias) v += bias[c];
      if (act == 1) v = fmaxf(v, 0.f);
      if (addb) v += base[(size_t)r * Nc + c];
      C[(size_t)r * Nc + c] = v;
    }
  }
}

// 128x128 tile, BK=32, 8x8 acc/thread via 4+4 split sub-tiles. Per-output
// k-accumulation: single accumulator, globally ascending k, same contraction
// -> bit-identical to the BK=16 version and to gemm_f32.
// Requires M%128==0, Nc%128==0, Kd%32==0.
__global__ __launch_bounds__(256) void gemm_f32_big(const float* __restrict__ A,
                                                    const float* __restrict__ Bm,
                                                    const float* __restrict__ bias,
                                                    const float* __restrict__ base,
                                                    float* __restrict__ C, int M, int Nc, int Kd,
                                                    int bt, int act, int addb) {
  __shared__ float As[32][128];
  __shared__ float Bs[32][128];
  int bm = blockIdx.x * 128, bn = blockIdx.y * 128;
  int t = threadIdx.x;
  int tx = t & 15, ty = t >> 4;
  int lrow = t >> 1, lseg = (t & 1) * 16;
  float acc[8][8] = {};
  for (int k0 = 0; k0 < Kd; k0 += 32) {
    {
      const float* src = A + (size_t)(bm + lrow) * Kd + k0 + lseg;
      float4 p0 = *(const float4*)src;
      float4 p1 = *(const float4*)(src + 4);
      float4 p2 = *(const float4*)(src + 8);
      float4 p3 = *(const float4*)(src + 12);
      As[lseg + 0][lrow] = p0.x;  As[lseg + 1][lrow] = p0.y;
      As[lseg + 2][lrow] = p0.z;  As[lseg + 3][lrow] = p0.w;
      As[lseg + 4][lrow] = p1.x;  As[lseg + 5][lrow] = p1.y;
      As[lseg + 6][lrow] = p1.z;  As[lseg + 7][lrow] = p1.w;
      As[lseg + 8][lrow] = p2.x;  As[lseg + 9][lrow] = p2.y;
      As[lseg + 10][lrow] = p2.z; As[lseg + 11][lrow] = p2.w;
      As[lseg + 12][lrow] = p3.x; As[lseg + 13][lrow] = p3.y;
      As[lseg + 14][lrow] = p3.z; As[lseg + 15][lrow] = p3.w;
    }
    if (bt == 0) {
      int bk = t >> 4, bcol = (t & 15) * 8;
      const float* src0 = Bm + (size_t)(k0 + bk) * Nc + bn + bcol;
      float4 q0 = *(const float4*)src0;
      float4 q1 = *(const float4*)(src0 + 4);
      *(float4*)&Bs[bk][bcol] = q0;
      *(float4*)&Bs[bk][bcol + 4] = q1;
      const float* src1 = Bm + (size_t)(k0 + bk + 16) * Nc + bn + bcol;
      float4 q2 = *(const float4*)src1;
      float4 q3 = *(const float4*)(src1 + 4);
      *(float4*)&Bs[bk + 16][bcol] = q2;
      *(float4*)&Bs[bk + 16][bcol + 4] = q3;
    } else {
      const float* src = Bm + (size_t)(bn + lrow) * Kd + k0 + lseg;
      float4 p0 = *(const float4*)src;
      float4 p1 = *(const float4*)(src + 4);
      float4 p2 = *(const float4*)(src + 8);
      float4 p3 = *(const float4*)(src + 12);
      Bs[lseg + 0][lrow] = p0.x;  Bs[lseg + 1][lrow] = p0.y;
      Bs[lseg + 2][lrow] = p0.z;  Bs[lseg + 3][lrow] = p0.w;
      Bs[lseg + 4][lrow] = p1.x;  Bs[lseg + 5][lrow] = p1.y;
      Bs[lseg + 6][lrow] = p1.z;  Bs[lseg + 7][lrow] = p1.w;
      Bs[lseg + 8][lrow] = p2.x;  Bs[lseg + 9][lrow] = p2.y;
      Bs[lseg + 10][lrow] = p2.z; Bs[lseg + 11][lrow] = p2.w;
      Bs[lseg + 12][lrow] = p3.x; Bs[lseg + 13][lrow] = p3.y;
      Bs[lseg + 14][lrow] = p3.z; Bs[lseg + 15][lrow] = p3.w;
    }
    __syncthreads();
#pragma unroll
    for (int kk = 0; kk < 32; ++kk) {
      float a0[8], b0[8];
#pragma unroll
      for (int q = 0; q < 4; ++q) { a0[q] = As[kk][ty * 4 + q]; a0[4 + q] = As[kk][64 + ty * 4 + q]; }
#pragma unroll
      for (int p = 0; p < 4; ++p) { b0[p] = Bs[kk][tx * 4 + p]; b0[4 + p] = Bs[kk][64 + tx * 4 + p]; }
#pragma unroll
      for (int q = 0; q < 8; ++q)
#pragma unroll
        for (int p = 0; p < 8; ++p) acc[q][p] += a0[q] * b0[p];
    }
    __syncthreads();
  }
  for (int q = 0; q < 8; ++q) {
    int r = bm + ((q < 4) ? (ty * 4 + q) : (64 + ty * 4 + (q - 4)));
#pragma unroll
    for (int p = 0; p < 8; ++p) {
      int c = bn + ((p < 4) ? (tx * 4 + p) : (64 + tx * 4 + (p - 4)));
      float vv = acc[q][p];
      if (bias) vv += bias[c];
      if (act == 1) vv = fmaxf(vv, 0.f);
      if (addb) vv += base[(size_t)r * Nc + c];
      C[(size_t)r * Nc + c] = vv;
    }
  }
}

__global__ __launch_bounds__(256) void rowln_kernel(const float* __restrict__ in,
                                                    const float* __restrict__ g,
                                                    const float* __restrict__ be,
                                                    float* __restrict__ out) {
  int r = blockIdx.x, t = threadIdx.x;
  __shared__ double s1[256], s2[256];
  const float* row = in + (size_t)r * 512;
  float v0 = row[t], v1 = row[t + 256];
  s1[t] = (double)v0 + (double)v1;
  s2[t] = (double)v0 * v0 + (double)v1 * v1;
  __syncthreads();
  for (int o = 128; o > 0; o >>= 1) { if (t < o) { s1[t] += s1[t + o]; s2[t] += s2[t + o]; } __syncthreads(); }
  double m = s1[0] / 512.0, var = s2[0] / 512.0 - m * m;
  float rstd = 1.0f / sqrtf((float)var + 1e-5f);
  float mf = (float)m;
  out[(size_t)r * 512 + t] = (v0 - mf) * rstd * g[t] + be[t];
  out[(size_t)r * 512 + t + 256] = (v1 - mf) * rstd * g[t + 256] + be[t + 256];
}

__global__ __launch_bounds__(256) void xnorm_kernel(float* kno) {
  int r = blockIdx.x, t = threadIdx.x;
  __shared__ double s1[256];
  float* row = kno + (size_t)r * 512;
  float v0 = row[t], v1 = row[t + 256];
  s1[t] = (double)v0 * v0 + (double)v1 * v1;
  __syncthreads();
  for (int o = 128; o > 0; o >>= 1) { if (t < o) s1[t] += s1[t + o]; __syncthreads(); }
  float nrm = fmaxf((float)sqrt(s1[0]), 1e-12f);
  row[t] = v0 / nrm; row[t + 256] = v1 / nrm;
}

__global__ __launch_bounds__(256) void cov_kernel(const float* __restrict__ xn, double* __restrict__ cov) {
  int b = blockIdx.x, it = blockIdx.y, jt = blockIdx.z;
  __shared__ float Xi[64][65], Xj[64][65];
  int t = threadIdx.x;
  int tx = t & 15, ty = t >> 4;
  double acc[4][4] = {};
  const float* xb = xn + (size_t)b * 131072;
  for (int f0 = 0; f0 < 512; f0 += 64) {
    for (int l = 0; l < 16; ++l) {
      int idx = t + l * 256;
      int r = idx >> 6, ff = idx & 63;
      Xi[r][ff] = xb[(size_t)(it * 64 + r) * 512 + f0 + ff];
      Xj[r][ff] = xb[(size_t)(jt * 64 + r) * 512 + f0 + ff];
    }
    __syncthreads();
    for (int ff = 0; ff < 64; ++ff) {
      double a0[4], b0[4];
#pragma unroll
      for (int q = 0; q < 4; ++q) { a0[q] = (double)Xi[ty * 4 + q][ff]; b0[q] = (double)Xj[tx * 4 + q][ff]; }
#pragma unroll
      for (int q = 0; q < 4; ++q)
#pragma unroll
        for (int p = 0; p < 4; ++p) acc[q][p] += a0[q] * b0[p];
    }
    __syncthreads();
  }
  double* cb = cov + (size_t)b * 65536;
  for (int q = 0; q < 4; ++q)
    for (int p = 0; p < 4; ++p)
      cb[(size_t)(it * 64 + ty * 4 + q) * 256 + jt * 64 + tx * 4 + p] = acc[q][p];
}

// Two-deep lazy Householder tridiagonalization (R6), with Phase 0 reading
// ROW i (coalesced) instead of column i: A is bitwise-symmetric throughout
// (cov bitwise symmetric; rank-2 updates commute bitwise; v-writes touch only
// dead lower columns), and the row-form correction equals the column-form
// bitwise by commutativity of +/*. dE[i] written inline from the corrected
// diagonal register. 1024 threads = 16 waves.
__global__ __launch_bounds__(1024) void dsytrd_kernel(double* Aall, double* dE, double* eE,
                                                      double* tauE) {
  int b = blockIdx.x, t = threadIdx.x;
  int lane = t & 63, wid = t >> 6;
  double* A = Aall + (size_t)b * 65536;
  __shared__ double bufA[256], bufB[256], bufC[256], bufD[256], bufE[256], bufF[256];
  __shared__ double v2[256];
  __shared__ double redw[16];
  const int n = 256;
  double* v = bufA;   double* w = bufB;    // current reflector / w-vector
  double* vp1 = bufC; double* wp1 = bufD;  // older pending
  double* vp2 = bufE; double* wp2 = bufF;  // newer pending
  int cnt = 0;
  for (int i = 0; i < n - 1; ++i) {
    // Phase 0: corrected row i (coalesced) -> v2; dE[i] from diagonal elem.
    for (int c = i + t; c < n; c += 1024) {
      double a = A[(size_t)i * 256 + c];
      if (cnt >= 1) {
        a = a - (vp1[c] * wp1[i] + wp1[c] * vp1[i]);
        if (cnt == 2) a = a - (vp2[c] * wp2[i] + wp2[c] * vp2[i]);
      }
      v2[c] = a;
      if (c == i) dE[b * 256 + i] = a;
    }
    __syncthreads();  // B0
    // norm below subdiagonal (R2 mapping r = i+2+t)
    double s = 0.0;
    for (int r = i + 2 + t; r < n; r += 1024) { double xv = v2[r]; s += xv * xv; }
    for (int o = 1; o < 64; o <<= 1) s += __shfl_xor(s, o);
    if (lane == 0) redw[wid] = s;
    __syncthreads();  // B1
    double xns = 0.0;
    for (int k = 0; k < 16; ++k) xns += redw[k];
    double alpha = v2[i + 1];
    double tau, beta, scl;
    if (xns == 0.0) { tau = 0.0; beta = alpha; scl = 0.0; }
    else {
      double xnorm = sqrt(xns);
      double rr = dlapy2d(alpha, xnorm);
      beta = (alpha >= 0.0) ? -rr : rr;
      tau = (beta - alpha) / beta;
      scl = 1.0 / (alpha - beta);
    }
    if (tau != 0.0) {
      int dow = (cnt == 2);
      // v setup (R2 mapping r = i+1+t); store v into subdiagonal column i
      for (int r = i + 1 + t; r < n; r += 1024) {
        double vr = (r == i + 1) ? 1.0 : v2[r] * scl;
        v[r] = vr;
        if (r >= i + 2) A[(size_t)r * 256 + i] = vr;
      }
      __syncthreads();  // B2
      // Phase E: apply pendings (write only when two) + matvec.
      // Wave per row (stride 16), lanes over columns (stride 64).
      for (int r = i + 1 + wid; r < n; r += 16) {
        double* Ar = A + (size_t)r * 256;
        double acc = 0.0;
        if (cnt == 2) {
          double v1r = vp1[r], w1r = wp1[r], v2r = vp2[r], w2r = wp2[r];
          for (int c = i + 1 + lane; c < n; c += 64) {
            double a = Ar[c] - (v1r * wp1[c] + w1r * vp1[c]);
            a = a - (v2r * wp2[c] + w2r * vp2[c]);
            Ar[c] = a;
            acc += a * v[c];
          }
        } else if (cnt == 1) {
          double v1r = vp1[r], w1r = wp1[r];
          for (int c = i + 1 + lane; c < n; c += 64) {
            double a = Ar[c] - (v1r * wp1[c] + w1r * vp1[c]);
            acc += a * v[c];
          }
        } else {
          for (int c = i + 1 + lane; c < n; c += 64) acc += Ar[c] * v[c];
        }
        for (int o = 1; o < 64; o <<= 1) acc += __shfl_xor(acc, o);
        if (lane == 0) w[r] = tau * acc;
      }
      __syncthreads();  // B3
      // dot = w.v (R2 mapping)
      double sd = 0.0;
      for (int r = i + 1 + t; r < n; r += 1024) sd += w[r] * v[r];
      for (int o = 1; o < 64; o <<= 1) sd += __shfl_xor(sd, o);
      if (lane == 0) redw[wid] = sd;
      __syncthreads();  // B4
      double dot = 0.0;
      for (int k = 0; k < 16; ++k) dot += redw[k];
      double alpha2 = -0.5 * tau * dot;
      for (int r = i + 1 + t; r < n; r += 1024) w[r] += alpha2 * v[r];
      if (t == 0) { eE[b * 256 + i] = beta; tauE[b * 256 + i] = tau; }
      __syncthreads();  // B5
      // rotate pendings (uniform per-thread bookkeeping)
      if (dow) {
        double* tv = v; v = vp1; vp1 = tv;
        double* tw = w; w = wp1; wp1 = tw;
        cnt = 1;  // p1,p2 applied; current becomes the only pending
      } else if (cnt == 0) {
        double* tv = v; v = vp1; vp1 = tv;
        double* tw = w; w = wp1; wp1 = tw;
        cnt = 1;
      } else {  // cnt == 1 read-step: current becomes newer pending
        double* tv = v; v = vp2; vp2 = tv;
        double* tw = w; w = wp2; wp2 = tw;
        cnt = 2;
      }
    } else {
      // no new reflector: flush any pendings into trailing square now
      if (cnt >= 1) {
        for (int r = i + 1 + wid; r < n; r += 16) {
          double* Ar = A + (size_t)r * 256;
          double v1r = vp1[r], w1r = wp1[r];
          double v2r = (cnt == 2) ? vp2[r] : 0.0, w2r = (cnt == 2) ? wp2[r] : 0.0;
          for (int c = i + 1 + lane; c < n; c += 64) {
            double a = Ar[c] - (v1r * wp1[c] + w1r * vp1[c]);
            if (cnt == 2) a = a - (v2r * wp2[c] + w2r * vp2[c]);
            Ar[c] = a;
          }
        }
      }
      if (t == 0) { eE[b * 256 + i] = beta; tauE[b * 256 + i] = tau; }
      __syncthreads();
      cnt = 0;
    }
  }
  // dE[n-1]: diagonal + any remaining pending corrections (same expr order).
  if (t == 0) {
    int r = n - 1;
    double dd = A[(size_t)r * 256 + r];
    if (cnt >= 1) dd = dd - (vp1[r] * wp1[r] + wp1[r] * vp1[r]);
    if (cnt == 2) dd = dd - (vp2[r] * wp2[r] + wp2[r] * vp2[r]);
    dE[b * 256 + r] = dd;
  }
}

__global__ __launch_bounds__(64) void tear_kernel(double* dE, const double* eE) {
  int b = threadIdx.x;
  if (b >= 64) return;
  for (int m = 1; m < 16; ++m) {
    int p = m * 16 - 1;
    double ae = fabs(eE[b * 256 + p]);
    dE[b * 256 + p] -= ae;
    dE[b * 256 + p + 1] -= ae;
  }
}

// One leaf per thread; Z (16x16) + d/e in LDS, XOR-swizzled.
__global__ __launch_bounds__(64) void leaf_kernel(double* dE, double* eE, double* Qe, int* indxq) {
  __shared__ double Zs[LPB * 256];
  __shared__ double des[LPB * 33];
  int t = threadIdx.x;
  int g = blockIdx.x * LPB + t;
  if (t >= LPB || g >= 1024) return;
  int b = g >> 4, lf = g & 15, off = lf * 16;
  double* zz = Zs + t * 256;
  double* dd = des + t * 33;
  double* ee = dd + 16;
  int sw = t & 15;
  for (int i = 1; i <= 16; ++i) dd[i] = dE[b * 256 + off + i - 1];
  for (int i = 1; i <= 15; ++i) ee[i] = eE[b * 256 + off + i - 1];
  ee[16] = 0.0;
  dsteqr16_lds(dd, ee, zz, sw);
  for (int i = 1; i <= 16; ++i) dE[b * 256 + off + i - 1] = dd[i];
  double* Qb = Qe + (size_t)b * 65536;
  for (int r = 0; r < 16; ++r)
    for (int c = 0; c < 16; ++c) Qb[(size_t)(off + r) * 256 + off + c] = zz[((r << 4) + c) ^ sw];
  for (int i = 0; i < 16; ++i) indxq[b * 256 + off + i] = i + 1;
}

// dlaed2 deflation scan. Block per (b, merge): serial scan on thread 0 with
// all arrays in LDS; Givens rotations deferred to a list (scan never reads Q
// after z extraction) and applied block-parallel row-partitioned afterwards.
__global__ __launch_bounds__(256) void merge_scan_kernel(int nm, int nmerge, double* Qsrc, double* dE,
                                                         const double* eE, int* indxq,
                                                         double* dlamda_g, double* w_g, double* rho_g,
                                                         int* surv_g, int* defl_g, int* Kb) {
  int b = blockIdx.x, mg = blockIdx.y;
  int off = mg * nm, n1 = nm / 2, n2 = nm - n1;
  double* Q = Qsrc + (size_t)b * 65536;
  double* dg = dE + b * 256 + off;
  int* iqg = indxq + b * 256 + off;
  int t = threadIdx.x;

  __shared__ double dl[257], zl[257], dlamA[257], wl2[257];
  __shared__ int iq[257], indxc[257], indxl[257], indxpl[257];
  __shared__ double rotc[256], rots[256];
  __shared__ int rotp[256], rotn[256];
  __shared__ int sh_nrot, sh_K, sh_zero;

  for (int ii = 1 + t; ii <= nm; ii += 256) { dl[ii] = dg[ii - 1]; iq[ii] = iqg[ii - 1]; }
  __syncthreads();

  if (t == 0) {
    double rho = eE[b * 256 + off + n1 - 1];
    for (int j = 1; j <= n1; ++j) zl[j] = Q[(size_t)(off + n1 - 1) * 256 + off + j - 1];
    for (int j = 1; j <= n2; ++j) zl[n1 + j] = Q[(size_t)(off + n1) * 256 + off + n1 + j - 1];
    if (rho < 0.0)
      for (int j = n1 + 1; j <= nm; ++j) zl[j] = -zl[j];
    double tconst = 1.0 / sqrt(2.0);
    for (int j = 1; j <= nm; ++j) zl[j] *= tconst;
    rho = fabs(2.0 * rho);
    rho_g[b * nmerge + mg] = rho;
    for (int i = n1 + 1; i <= nm; ++i) iq[i] += n1;
    for (int i = 1; i <= nm; ++i) dlamA[i] = dl[iq[i]];
    dlamrg_dev(n1, n2, dlamA, 1, 1, indxc);
    for (int i = 1; i <= nm; ++i) indxl[i] = iq[indxc[i]];
    int imax = 1, jmax = 1;
    for (int i = 2; i <= nm; ++i) {
      if (fabs(zl[i]) > fabs(zl[imax])) imax = i;
      if (fabs(dl[i]) > fabs(dl[jmax])) jmax = i;
    }
    double tol = 8.0 * EPS_D * fmax(fabs(dl[jmax]), fabs(zl[imax]));
    if (rho * fabs(zl[imax]) <= tol) {
      sh_K = 0; sh_zero = 1; sh_nrot = 0;
    } else {
      sh_zero = 0;
      int nrot = 0;
      int K = 0, K2 = nm + 1, pj = 0, j = 1;
      bool havepj = false;
      for (j = 1; j <= nm; ++j) {
        int nj = indxl[j];
        if (rho * fabs(zl[nj]) <= tol) {
          K2--; indxpl[K2] = nj;
          if (j == nm) break;
        } else { pj = nj; havepj = true; break; }
      }
      if (havepj) {
        for (;;) {
          j = j + 1;
          if (j > nm) break;
          int nj = indxl[j];
          if (rho * fabs(zl[nj]) <= tol) { K2--; indxpl[K2] = nj; }
          else {
            double s_ = zl[pj], c_ = zl[nj];
            double tau_ = dlapy2d(c_, s_);
            double t_ = dl[nj] - dl[pj];
            c_ = c_ / tau_; s_ = -s_ / tau_;
            if (fabs(t_ * c_ * s_) <= tol) {
              zl[nj] = tau_; zl[pj] = 0.0;
              rotp[nrot] = pj; rotn[nrot] = nj; rotc[nrot] = c_; rots[nrot] = s_; ++nrot;
              double t2 = dl[pj] * c_ * c_ + dl[nj] * s_ * s_;
              dl[nj] = dl[pj] * s_ * s_ + dl[nj] * c_ * c_;
              dl[pj] = t2;
              K2--;
              int i_ = 1;
              for (;;) {
                if (K2 + i_ <= nm) {
                  if (dl[pj] < dl[indxpl[K2 + i_]]) {
                    indxpl[K2 + i_ - 1] = indxpl[K2 + i_];
                    indxpl[K2 + i_] = pj;
                    i_++;
                  } else { indxpl[K2 + i_ - 1] = pj; break; }
                } else { indxpl[K2 + i_ - 1] = pj; break; }
              }
              pj = nj;
            } else {
              K++; dlamA[K] = dl[pj]; wl2[K] = zl[pj]; indxpl[K] = pj; pj = nj;
            }
          }
        }
        K++; dlamA[K] = dl[pj]; wl2[K] = zl[pj]; indxpl[K] = pj;
      }
      sh_K = K; sh_nrot = nrot;
    }
  }
  __syncthreads();
  int nrot = sh_nrot, K = sh_K;
  // apply deferred rotations in order; rows partitioned across threads
  for (int r = t; r < nm; r += 256) {
    size_t rowb = (size_t)(off + r) * 256;
    for (int k = 0; k < nrot; ++k) {
      int cp = off + rotp[k] - 1, cn = off + rotn[k] - 1;
      double c_ = rotc[k], s_ = rots[k];
      double x = Q[rowb + cp], y = Q[rowb + cn];
      Q[rowb + cp] = c_ * x + s_ * y;
      Q[rowb + cn] = c_ * y - s_ * x;
    }
  }
  if (sh_zero) {
    if (t == 0) Kb[b * nmerge + mg] = 0;
    for (int j = 1 + t; j <= nm; j += 256) {
      int il = indxl[j];
      defl_g[b * 256 + off + j - 1] = il;
      dg[j - 1] = dl[il];
      iqg[j - 1] = j;
    }
  } else {
    if (t == 0) Kb[b * nmerge + mg] = K;
    for (int i = 1 + t; i <= K; i += 256) {
      dlamda_g[b * 256 + off + i - 1] = dlamA[i];
      w_g[b * 256 + off + i - 1] = wl2[i];
      surv_g[b * 256 + off + i - 1] = indxpl[i];
    }
    for (int jj = K + 1 + t; jj <= nm; jj += 256) {
      defl_g[b * 256 + off + jj - 1] = indxpl[jj];
      dg[jj - 1] = dl[indxpl[jj]];
    }
  }
}

// secular solver (dlaed4-equivalent, bisection)
__global__ __launch_bounds__(256) void secular_kernel(int nm, int nmerge, const double* dlamda_g,
                                                      const double* w_g, const double* rho_g,
                                                      const int* Kb, double* dE, double* tau_g,
                                                      int* orig_g) {
  int b = blockIdx.x, pos = threadIdx.x;
  int mg = pos / nm, jl = pos % nm + 1;
  int K = Kb[b * nmerge + mg];
  if (jl > K) return;
  int base = b * 256 + mg * nm;
  const double* dl = dlamda_g + base;
  const double* w = w_g + base;
  double rho = rho_g[b * nmerge + mg];
  int orig; double lo, hi;
  if (jl < K) {
    double dj = dl[jl - 1], dj1 = dl[jl];
    double mid = (dj + dj1) * 0.5;
    double acc = 0.0;
    for (int i = 0; i < K; ++i) acc += w[i] * w[i] / (dl[i] - mid);
    double fmid = 1.0 + rho * acc;
    if (fmid > 0.0) { orig = jl; lo = 0.0; hi = mid - dj; }
    else { orig = jl + 1; lo = mid - dj1; hi = 0.0; }
  } else {
    orig = K;
    double zs = 0.0;
    for (int i = 0; i < K; ++i) zs += w[i] * w[i];
    lo = 0.0; hi = rho * zs;
  }
  double dorig = dl[orig - 1];
  for (int it = 0; it < 100; ++it) {
    double tm = 0.5 * (lo + hi);
    if (tm == lo || tm == hi) break;
    double acc = 0.0;
    for (int i = 0; i < K; ++i) acc += w[i] * w[i] / ((dl[i] - dorig) - tm);
    double g = 1.0 + rho * acc;
    if (g > 0.0) hi = tm; else lo = tm;
  }
  double tau = 0.5 * (lo + hi);
  tau_g[base + jl - 1] = tau;
  orig_g[base + jl - 1] = orig;
  dE[base + jl - 1] = dorig + tau;
}

__global__ __launch_bounds__(256) void zhat_kernel(int nm, int nmerge, const double* dlamda_g,
                                                   const double* w_g, const double* tau_g,
                                                   const int* orig_g, const int* Kb, double* zhat_g) {
  int b = blockIdx.x, pos = threadIdx.x;
  int mg = pos / nm, il = pos % nm + 1;
  int K = Kb[b * nmerge + mg];
  if (il > K) return;
  int base = b * 256 + mg * nm;
  const double* dl = dlamda_g + base;
  double di = dl[il - 1];
  double p = (di - dl[orig_g[base + il - 1] - 1]) - tau_g[base + il - 1];
  for (int jj = 1; jj <= K; ++jj) {
    if (jj == il) continue;
    double del = (di - dl[orig_g[base + jj - 1] - 1]) - tau_g[base + jj - 1];
    p *= del / (di - dl[jj - 1]);
  }
  double val = sqrt(fmax(-p, 0.0));
  zhat_g[base + il - 1] = fsign(val, w_g[base + il - 1]);
}

__global__ __launch_bounds__(256) void coeff_kernel(int nm, int nmerge, const double* dlamda_g,
                                                    const double* zhat_g, const double* tau_g,
                                                    const int* orig_g, const int* Kb, double* Cbuf) {
  int b = blockIdx.x, pos = threadIdx.x;
  int mg = pos / nm, jl = pos % nm + 1;
  int K = Kb[b * nmerge + mg];
  if (jl > K) return;
  int off = mg * nm, base = b * 256 + off;
  double* C = Cbuf + (size_t)b * 65536;
  const double* dl = dlamda_g + base;
  if (K == 1) { C[(size_t)off * 256 + off + jl - 1] = 1.0; return; }
  double dorig = dl[orig_g[base + jl - 1] - 1];
  double tau = tau_g[base + jl - 1];
  double ss = 0.0;
  for (int i = 1; i <= K; ++i) {
    double del = (dl[i - 1] - dorig) - tau;
    double ci = zhat_g[base + i - 1] / del;
    C[(size_t)(off + i - 1) * 256 + off + jl - 1] = ci;
    ss += ci * ci;
  }
  double inv = 1.0 / sqrt(ss);
  for (int i = 1; i <= K; ++i) C[(size_t)(off + i - 1) * 256 + off + jl - 1] *= inv;
}

__global__ __launch_bounds__(64) void dlamrg_kernel(int nm, int nmerge, const double* dE,
                                                    const int* Kb, int* indxq) {
  int gid = blockIdx.x * 64 + threadIdx.x;
  if (gid >= 64 * nmerge) return;
  int b = gid / nmerge, mg = gid % nmerge;
  int off = mg * nm;
  int K = Kb[b * nmerge + mg];
  int* iqg = indxq + b * 256 + off;
  if (K == 0) return;  // identity already set by scan
  const double* dg = dE + b * 256 + off;
  int n1sv = K, n2sv = nm - K;
  int ind1 = 1, ind2 = nm;
  int i = 1;
  int idx[257];
  while (n1sv > 0 && n2sv > 0) {
    if (dg[ind1 - 1] <= dg[ind2 - 1]) { idx[i++] = ind1; ind1++; n1sv--; }
    else { idx[i++] = ind2; ind2--; n2sv--; }
  }
  if (n1sv == 0) { while (n2sv > 0) { idx[i++] = ind2; ind2--; n2sv--; } }
  else { while (n1sv > 0) { idx[i++] = ind1; ind1++; n1sv--; } }
  for (int t = 1; t <= nm; ++t) iqg[t - 1] = idx[t];
}

__global__ __launch_bounds__(256) void merge_gemm_kernel(int nm, int nmerge, const double* Qsrc,
                                                         const double* Cbuf, const int* surv_g,
                                                         const int* Kb, double* Qdst) {
  int b = blockIdx.x, mg = blockIdx.y;
  int tcnt = nm / 32;
  int rt = blockIdx.z / tcnt, ct = blockIdx.z % tcnt;
  int off = mg * nm;
  int K = Kb[b * nmerge + mg];
  if (ct * 32 >= K) return;
  __shared__ double Qs[32][33];
  __shared__ double Cs[32][33];
  __shared__ int svs[32];
  int t = threadIdx.x;
  int tc = t & 31, tr = t >> 5;
  const double* Qsb = Qsrc + (size_t)b * 65536;
  const double* Cb = Cbuf + (size_t)b * 65536;
  double acc[4] = {0, 0, 0, 0};
  int r0 = off + rt * 32, c0 = off + ct * 32;
  for (int i0 = 0; i0 < K; i0 += 32) {
    if (t < 32) svs[t] = (i0 + t < K) ? surv_g[b * 256 + off + i0 + t] : 0;
    __syncthreads();
    for (int l = 0; l < 4; ++l) {
      int idx = t + l * 256;
      int r = idx >> 5, ii = idx & 31;
      int sc = svs[ii];
      Qs[r][ii] = (sc > 0) ? Qsb[(size_t)(r0 + r) * 256 + off + sc - 1] : 0.0;
      Cs[r][ii] = (i0 + r < K && ct * 32 + ii < K) ? Cb[(size_t)(off + i0 + r) * 256 + c0 + ii] : 0.0;
    }
    __syncthreads();
    for (int ii = 0; ii < 32; ++ii) {
      double cv = Cs[ii][tc];
#pragma unroll
      for (int q = 0; q < 4; ++q) acc[q] += Qs[tr * 4 + q][ii] * cv;
    }
    __syncthreads();
  }
  if (ct * 32 + tc < K) {
    double* Qd = Qdst + (size_t)b * 65536;
    for (int q = 0; q < 4; ++q) Qd[(size_t)(r0 + tr * 4 + q) * 256 + c0 + tc] = acc[q];
  }
}

// deflated-column copy, row-parallel (each thread owns rows; loops columns)
__global__ __launch_bounds__(256) void defl_copy_kernel(int nm, int nmerge, const double* Qsrc,
                                                        const int* defl_g, const int* Kb,
                                                        double* Qdst) {
  int b = blockIdx.x, mg = blockIdx.y;
  int off = mg * nm;
  int K = Kb[b * nmerge + mg];
  int t = threadIdx.x;
  const double* Qs = Qsrc + (size_t)b * 65536;
  double* Qd = Qdst + (size_t)b * 65536;
  for (int r = t; r < nm; r += 256) {
    const double* Qsr = Qs + (size_t)(off + r) * 256;
    double* Qdr = Qd + (size_t)(off + r) * 256;
    for (int jl = K + 1; jl <= nm; ++jl)
      Qdr[off + jl - 1] = Qsr[off + defl_g[b * 256 + off + jl - 1] - 1];
  }
}

// gather ranks 2..9, apply Householder back-transform, emit E (f32, [b][s][n])
__global__ __launch_bounds__(256) void dormtr_kernel(const double* Aall, const double* tauE,
                                                     const double* Qe, const int* indxq, float* E) {
  int b = blockIdx.x, t = threadIdx.x;
  const double* A = Aall + (size_t)b * 65536;
  __shared__ double U[256][8];
  __shared__ double wred[32][8];
  __shared__ double wfin[8];
  __shared__ int sel[8];
  if (t < 8) sel[t] = indxq[b * 256 + 1 + t] - 1;
  __syncthreads();
  for (int i = t; i < 256 * 8; i += 256) {
    int r = i >> 3, c = i & 7;
    U[r][c] = Qe[(size_t)b * 65536 + (size_t)r * 256 + sel[c]];
  }
  __syncthreads();
  int lane = t & 31, col = t >> 5;
  for (int s = 254; s >= 0; --s) {
    double tv = tauE[b * 256 + s];
    if (tv == 0.0) continue;
    double acc = (lane == 0) ? U[s + 1][col] : 0.0;
    for (int r = s + 2 + lane; r < 256; r += 32) acc += A[(size_t)r * 256 + s] * U[r][col];
    wred[lane][col] = acc;
    __syncthreads();
    if (t < 8) { double a = 0.0; for (int l2 = 0; l2 < 32; ++l2) a += wred[l2][t]; wfin[t] = a; }
    __syncthreads();
    double wc = wfin[col] * tv;
    if (lane == 0) U[s + 1][col] -= wc;
    for (int r = s + 2 + lane; r < 256; r += 32) U[r][col] -= A[(size_t)r * 256 + s] * wc;
    __syncthreads();
  }
  for (int i = t; i < 8 * 256; i += 256) {
    int s = i >> 8, nn = i & 255;
    E[((size_t)b * 8 + s) * 256 + nn] = (float)U[nn][s];
  }
}

// z = E2 . fnp, coalesced streaming of fnp rows; per-output accumulation order
// identical to the original column-wise version (ascending n) -> bit-identical.
__global__ __launch_bounds__(256) void zproj_kernel(const float* __restrict__ fnp,
                                                    const float* __restrict__ E2,
                                                    float* __restrict__ z) {
  int b = blockIdx.x, t = threadIdx.x;
  __shared__ float er[8][256];
  for (int i = t; i < 8 * 256; i += 256) er[i >> 8][i & 255] = E2[(size_t)b * 2048 + i];
  __syncthreads();
  for (int d0 = 0; d0 < 512; d0 += 256) {
    int d = d0 + t;
    float a0 = 0.f, a1 = 0.f, a2 = 0.f, a3 = 0.f, a4 = 0.f, a5 = 0.f, a6 = 0.f, a7 = 0.f;
    for (int n = 0; n < 256; ++n) {
      float f = fnp[((size_t)b * 256 + n) * 512 + d];
      a0 += er[0][n] * f; a1 += er[1][n] * f; a2 += er[2][n] * f; a3 += er[3][n] * f;
      a4 += er[4][n] * f; a5 += er[5][n] * f; a6 += er[6][n] * f; a7 += er[7][n] * f;
    }
    z[((size_t)b * 8 + 0) * 512 + d] = a0;
    z[((size_t)b * 8 + 1) * 512 + d] = a1;
    z[((size_t)b * 8 + 2) * 512 + d] = a2;
    z[((size_t)b * 8 + 3) * 512 + d] = a3;
    z[((size_t)b * 8 + 4) * 512 + d] = a4;
    z[((size_t)b * 8 + 5) * 512 + d] = a5;
    z[((size_t)b * 8 + 6) * 512 + d] = a6;
    z[((size_t)b * 8 + 7) * 512 + d] = a7;
  }
}

__global__ __launch_bounds__(64) void d2_kernel(const float* __restrict__ z,
                                                const float* __restrict__ ts, double* sdist,
                                                int* idxr) {
  int row = blockIdx.x;
  int lane = threadIdx.x;
  const float* zr = z + (size_t)row * 512;
  const float* tr = ts + (size_t)lane * 512;
  double zz = 0, zt = 0, tt = 0;
  for (int d = 0; d < 512; ++d) {
    double zv = zr[d], tv = tr[d];
    zz += zv * zv; zt += zv * tv; tt += tv * tv;
  }
  double d2 = zz + tt - 2.0 * zt;
  int best = lane; double bv = d2;
  for (int off = 32; off > 0; off >>= 1) {
    double ov = __shfl_down(bv, off);
    int oi = __shfl_down(best, off);
    if (ov < bv || (ov == bv && oi < best)) { bv = ov; best = oi; }
  }
  if (lane == 0) { sdist[row] = bv; idxr[row] = best; }
}

__global__ __launch_bounds__(64) void order_kernel(const double* sdist, const int* idxr, int* fidx,
                                                   float* out_idx) {
  int b = threadIdx.x;
  if (b >= 64) return;
  double sd[8]; int ord[8];
  for (int s = 0; s < 8; ++s) { sd[s] = sdist[b * 8 + s]; ord[s] = s; }
  for (int a = 1; a < 8; ++a) {
    double kv = sd[a]; int ko = ord[a]; int c = a - 1;
    while (c >= 0 && sd[c] > kv) { sd[c + 1] = sd[c]; ord[c + 1] = ord[c]; --c; }
    sd[c + 1] = kv; ord[c + 1] = ko;
  }
  for (int s = 0; s < 8; ++s) {
    int fi = idxr[ord[s]];  // cross-batch quirk: always batch 0's argmins
    fidx[b * 8 + s] = fi;
    out_idx[b * 8 + s] = (float)fi;
  }
}

__global__ __launch_bounds__(256) void slots0_kernel(const float* z, const float* emb,
                                                     const int* fidx, float* slots) {
  int i = blockIdx.x * 256 + threadIdx.x;
  if (i >= 512 * 512) return;
  int t = i / 512, d = i % 512;
  float zv = z[i];
  float zq = emb[fidx[t] * 512 + d];
  slots[i] = zv + (zq - zv);
}

__global__ __launch_bounds__(256) void qloss_kernel(const float* z, const float* ts, const int* fidx,
                                                    float* out) {
  __shared__ double red[256];
  int t = threadIdx.x;
  double acc = 0.0;
  for (int i = t; i < 512 * 512; i += 256) {
    int r = i / 512, d = i % 512;
    float diff = ts[fidx[r] * 512 + d] - z[i];
    acc += (double)diff * (double)diff;
  }
  red[t] = acc; __syncthreads();
  for (int o = 128; o > 0; o >>= 1) { if (t < o) red[t] += red[t + o]; __syncthreads(); }
  if (t == 0) {
    float a = (float)(red[0] / 64.0);
    out[0] = a + 0.99f * a;
  }
}

__global__ __launch_bounds__(256) void dots_kernel(const float* __restrict__ q,
                                                   const float* __restrict__ k,
                                                   float* __restrict__ dots) {
  int b = blockIdx.x, jt = blockIdx.y;
  __shared__ float qs[8][513];
  __shared__ float kc[64][33];
  int t = threadIdx.x;
  for (int i = t; i < 8 * 512; i += 256) qs[i / 512][i % 512] = q[((size_t)b * 8 + i / 512) * 512 + i % 512];
  int j = t % 64, ig = t / 64;
  float acc0 = 0.f, acc1 = 0.f;
  for (int d0 = 0; d0 < 512; d0 += 32) {
    __syncthreads();
    for (int l = 0; l < 8; ++l) {
      int idx = t + l * 256;
      int r = idx >> 5, dd = idx & 31;
      kc[r][dd] = k[((size_t)b * 256 + jt * 64 + r) * 512 + d0 + dd];
    }
    __syncthreads();
    for (int dd = 0; dd < 32; ++dd) {
      float kv = kc[j][dd];
      acc0 += qs[ig * 2][d0 + dd] * kv;
      acc1 += qs[ig * 2 + 1][d0 + dd] * kv;
    }
  }
  const float scale = (float)(1.0 / sqrt(512.0));
  dots[((size_t)b * 8 + ig * 2) * 256 + jt * 64 + j] = acc0 * scale;
  dots[((size_t)b * 8 + ig * 2 + 1) * 256 + jt * 64 + j] = acc1 * scale;
}

__global__ __launch_bounds__(256) void softmax_kernel(const float* dots, float* attn) {
  int b = blockIdx.x, j = threadIdx.x;
  float v[8]; float mx = -1e30f;
  for (int i = 0; i < 8; ++i) { v[i] = dots[((size_t)b * 8 + i) * 256 + j]; mx = fmaxf(mx, v[i]); }
  float s = 0.f;
  for (int i = 0; i < 8; ++i) { v[i] = expf(v[i] - mx); s += v[i]; }
  for (int i = 0; i < 8; ++i) attn[((size_t)b * 8 + i) * 256 + j] = v[i] / s;
}

__global__ __launch_bounds__(64) void asum_kernel(const float* attn, float* asum) {
  int bi = blockIdx.x, lane = threadIdx.x;
  float s = 0.f;
  for (int j = lane; j < 256; j += 64) s += attn[(size_t)bi * 256 + j] + 1e-8f;
  for (int off = 32; off > 0; off >>= 1) s += __shfl_down(s, off);
  if (lane == 0) asum[bi] = s;
}

__global__ __launch_bounds__(256) void updates_kernel(const float* attn, const float* asum,
                                                      const float* v, float* upd) {
  int b = blockIdx.x;
  __shared__ float at[8][257];
  int t = threadIdx.x;
  for (int i = t; i < 8 * 256; i += 256) {
    int ii = i / 256, j = i % 256;
    at[ii][j] = (attn[((size_t)b * 8 + ii) * 256 + j] + 1e-8f) / asum[b * 8 + ii];
  }
  __syncthreads();
  for (int d = t; d < 512; d += 256) {
    float acc[8] = {0, 0, 0, 0, 0, 0, 0, 0};
    for (int j = 0; j < 256; ++j) {
      float vv = v[((size_t)b * 256 + j) * 512 + d];
#pragma unroll
      for (int ii = 0; ii < 8; ++ii) acc[ii] += at[ii][j] * vv;
    }
    for (int ii = 0; ii < 8; ++ii) upd[((size_t)b * 8 + ii) * 512 + d] = acc[ii];
  }
}

__global__ __launch_bounds__(256) void gru_kernel(const float* gi, const float* gh, const float* h,
                                                  float* out) {
  int i = blockIdx.x * 256 + threadIdx.x;
  if (i >= 512 * 512) return;
  int t = i / 512, d = i % 512;
  const float* gir = gi + (size_t)t * 1536;
  const float* ghr = gh + (size_t)t * 1536;
  float r = 1.f / (1.f + expf(-(gir[d] + ghr[d])));
  float zg = 1.f / (1.f + expf(-(gir[512 + d] + ghr[512 + d])));
  float n = tanhf(gir[1024 + d] + r * ghr[1024 + d]);
  out[i] = (1.f - zg) * n + zg * h[i];
}

__global__ __launch_bounds__(64) void feats_kernel(const float* slots, const float* dposT,
                                                   float* out) {
  int blk = blockIdx.x;  // bs*512 + d
  int bs = blk >> 9, d = blk & 511;
  float s = slots[(size_t)bs * 512 + d];
  const float* dp = dposT + (size_t)d * 256;
  int n0 = threadIdx.x * 4;
  float4 o;
  o.x = s + dp[n0]; o.y = s + dp[n0 + 1]; o.z = s + dp[n0 + 2]; o.w = s + dp[n0 + 3];
  *(float4*)(out + (size_t)blk * 256 + n0) = o;
}

// ------------------------------ host driver --------------------------------

extern "C" void kernel_launch(void* const* d_in, const int* in_sizes, int n_in, void* d_out,
                              int out_size, void* d_ws, size_t ws_size, hipStream_t stream) {
  const float* x = (const float*)d_in[0];
  const float* enc_pos_w = (const float*)d_in[1];
  const float* enc_pos_b = (const float*)d_in[2];
  const float* enc_norm_g = (const float*)d_in[3];
  const float* enc_norm_b = (const float*)d_in[4];
  const float* enc_mlp_w1 = (const float*)d_in[5];
  const float* enc_mlp_b1 = (const float*)d_in[6];
  const float* enc_mlp_w2 = (const float*)d_in[7];
  const float* enc_mlp_b2 = (const float*)d_in[8];
  const float* anch_w1 = (const float*)d_in[9];
  const float* anch_b1 = (const float*)d_in[10];
  const float* anch_w2 = (const float*)d_in[11];
  const float* anch_b2 = (const float*)d_in[12];
  const float* wq = (const float*)d_in[13];
  const float* bq = (const float*)d_in[14];
  const float* wk = (const float*)d_in[15];
  const float* bk = (const float*)d_in[16];
  const float* wv = (const float*)d_in[17];
  const float* bv = (const float*)d_in[18];
  const float* gru_wih = (const float*)d_in[19];
  const float* gru_whh = (const float*)d_in[20];
  const float* gru_bih = (const float*)d_in[21];
  const float* gru_bhh = (const float*)d_in[22];
  const float* mlp_w1 = (const float*)d_in[23];
  const float* mlp_b1 = (const float*)d_in[24];
  const float* mlp_w2 = (const float*)d_in[25];
  const float* mlp_b2 = (const float*)d_in[26];
  const float* ni_g = (const float*)d_in[27];
  const float* ni_b = (const float*)d_in[28];
  const float* ns_g = (const float*)d_in[29];
  const float* ns_b = (const float*)d_in[30];
  const float* npf_g = (const float*)d_in[31];
  const float* npf_b = (const float*)d_in[32];
  const float* emb = (const float*)d_in[33];
  const float* dec_pos_w = (const float*)d_in[34];
  const float* dec_pos_b = (const float*)d_in[35];

  float* out = (float*)d_out;
  const size_t FEATS = (size_t)512 * 512 * 256;  // 67108864
  float* out_slots = out + FEATS;
  float* out_idx = out + FEATS + 262144;
  float* out_qloss = out + FEATS + 262144 + 512;

  // workspace layout
  char* ws = (char*)d_ws;
  size_t off = 0;
  auto alloc = [&](size_t bytes) { size_t o = off; off = (off + bytes + 255) & ~(size_t)255; return (void*)(ws + o); };
  const size_t S = (size_t)64 * 256 * 512 * 4;  // 33554432
  float* fnp = (float*)alloc(S);
  float* R2 = (float*)alloc(S);  // kno/xn -> later Cbuf(f64)
  float* R3 = (float*)alloc(S);  // fpln -> later covA(f64)
  float* R4 = (float*)alloc(S);  // h1 -> later Qe(f64)
  float* R5 = (float*)alloc(S);  // fp -> later Q2(f64)
  float* kbuf = (float*)alloc(S);
  float* vbuf = (float*)alloc(S);
  float* posT = (float*)alloc(512 * 256 * 4);
  float* dposT = (float*)alloc(512 * 256 * 4);
  float* m1 = (float*)alloc(64 * 4);
  float* r1 = (float*)alloc(64 * 4);
  float* m2 = (float*)alloc(64 * 4);
  float* r2 = (float*)alloc(64 * 4);
  double* dE = (double*)alloc(64 * 256 * 8);
  double* eE = (double*)alloc(64 * 256 * 8);
  double* tauE = (double*)alloc(64 * 256 * 8);
  double* dlamda_g = (double*)alloc(64 * 256 * 8);
  double* w_g = (double*)alloc(64 * 256 * 8);
  double* zhat_g = (double*)alloc(64 * 256 * 8);
  double* tau_g = (double*)alloc(64 * 256 * 8);
  double* rho_g = (double*)alloc(64 * 8 * 8);
  int* indxq = (int*)alloc(64 * 256 * 4);
  int* surv_g = (int*)alloc(64 * 256 * 4);
  int* defl_g = (int*)alloc(64 * 256 * 4);
  int* orig_g = (int*)alloc(64 * 256 * 4);
  int* Kb = (int*)alloc(64 * 8 * 4);
  int* fidx = (int*)alloc(512 * 4);
  float* E = (float*)alloc(64 * 8 * 256 * 4);
  float* Eh = (float*)alloc(64 * 8 * 256 * 4);
  float* E2 = (float*)alloc(64 * 8 * 256 * 4);
  float* z = (float*)alloc(512 * 512 * 4);
  float* tslots = (float*)alloc(64 * 512 * 4);
  double* sdist = (double*)alloc(512 * 8);
  int* idxr = (int*)alloc(512 * 4);
  float* sA = (float*)alloc(512 * 512 * 4);
  float* sB = (float*)alloc(512 * 512 * 4);
  float* lnbuf = (float*)alloc(512 * 512 * 4);
  float* qbuf = (float*)alloc(512 * 512 * 4);
  float* dotsb = (float*)alloc(64 * 8 * 256 * 4);
  float* attnb = (float*)alloc(64 * 8 * 256 * 4);
  float* asumb = (float*)alloc(64 * 8 * 4);
  float* updb = (float*)alloc(512 * 512 * 4);
  float* gib = (float*)alloc((size_t)512 * 1536 * 4);
  float* ghb = (float*)alloc((size_t)512 * 1536 * 4);
  float* hidb = (float*)alloc(512 * 512 * 4);
  (void)ws_size; (void)in_sizes; (void)n_in; (void)out_size;

  auto gemm = [&](const float* A, const float* Bm, const float* bias, const float* base, float* C,
                  int M, int Nc, int Kd, int bt, int act, int addb) {
    // big path only when it yields enough blocks to fill the chip; else the
    // 64-tile kernel (more blocks). Both accumulate ascending-k with a single
    // accumulator per output -> identical results either way.
    if ((M % 128) == 0 && (Nc % 128) == 0 && (Kd % 32) == 0 &&
        (M / 128) * (Nc / 128) >= 128) {
      dim3 g(M / 128, Nc / 128);
      gemm_f32_big<<<g, 256, 0, stream>>>(A, Bm, bias, base, C, M, Nc, Kd, bt, act, addb);
    } else {
      dim3 g((M + 63) / 64, (Nc + 63) / 64);
      gemm_f32<<<g, 256, 0, stream>>>(A, Bm, bias, base, C, M, Nc, Kd, bt, act, addb);
    }
  };

  // positional embeddings (transposed [d][n])
  pos_kernel<<<(131072 + 255) / 256, 256, 0, stream>>>(enc_pos_w, enc_pos_b, posT);
  pos_kernel<<<(131072 + 255) / 256, 256, 0, stream>>>(dec_pos_w, dec_pos_b, dposT);
  // batch LN stats over (N,D)
  stats_kernel<<<64, 256, 0, stream>>>(x, posT, m1, r1, 0);
  stats_kernel<<<64, 256, 0, stream>>>(x, posT, m2, r2, 1);
  // transpose + LN -> fnp, fpln
  tln_kernel<<<dim3(64, 16, 8), 256, 0, stream>>>(x, posT, enc_norm_g, enc_norm_b, m1, r1, m2, r2,
                                                  fnp, R3);
  // k_nopos
  gemm(fnp, wk, bk, nullptr, R2, 16384, 512, 512, 0, 0, 0);
  // encoder MLP + ni LN -> fp (R5)
  gemm(R3, enc_mlp_w1, enc_mlp_b1, nullptr, R4, 16384, 512, 512, 0, 1, 0);
  gemm(R4, enc_mlp_w2, enc_mlp_b2, nullptr, R5, 16384, 512, 512, 0, 0, 0);
  rowln_kernel<<<16384, 256, 0, stream>>>(R5, ni_g, ni_b, R5);
  gemm(R5, wk, bk, nullptr, kbuf, 16384, 512, 512, 0, 0, 0);
  gemm(R5, wv, bv, nullptr, vbuf, 16384, 512, 512, 0, 0, 0);
  // xn + cov (f64) into R3 region
  xnorm_kernel<<<16384, 256, 0, stream>>>(R2);
  double* covA = (double*)R3;
  cov_kernel<<<dim3(64, 4, 4), 256, 0, stream>>>(R2, covA);
  // eigensolver buffers
  double* Qe = (double*)R4;
  double* Q2 = (double*)R5;
  double* Cbuf = (double*)R2;
  hipMemsetAsync(Qe, 0, S, stream);
  hipMemsetAsync(Q2, 0, S, stream);
  dsytrd_kernel<<<64, 1024, 0, stream>>>(covA, dE, eE, tauE);
  tear_kernel<<<1, 64, 0, stream>>>(dE, eE);
  leaf_kernel<<<(1024 + LPB - 1) / LPB, LPB, 0, stream>>>(dE, eE, Qe, indxq);
  for (int L = 0; L < 4; ++L) {
    int nm = 32 << L;
    int nmerge = 256 / nm;
    double* src = (L % 2 == 0) ? Qe : Q2;
    double* dst = (L % 2 == 0) ? Q2 : Qe;
    int gScan = (64 * nmerge + 63) / 64;
    merge_scan_kernel<<<dim3(64, nmerge), 256, 0, stream>>>(nm, nmerge, src, dE, eE, indxq,
                                                            dlamda_g, w_g, rho_g, surv_g, defl_g, Kb);
    secular_kernel<<<64, 256, 0, stream>>>(nm, nmerge, dlamda_g, w_g, rho_g, Kb, dE, tau_g, orig_g);
    zhat_kernel<<<64, 256, 0, stream>>>(nm, nmerge, dlamda_g, w_g, tau_g, orig_g, Kb, zhat_g);
    coeff_kernel<<<64, 256, 0, stream>>>(nm, nmerge, dlamda_g, zhat_g, tau_g, orig_g, Kb, Cbuf);
    int tcnt = nm / 32;
    merge_gemm_kernel<<<dim3(64, nmerge, tcnt * tcnt), 256, 0, stream>>>(nm, nmerge, src, Cbuf,
                                                                         surv_g, Kb, dst);
    defl_copy_kernel<<<dim3(64, nmerge), 256, 0, stream>>>(nm, nmerge, src, defl_g, Kb, dst);
    dlamrg_kernel<<<gScan, 64, 0, stream>>>(nm, nmerge, dE, Kb, indxq);
  }
  // final eigvecs in Qe; back-transform ranks 2..9 -> E
  dormtr_kernel<<<64, 256, 0, stream>>>(covA, tauE, Qe, indxq, E);
  // anchor MLP
  gemm(E, anch_w1, anch_b1, nullptr, Eh, 512, 256, 256, 0, 1, 0);
  gemm(Eh, anch_w2, anch_b2, nullptr, E2, 512, 256, 256, 0, 0, 0);
  // z projection
  zproj_kernel<<<64, 256, 0, stream>>>(fnp, E2, z);
  // template slots + quantization
  gemm(emb, wq, bq, nullptr, tslots, 64, 512, 512, 0, 0, 0);
  d2_kernel<<<512, 64, 0, stream>>>(z, tslots, sdist, idxr);
  order_kernel<<<1, 64, 0, stream>>>(sdist, idxr, fidx, out_idx);
  slots0_kernel<<<1024, 256, 0, stream>>>(z, emb, fidx, sA);
  qloss_kernel<<<1, 256, 0, stream>>>(z, tslots, fidx, out_qloss);
  // slot attention iterations
  for (int it = 0; it < 3; ++it) {
    rowln_kernel<<<512, 256, 0, stream>>>(sA, ns_g, ns_b, lnbuf);
    gemm(lnbuf, wq, bq, nullptr, qbuf, 512, 512, 512, 0, 0, 0);
    dots_kernel<<<dim3(64, 4), 256, 0, stream>>>(qbuf, kbuf, dotsb);
    softmax_kernel<<<64, 256, 0, stream>>>(dotsb, attnb);
    asum_kernel<<<512, 64, 0, stream>>>(attnb, asumb);
    updates_kernel<<<64, 256, 0, stream>>>(attnb, asumb, vbuf, updb);
    gemm(updb, gru_wih, gru_bih, nullptr, gib, 512, 1536, 512, 1, 0, 0);
    gemm(sA, gru_whh, gru_bhh, nullptr, ghb, 512, 1536, 512, 1, 0, 0);
    gru_kernel<<<1024, 256, 0, stream>>>(gib, ghb, sA, sB);
    rowln_kernel<<<512, 256, 0, stream>>>(sB, npf_g, npf_b, lnbuf);
    gemm(lnbuf, mlp_w1, mlp_b1, nullptr, hidb, 512, 512, 512, 0, 1, 0);
    gemm(hidb, mlp_w2, mlp_b2, sB, sA, 512, 512, 512, 0, 0, 1);
  }
  // outputs
  feats_kernel<<<262144, 64, 0, stream>>>(sA, dposT, out);
  hipMemcpyAsync(out_slots, sA, 262144 * 4, hipMemcpyDeviceToDevice, stream);
}